// Round 10
// baseline (654.035 us; speedup 1.0000x reference)
//
#include <hip/hip_runtime.h>
#include <hip/hip_bf16.h>

typedef __hip_bfloat16 bf16;

#define N_DOC   10000
#define N_WORD  20000
#define N_ENT   10000
#define N_POS   60
#define DD      128
#define D_WEMB  300
#define E11     320000
#define E22     160000
#define E33     3600
#define E01     300000
#define E02     100000
#define E03     150000

// Runtime dtype flag (ws[0]): 1 if float inputs are packed bf16, 0 if fp32.
// When flag==1, ws intermediates are ALSO stored bf16 (fp32 accumulate, bf16 store).
__device__ __forceinline__ float loadf(const void* p, size_t i, int isb) {
    return isb ? __bfloat162float(((const bf16*)p)[i])
               : ((const float*)p)[i];
}
__device__ __forceinline__ float b2f(unsigned u16) {
    union { unsigned v; float f; } x; x.v = u16 << 16; return x.f;
}
__device__ __forceinline__ unsigned f2b(float f) {
    bf16 h = __float2bfloat16(f);
    union { bf16 h; unsigned short u; } x; x.h = h; return (unsigned)x.u;
}
__device__ __forceinline__ void storef(void* p, size_t i, int asb, float v) {
    if (asb) ((unsigned short*)p)[i] = (unsigned short)f2b(v);
    else     ((float*)p)[i] = v;
}

// Detect input dtype from a randn fp32-or-bf16 buffer (see R2 notes).
__global__ void detect_kernel(const unsigned* __restrict__ probe, int* __restrict__ flag) {
    __shared__ int cnt;
    if (threadIdx.x == 0) cnt = 0;
    __syncthreads();
    int insane = 0;
    for (int i = threadIdx.x; i < 1024; i += 256) {
        float x = __uint_as_float(probe[i]);
        float a = fabsf(x);
        if (!(a > 1e-10f && a < 1e10f)) insane++;
    }
    atomicAdd(&cnt, insane);
    __syncthreads();
    if (threadIdx.x == 0) *flag = (cnt > 512) ? 1 : 0;
}

// ======================= fused 2-matrix CSR build =======================
__global__ void hist2_kernel(const int* __restrict__ rowsA, int nEA,
                             const int* __restrict__ rowsB, int nEB,
                             int nA, int* __restrict__ cnt) {
    int i = blockIdx.x * blockDim.x + threadIdx.x;
    if (i < nEA) atomicAdd(cnt + rowsA[i], 1);
    else if (i < nEA + nEB) atomicAdd(cnt + nA + rowsB[i - nEA], 1);
}

// Exclusive scan (1024 threads, wave shfl-scan + cross-wave LDS).
__device__ void scan_ex(const int* __restrict__ cnt, int* __restrict__ rp, int n) {
    __shared__ int wsum[16];
    __shared__ int carry;
    int t = threadIdx.x, lane = t & 63, w = t >> 6;
    if (t == 0) carry = 0;
    __syncthreads();
    for (int base = 0; base < n; base += 1024) {
        int i = base + t;
        int x = (i < n) ? cnt[i] : 0;
        int s = x;
        #pragma unroll
        for (int off = 1; off < 64; off <<= 1) {
            int y = __shfl_up(s, off);
            if (lane >= off) s += y;
        }
        if (lane == 63) wsum[w] = s;
        __syncthreads();
        if (w == 0) {
            int v = (lane < 16) ? wsum[lane] : 0;
            #pragma unroll
            for (int off = 1; off < 16; off <<= 1) {
                int y = __shfl_up(v, off);
                if (lane >= off) v += y;
            }
            if (lane < 16) wsum[lane] = v;
        }
        __syncthreads();
        int woff = (w > 0) ? wsum[w - 1] : 0;
        if (i < n) rp[i] = carry + woff + s - x;
        __syncthreads();
        if (t == 0) carry += wsum[15];
        __syncthreads();
    }
    if (t == 0) rp[n] = carry;
}

__global__ __launch_bounds__(1024) void scan2_kernel(
        const int* __restrict__ cntA, int* __restrict__ rpA, int nA,
        const int* __restrict__ cntB, int* __restrict__ rpB, int nB) {
    scan_ex(cntA, rpA, nA);
    __syncthreads();
    scan_ex(cntB, rpB, nB);
}

__global__ void copy2_kernel(const int* __restrict__ rpA, const int* __restrict__ rpB,
                             int nA, int nB, int* __restrict__ cur) {
    int i = blockIdx.x * blockDim.x + threadIdx.x;
    if (i < nA) cur[i] = rpA[i];
    else if (i < nA + nB) cur[i] = rpB[i - nA];
}

__global__ void scatter2_kernel(const int* __restrict__ rowsA, const int* __restrict__ colsA,
                                const void* __restrict__ valsA, int nEA,
                                const int* __restrict__ rowsB, const int* __restrict__ colsB,
                                const void* __restrict__ valsB, int nEB,
                                int nA, int* __restrict__ cur,
                                int2* __restrict__ pairsA, int2* __restrict__ pairsB,
                                const int* __restrict__ dflag) {
    int i = blockIdx.x * blockDim.x + threadIdx.x;
    int isb = *dflag;
    if (i < nEA) {
        int p = atomicAdd(cur + rowsA[i], 1);
        pairsA[p] = make_int2(colsA[i], __float_as_int(loadf(valsA, i, isb)));
    } else if (i < nEA + nEB) {
        int k = i - nEA;
        int p = atomicAdd(cur + nA + rowsB[k], 1);
        pairsB[p] = make_int2(colsB[k], __float_as_int(loadf(valsB, k, isb)));
    }
}

// ======================= gather SpMM (no atomics) =======================
// dst[row, 0..D) = sum_e vals[e] * act(src[cols[e], 0..D)); one wave/row.
// 2-edge unroll, dual accumulators. src/dst dtype follow *dflag when flagged.
template<bool RELU, int D>
__global__ void spmm_gather(const int* __restrict__ rowptr, const int2* __restrict__ pairs,
                            const void* __restrict__ src, int sstride, int src_flagged,
                            void* __restrict__ dst, int dstride, int doff, int dst_flagged,
                            int n, const int* __restrict__ dflag) {
    constexpr int PAIRS = D / 2;
    constexpr int NS = (PAIRS + 63) / 64;
    int row = blockIdx.x * (blockDim.x >> 6) + (threadIdx.x >> 6);
    if (row >= n) return;
    int isb  = *dflag;
    int sisb = src_flagged ? isb : 0;
    int disb = dst_flagged ? isb : 0;
    int lane = threadIdx.x & 63;
    int e0 = rowptr[row], e1 = rowptr[row + 1];
    float2 acc[NS], acc2[NS];
    #pragma unroll
    for (int s = 0; s < NS; ++s) { acc[s] = make_float2(0.f, 0.f); acc2[s] = make_float2(0.f, 0.f); }
    if (sisb) {
        int e = e0;
        for (; e + 2 <= e1; e += 2) {
            int2 p0 = pairs[e], p1 = pairs[e + 1];
            float v0 = __int_as_float(p0.y), v1 = __int_as_float(p1.y);
            const unsigned* s0 = (const unsigned*)((const bf16*)src + (size_t)p0.x * sstride);
            const unsigned* s1 = (const unsigned*)((const bf16*)src + (size_t)p1.x * sstride);
            #pragma unroll
            for (int s = 0; s < NS; ++s) {
                int pi = lane + 64 * s;
                if (pi < PAIRS) {
                    unsigned u0 = s0[pi], u1 = s1[pi];
                    float a0 = b2f(u0 & 0xffffu), a1 = b2f(u0 >> 16);
                    float c0 = b2f(u1 & 0xffffu), c1 = b2f(u1 >> 16);
                    if (RELU) { a0 = fmaxf(a0, 0.f); a1 = fmaxf(a1, 0.f);
                                c0 = fmaxf(c0, 0.f); c1 = fmaxf(c1, 0.f); }
                    acc[s].x  = fmaf(v0, a0, acc[s].x);
                    acc[s].y  = fmaf(v0, a1, acc[s].y);
                    acc2[s].x = fmaf(v1, c0, acc2[s].x);
                    acc2[s].y = fmaf(v1, c1, acc2[s].y);
                }
            }
        }
        if (e < e1) {
            int2 p = pairs[e];
            float v = __int_as_float(p.y);
            const unsigned* sp = (const unsigned*)((const bf16*)src + (size_t)p.x * sstride);
            #pragma unroll
            for (int s = 0; s < NS; ++s) {
                int pi = lane + 64 * s;
                if (pi < PAIRS) {
                    unsigned u = sp[pi];
                    float x0 = b2f(u & 0xffffu), x1 = b2f(u >> 16);
                    if (RELU) { x0 = fmaxf(x0, 0.f); x1 = fmaxf(x1, 0.f); }
                    acc[s].x = fmaf(v, x0, acc[s].x);
                    acc[s].y = fmaf(v, x1, acc[s].y);
                }
            }
        }
    } else {
        int e = e0;
        for (; e + 2 <= e1; e += 2) {
            int2 p0 = pairs[e], p1 = pairs[e + 1];
            float v0 = __int_as_float(p0.y), v1 = __int_as_float(p1.y);
            const float2* s0 = (const float2*)((const float*)src + (size_t)p0.x * sstride);
            const float2* s1 = (const float2*)((const float*)src + (size_t)p1.x * sstride);
            #pragma unroll
            for (int s = 0; s < NS; ++s) {
                int pi = lane + 64 * s;
                if (pi < PAIRS) {
                    float2 x = s0[pi], y = s1[pi];
                    if (RELU) { x.x = fmaxf(x.x, 0.f); x.y = fmaxf(x.y, 0.f);
                                y.x = fmaxf(y.x, 0.f); y.y = fmaxf(y.y, 0.f); }
                    acc[s].x  = fmaf(v0, x.x, acc[s].x);
                    acc[s].y  = fmaf(v0, x.y, acc[s].y);
                    acc2[s].x = fmaf(v1, y.x, acc2[s].x);
                    acc2[s].y = fmaf(v1, y.y, acc2[s].y);
                }
            }
        }
        if (e < e1) {
            int2 p = pairs[e];
            float v = __int_as_float(p.y);
            const float2* sp = (const float2*)((const float*)src + (size_t)p.x * sstride);
            #pragma unroll
            for (int s = 0; s < NS; ++s) {
                int pi = lane + 64 * s;
                if (pi < PAIRS) {
                    float2 x = sp[pi];
                    if (RELU) { x.x = fmaxf(x.x, 0.f); x.y = fmaxf(x.y, 0.f); }
                    acc[s].x = fmaf(v, x.x, acc[s].x);
                    acc[s].y = fmaf(v, x.y, acc[s].y);
                }
            }
        }
    }
    if (disb) {
        unsigned* dp = (unsigned*)((bf16*)dst + (size_t)row * dstride + doff);
        #pragma unroll
        for (int s = 0; s < NS; ++s) {
            int pi = lane + 64 * s;
            if (pi < PAIRS)
                dp[pi] = f2b(acc[s].x + acc2[s].x) | (f2b(acc[s].y + acc2[s].y) << 16);
        }
    } else {
        float2* dp = (float2*)((float*)dst + (size_t)row * dstride + doff);
        #pragma unroll
        for (int s = 0; s < NS; ++s) {
            int pi = lane + 64 * s;
            if (pi < PAIRS) dp[pi] = make_float2(acc[s].x + acc2[s].x, acc[s].y + acc2[s].y);
        }
    }
}

// ===== fused doc-agg + L2-norm, D=128: agg row held in regs, normed, stored to out =====
// out[elem_off + row*128 + j] = agg[j] / (||agg|| + 1e-9). one wave/row.
template<bool RELU>
__global__ void spmm_norm128(const int* __restrict__ rowptr, const int2* __restrict__ pairs,
                             const void* __restrict__ src, int src_flagged,
                             void* __restrict__ out, size_t elem_off,
                             int n, const int* __restrict__ dflag) {
    int row = blockIdx.x * (blockDim.x >> 6) + (threadIdx.x >> 6);
    if (row >= n) return;
    int isb  = *dflag;
    int sisb = src_flagged ? isb : 0;
    int lane = threadIdx.x & 63;
    int e0 = rowptr[row], e1 = rowptr[row + 1];
    float2 acc = make_float2(0.f, 0.f), acc2 = make_float2(0.f, 0.f);
    if (sisb) {
        int e = e0;
        for (; e + 2 <= e1; e += 2) {
            int2 p0 = pairs[e], p1 = pairs[e + 1];
            float v0 = __int_as_float(p0.y), v1 = __int_as_float(p1.y);
            unsigned u0 = ((const unsigned*)((const bf16*)src + (size_t)p0.x * DD))[lane];
            unsigned u1 = ((const unsigned*)((const bf16*)src + (size_t)p1.x * DD))[lane];
            float a0 = b2f(u0 & 0xffffu), a1 = b2f(u0 >> 16);
            float c0 = b2f(u1 & 0xffffu), c1 = b2f(u1 >> 16);
            if (RELU) { a0 = fmaxf(a0, 0.f); a1 = fmaxf(a1, 0.f);
                        c0 = fmaxf(c0, 0.f); c1 = fmaxf(c1, 0.f); }
            acc.x  = fmaf(v0, a0, acc.x);  acc.y  = fmaf(v0, a1, acc.y);
            acc2.x = fmaf(v1, c0, acc2.x); acc2.y = fmaf(v1, c1, acc2.y);
        }
        if (e < e1) {
            int2 p = pairs[e];
            float v = __int_as_float(p.y);
            unsigned u = ((const unsigned*)((const bf16*)src + (size_t)p.x * DD))[lane];
            float x0 = b2f(u & 0xffffu), x1 = b2f(u >> 16);
            if (RELU) { x0 = fmaxf(x0, 0.f); x1 = fmaxf(x1, 0.f); }
            acc.x = fmaf(v, x0, acc.x); acc.y = fmaf(v, x1, acc.y);
        }
    } else {
        int e = e0;
        for (; e + 2 <= e1; e += 2) {
            int2 p0 = pairs[e], p1 = pairs[e + 1];
            float v0 = __int_as_float(p0.y), v1 = __int_as_float(p1.y);
            float2 x = ((const float2*)((const float*)src + (size_t)p0.x * DD))[lane];
            float2 y = ((const float2*)((const float*)src + (size_t)p1.x * DD))[lane];
            if (RELU) { x.x = fmaxf(x.x, 0.f); x.y = fmaxf(x.y, 0.f);
                        y.x = fmaxf(y.x, 0.f); y.y = fmaxf(y.y, 0.f); }
            acc.x  = fmaf(v0, x.x, acc.x);  acc.y  = fmaf(v0, x.y, acc.y);
            acc2.x = fmaf(v1, y.x, acc2.x); acc2.y = fmaf(v1, y.y, acc2.y);
        }
        if (e < e1) {
            int2 p = pairs[e];
            float v = __int_as_float(p.y);
            float2 x = ((const float2*)((const float*)src + (size_t)p.x * DD))[lane];
            if (RELU) { x.x = fmaxf(x.x, 0.f); x.y = fmaxf(x.y, 0.f); }
            acc.x = fmaf(v, x.x, acc.x); acc.y = fmaf(v, x.y, acc.y);
        }
    }
    float tx = acc.x + acc2.x, ty = acc.y + acc2.y;
    float ss = tx * tx + ty * ty;
    #pragma unroll
    for (int off = 32; off > 0; off >>= 1) ss += __shfl_down(ss, off);
    ss = __shfl(ss, 0);
    float inv = 1.0f / (sqrtf(ss) + 1e-9f);
    size_t base = elem_off + (size_t)row * DD;
    if (isb) {
        ((unsigned*)((bf16*)out + base))[lane] = f2b(tx * inv) | (f2b(ty * inv) << 16);
    } else {
        ((float2*)((float*)out + base))[lane] = make_float2(tx * inv, ty * inv);
    }
}

// ===== fused type-2 doc-agg (A02@relu(E0) ++ A02@wemb) + L2-norm over 428 cols =====
// one wave/row. src1: 128-wide (RELU), src2: 300-wide (no relu).
__global__ void spmm2_norm(const int* __restrict__ rowptr, const int2* __restrict__ pairs,
                           const void* __restrict__ src1, int s1_flagged,
                           const void* __restrict__ src2, int s2_flagged,
                           void* __restrict__ out, size_t elem_off,
                           int n, const int* __restrict__ dflag) {
    constexpr int P2 = D_WEMB / 2;   // 150
    int row = blockIdx.x * (blockDim.x >> 6) + (threadIdx.x >> 6);
    if (row >= n) return;
    int isb = *dflag;
    int s1b = s1_flagged ? isb : 0;
    int s2b = s2_flagged ? isb : 0;
    int lane = threadIdx.x & 63;
    int e0 = rowptr[row], e1 = rowptr[row + 1];
    float2 a1 = make_float2(0.f, 0.f);
    float2 a2[3];
    #pragma unroll
    for (int s = 0; s < 3; ++s) a2[s] = make_float2(0.f, 0.f);
    for (int e = e0; e < e1; ++e) {
        int2 p = pairs[e];
        float v = __int_as_float(p.y);
        // part 1: 128-wide, RELU
        float x0, x1;
        if (s1b) {
            unsigned u = ((const unsigned*)((const bf16*)src1 + (size_t)p.x * DD))[lane];
            x0 = b2f(u & 0xffffu); x1 = b2f(u >> 16);
        } else {
            float2 x = ((const float2*)((const float*)src1 + (size_t)p.x * DD))[lane];
            x0 = x.x; x1 = x.y;
        }
        x0 = fmaxf(x0, 0.f); x1 = fmaxf(x1, 0.f);
        a1.x = fmaf(v, x0, a1.x); a1.y = fmaf(v, x1, a1.y);
        // part 2: 300-wide, no relu
        if (s2b) {
            const unsigned* sp = (const unsigned*)((const bf16*)src2 + (size_t)p.x * D_WEMB);
            #pragma unroll
            for (int s = 0; s < 3; ++s) {
                int pi = lane + 64 * s;
                if (pi < P2) {
                    unsigned u = sp[pi];
                    a2[s].x = fmaf(v, b2f(u & 0xffffu), a2[s].x);
                    a2[s].y = fmaf(v, b2f(u >> 16),     a2[s].y);
                }
            }
        } else {
            const float2* sp = (const float2*)((const float*)src2 + (size_t)p.x * D_WEMB);
            #pragma unroll
            for (int s = 0; s < 3; ++s) {
                int pi = lane + 64 * s;
                if (pi < P2) {
                    float2 x = sp[pi];
                    a2[s].x = fmaf(v, x.x, a2[s].x);
                    a2[s].y = fmaf(v, x.y, a2[s].y);
                }
            }
        }
    }
    float ss = a1.x * a1.x + a1.y * a1.y;
    #pragma unroll
    for (int s = 0; s < 3; ++s) {
        int pi = lane + 64 * s;
        if (pi < P2) ss += a2[s].x * a2[s].x + a2[s].y * a2[s].y;
    }
    #pragma unroll
    for (int off = 32; off > 0; off >>= 1) ss += __shfl_down(ss, off);
    ss = __shfl(ss, 0);
    float inv = 1.0f / (sqrtf(ss) + 1e-9f);
    size_t base = elem_off + (size_t)row * (DD + D_WEMB);
    if (isb) {
        ((unsigned*)((bf16*)out + base))[lane] = f2b(a1.x * inv) | (f2b(a1.y * inv) << 16);
        unsigned* o2 = (unsigned*)((bf16*)out + base + DD);
        #pragma unroll
        for (int s = 0; s < 3; ++s) {
            int pi = lane + 64 * s;
            if (pi < P2) o2[pi] = f2b(a2[s].x * inv) | (f2b(a2[s].y * inv) << 16);
        }
    } else {
        ((float2*)((float*)out + base))[lane] = make_float2(a1.x * inv, a1.y * inv);
        float2* o2 = (float2*)((float*)out + base + DD);
        #pragma unroll
        for (int s = 0; s < 3; ++s) {
            int pi = lane + 64 * s;
            if (pi < P2) o2[pi] = make_float2(a2[s].x * inv, a2[s].y * inv);
        }
    }
}

// ======================= atomic SpMM (ws_size fallback only) =======================
template<bool RELU>
__global__ void spmm_kernel(const int* __restrict__ rows, const int* __restrict__ cols,
                            const void* __restrict__ vals,
                            const void* __restrict__ src, int sstride, int src_flagged,
                            float* __restrict__ dst, int dstride, int doff,
                            int d, int nE, const int* __restrict__ dflag) {
    int e = blockIdx.x * (blockDim.x >> 6) + (threadIdx.x >> 6);
    if (e >= nE) return;
    int isb  = *dflag;
    int sisb = src_flagged ? isb : 0;
    int lane = threadIdx.x & 63;
    int r = rows[e];
    int c = cols[e];
    float v = loadf(vals, e, isb);
    size_t sbase = (size_t)c * sstride;
    float* dp = dst + (size_t)r * dstride + doff;
    if (sisb) {
        const unsigned* sp = (const unsigned*)((const bf16*)src + sbase);
        for (int j = 2 * lane; j < d; j += 128) {
            unsigned u = sp[j >> 1];
            float x0 = b2f(u & 0xffffu);
            float x1 = b2f(u >> 16);
            if (RELU) { x0 = fmaxf(x0, 0.f); x1 = fmaxf(x1, 0.f); }
            atomicAdd(dp + j,     v * x0);
            atomicAdd(dp + j + 1, v * x1);
        }
    } else {
        const float2* sp = (const float2*)((const float*)src + sbase);
        for (int j = 2 * lane; j < d; j += 128) {
            float2 x = sp[j >> 1];
            if (RELU) { x.x = fmaxf(x.x, 0.f); x.y = fmaxf(x.y, 0.f); }
            atomicAdd(dp + j,     v * x.x);
            atomicAdd(dp + j + 1, v * x.y);
        }
    }
}

// ======================= dense GEMMs =======================
// out[n x 128] = act(X[n x 128]) @ W[128 x 128] + b.  1-D grid of 64-row tiles.
// Each block loops over the four 32-col W tiles (16 KB LDS each); X re-reads
// across tiles hit L1 (64 rows x 256 B = 16 KB). X/out follow *dflag.
template<bool RELU>
__global__ __launch_bounds__(256) void gemm_tile(
        const void* __restrict__ X, const void* __restrict__ W,
        const void* __restrict__ b, void* __restrict__ out, int n,
        const int* __restrict__ dflag) {
    __shared__ float Wl[128 * 32];
    int isb = *dflag;
    int tid = threadIdx.x;
    int j = tid & 31;
    int g = tid >> 5;
    int i0 = blockIdx.x * 64 + g * 8;
    for (int ct = 0; ct < 4; ++ct) {
        int jc = ct * 32;
        if (ct > 0) __syncthreads();          // prior tile's readers done
        if (isb) {
            const uint2* Wg = (const uint2*)W;
            float4* Wl4 = (float4*)Wl;
            for (int vidx = tid; vidx < 1024; vidx += 256) {
                int k = vidx >> 3, jl4 = vidx & 7;
                uint2 u = Wg[k * 32 + (jc >> 2) + jl4];
                float4 vv;
                vv.x = b2f(u.x & 0xffffu);
                vv.y = b2f(u.x >> 16);
                vv.z = b2f(u.y & 0xffffu);
                vv.w = b2f(u.y >> 16);
                Wl4[vidx] = vv;
            }
        } else {
            const float4* Wg = (const float4*)W;
            float4* Wl4 = (float4*)Wl;
            for (int vidx = tid; vidx < 1024; vidx += 256) {
                int k = vidx >> 3, jl4 = vidx & 7;
                Wl4[vidx] = Wg[k * 32 + (jc >> 2) + jl4];
            }
        }
        __syncthreads();
        float bj = loadf(b, jc + j, isb);
        float a[8];
        #pragma unroll
        for (int r = 0; r < 8; ++r) a[r] = bj;
        if (isb) {
            const uint2* xp = (const uint2*)((const bf16*)X + (size_t)i0 * 128);
            #pragma unroll 2
            for (int k4 = 0; k4 < 32; ++k4) {
                float w0 = Wl[(4 * k4 + 0) * 32 + j];
                float w1 = Wl[(4 * k4 + 1) * 32 + j];
                float w2 = Wl[(4 * k4 + 2) * 32 + j];
                float w3 = Wl[(4 * k4 + 3) * 32 + j];
                #pragma unroll
                for (int r = 0; r < 8; ++r) {
                    uint2 u = xp[r * 32 + k4];
                    float vx = b2f(u.x & 0xffffu), vy = b2f(u.x >> 16);
                    float vz = b2f(u.y & 0xffffu), vw = b2f(u.y >> 16);
                    if (RELU) {
                        vx = fmaxf(vx, 0.f); vy = fmaxf(vy, 0.f);
                        vz = fmaxf(vz, 0.f); vw = fmaxf(vw, 0.f);
                    }
                    a[r] = fmaf(vw, w3, fmaf(vz, w2, fmaf(vy, w1, fmaf(vx, w0, a[r]))));
                }
            }
        } else {
            const float4* xp = (const float4*)((const float*)X + (size_t)i0 * 128);
            #pragma unroll 2
            for (int k4 = 0; k4 < 32; ++k4) {
                float w0 = Wl[(4 * k4 + 0) * 32 + j];
                float w1 = Wl[(4 * k4 + 1) * 32 + j];
                float w2 = Wl[(4 * k4 + 2) * 32 + j];
                float w3 = Wl[(4 * k4 + 3) * 32 + j];
                #pragma unroll
                for (int r = 0; r < 8; ++r) {
                    float4 v = xp[r * 32 + k4];
                    if (RELU) {
                        v.x = fmaxf(v.x, 0.f); v.y = fmaxf(v.y, 0.f);
                        v.z = fmaxf(v.z, 0.f); v.w = fmaxf(v.w, 0.f);
                    }
                    a[r] = fmaf(v.w, w3, fmaf(v.z, w2, fmaf(v.y, w1, fmaf(v.x, w0, a[r]))));
                }
            }
        }
        #pragma unroll
        for (int r = 0; r < 8; ++r) {
            int i = i0 + r;
            if (i < n) storef(out, (size_t)i * 128 + jc + j, isb, a[r]);
        }
    }
}

// Legacy big-LDS GEMM (fallback path only; fp32 ws).
template<bool RELU>
__global__ __launch_bounds__(256) void gemm128_kernel(
        const float* __restrict__ X, const void* __restrict__ W,
        const void* __restrict__ b, float* __restrict__ out, int n,
        const int* __restrict__ dflag) {
    __shared__ float Wl[128 * 128];
    int isb = *dflag;
    int tid = threadIdx.x;
    if (isb) {
        const uint2* Wg = (const uint2*)W;
        float4* Wl4 = (float4*)Wl;
        for (int idx = tid; idx < 4096; idx += 256) {
            uint2 u = Wg[idx];
            float4 vv;
            vv.x = b2f(u.x & 0xffffu);
            vv.y = b2f(u.x >> 16);
            vv.z = b2f(u.y & 0xffffu);
            vv.w = b2f(u.y >> 16);
            Wl4[idx] = vv;
        }
    } else {
        const float4* Wg = (const float4*)W;
        float4* Wl4 = (float4*)Wl;
        for (int idx = tid; idx < 4096; idx += 256) Wl4[idx] = Wg[idx];
    }
    __syncthreads();
    int j = tid & 127;
    int h = tid >> 7;
    float bj = loadf(b, j, isb);
    int row0 = blockIdx.x * 64 + h * 32;
    for (int q = 0; q < 8; ++q) {
        int gi = row0 + q * 4;
        if (gi >= n) break;
        const float4* x0 = (const float4*)(X + (size_t)gi * 128);
        const float4* x1 = x0 + 32;
        const float4* x2 = x1 + 32;
        const float4* x3 = x2 + 32;
        float a0 = bj, a1 = bj, a2 = bj, a3 = bj;
        #pragma unroll 4
        for (int k4 = 0; k4 < 32; ++k4) {
            float4 v0 = x0[k4], v1 = x1[k4], v2 = x2[k4], v3 = x3[k4];
            if (RELU) {
                v0.x = fmaxf(v0.x, 0.f); v0.y = fmaxf(v0.y, 0.f); v0.z = fmaxf(v0.z, 0.f); v0.w = fmaxf(v0.w, 0.f);
                v1.x = fmaxf(v1.x, 0.f); v1.y = fmaxf(v1.y, 0.f); v1.z = fmaxf(v1.z, 0.f); v1.w = fmaxf(v1.w, 0.f);
                v2.x = fmaxf(v2.x, 0.f); v2.y = fmaxf(v2.y, 0.f); v2.z = fmaxf(v2.z, 0.f); v2.w = fmaxf(v2.w, 0.f);
                v3.x = fmaxf(v3.x, 0.f); v3.y = fmaxf(v3.y, 0.f); v3.z = fmaxf(v3.z, 0.f); v3.w = fmaxf(v3.w, 0.f);
            }
            float w0 = Wl[(4 * k4 + 0) * 128 + j];
            float w1 = Wl[(4 * k4 + 1) * 128 + j];
            float w2 = Wl[(4 * k4 + 2) * 128 + j];
            float w3 = Wl[(4 * k4 + 3) * 128 + j];
            a0 = fmaf(v0.w, w3, fmaf(v0.z, w2, fmaf(v0.y, w1, fmaf(v0.x, w0, a0))));
            a1 = fmaf(v1.w, w3, fmaf(v1.z, w2, fmaf(v1.y, w1, fmaf(v1.x, w0, a1))));
            a2 = fmaf(v2.w, w3, fmaf(v2.z, w2, fmaf(v2.y, w1, fmaf(v2.x, w0, a2))));
            a3 = fmaf(v3.w, w3, fmaf(v3.z, w2, fmaf(v3.y, w1, fmaf(v3.x, w0, a3))));
        }
        float* o = out + (size_t)gi * 128 + j;
        o[0] = a0; o[128] = a1; o[256] = a2; o[384] = a3;
    }
}

// Row-parallel tiny GEMM (type-3, n=60): one block per row, 128 threads.
template<bool RELU, int K>
__global__ void rowpar_gemm(const void* __restrict__ X, int x_flagged,
                            const void* __restrict__ W, const void* __restrict__ b,
                            void* __restrict__ out, int out_flagged,
                            const int* __restrict__ dflag) {
    __shared__ float xr[K];
    int isb  = *dflag;
    int xisb = x_flagged ? isb : 0;
    int oisb = out_flagged ? isb : 0;
    int row = blockIdx.x;
    int j = threadIdx.x;
    if (j < K) {
        float x = loadf(X, (size_t)row * K + j, xisb);
        if (RELU) x = fmaxf(x, 0.f);
        xr[j] = x;
    }
    __syncthreads();
    float acc = loadf(b, j, isb);
    #pragma unroll 8
    for (int k = 0; k < K; ++k)
        acc = fmaf(xr[k], loadf(W, (size_t)k * 128 + j, isb), acc);
    storef(out, (size_t)row * 128 + j, oisb, acc);
}

// Generic small GEMM (fallback path only).
template<bool RELU, int K>
__global__ void gemm_kernel(const void* __restrict__ X, int x_flagged,
                            const void* __restrict__ W,
                            const void* __restrict__ b,
                            float* __restrict__ out, int n,
                            const int* __restrict__ dflag) {
    __shared__ float Wl[K * 128];
    int isb  = *dflag;
    int xisb = x_flagged ? isb : 0;
    int j = threadIdx.x;
    for (int idx = j; idx < K * 128; idx += 128)
        Wl[idx] = loadf(W, idx, isb);
    __syncthreads();
    float bj = loadf(b, j, isb);
    int row0 = blockIdx.x * 64;
    for (int i0 = 0; i0 < 64; i0 += 4) {
        int i = row0 + i0;
        if (i >= n) break;
        size_t r0 = (size_t)i * K;
        float a0 = bj, a1 = bj, a2 = bj, a3 = bj;
        for (int k = 0; k < K; ++k) {
            float w = Wl[k * 128 + j];
            float v0 = loadf(X, r0 + k, xisb);
            float v1 = loadf(X, r0 + K + k, xisb);
            float v2 = loadf(X, r0 + 2 * K + k, xisb);
            float v3 = loadf(X, r0 + 3 * K + k, xisb);
            if (RELU) {
                v0 = fmaxf(v0, 0.f); v1 = fmaxf(v1, 0.f);
                v2 = fmaxf(v2, 0.f); v3 = fmaxf(v3, 0.f);
            }
            a0 = fmaf(v0, w, a0);
            a1 = fmaf(v1, w, a1);
            a2 = fmaf(v2, w, a2);
            a3 = fmaf(v3, w, a3);
        }
        float* o = out + (size_t)i * 128 + j;
        o[0] = a0; o[128] = a1; o[256] = a2; o[384] = a3;
    }
}

// L2-norm (fallback path only).
__global__ void l2norm_kernel(const float* __restrict__ agg, int d,
                              void* __restrict__ out, size_t elem_off, int n,
                              const int* __restrict__ dflag) {
    int row = blockIdx.x * (blockDim.x >> 6) + (threadIdx.x >> 6);
    if (row >= n) return;
    int isb  = *dflag;
    int lane = threadIdx.x & 63;
    const float2* a2 = (const float2*)(agg + (size_t)row * d);
    float ss = 0.f;
    for (int j = 2 * lane; j < d; j += 128) {
        float2 x = a2[j >> 1];
        ss += x.x * x.x + x.y * x.y;
    }
    #pragma unroll
    for (int off = 32; off > 0; off >>= 1) ss += __shfl_down(ss, off);
    ss = __shfl(ss, 0);
    float inv = 1.0f / (sqrtf(ss) + 1e-9f);
    size_t bbase = elem_off + (size_t)row * d;
    if (isb) {
        unsigned* o = (unsigned*)((bf16*)out + bbase);
        for (int j = 2 * lane; j < d; j += 128) {
            float2 x = a2[j >> 1];
            o[j >> 1] = f2b(x.x * inv) | (f2b(x.y * inv) << 16);
        }
    } else {
        float2* o = (float2*)((float*)out + bbase);
        for (int j = 2 * lane; j < d; j += 128) {
            float2 x = a2[j >> 1];
            o[j >> 1] = make_float2(x.x * inv, x.y * inv);
        }
    }
}

static inline int spmm_grid(int nE) { return (nE + 3) / 4; }
static inline int row_grid(int n)   { return (n + 3) / 4; }

// Fused per-phase CSR build for two matrices A,B sharing one cursor block.
static void build2(hipStream_t stream,
                   const int* rowsA, const int* colsA, const void* valsA, int nA, int nEA,
                   const int* rowsB, const int* colsB, const void* valsB, int nB, int nEB,
                   int* rpA, int* rpB, int* curAB, int2* pairsA, int2* pairsB,
                   const int* dflag) {
    int nE = nEA + nEB;
    hipMemsetAsync(curAB, 0, (size_t)(nA + nB) * 4, stream);
    hist2_kernel<<<(nE + 255) / 256, 256, 0, stream>>>(rowsA, nEA, rowsB, nEB, nA, curAB);
    scan2_kernel<<<1, 1024, 0, stream>>>(curAB, rpA, nA, curAB + nA, rpB, nB);
    copy2_kernel<<<(nA + nB + 255) / 256, 256, 0, stream>>>(rpA, rpB, nA, nB, curAB);
    scatter2_kernel<<<(nE + 255) / 256, 256, 0, stream>>>(
        rowsA, colsA, valsA, nEA, rowsB, colsB, valsB, nEB, nA, curAB, pairsA, pairsB, dflag);
}

extern "C" void kernel_launch(void* const* d_in, const int* in_sizes, int n_in,
                              void* d_out, int out_size, void* d_ws, size_t ws_size,
                              hipStream_t stream) {
    const void* f1   = d_in[0];
    const void* f2   = d_in[1];
    const void* f3   = d_in[2];
    const void* wemb = d_in[3];
    const int*  a11r = (const int*)d_in[4];
    const int*  a11c = (const int*)d_in[5];
    const void* a11v = d_in[6];
    const int*  a22r = (const int*)d_in[7];
    const int*  a22c = (const int*)d_in[8];
    const void* a22v = d_in[9];
    const int*  a33r = (const int*)d_in[10];
    const int*  a33c = (const int*)d_in[11];
    const void* a33v = d_in[12];
    const int*  a01r = (const int*)d_in[13];
    const int*  a01c = (const int*)d_in[14];
    const void* a01v = d_in[15];
    const int*  a02r = (const int*)d_in[16];
    const int*  a02c = (const int*)d_in[17];
    const void* a02v = d_in[18];
    const int*  a03r = (const int*)d_in[19];
    const int*  a03c = (const int*)d_in[20];
    const void* a03v = d_in[21];
    const void* W3   = d_in[22];
    const void* b3   = d_in[23];
    const void* W1_2 = d_in[24];
    const void* b1_2 = d_in[25];
    const void* W2_2 = d_in[26];
    const void* b2_2 = d_in[27];
    const void* W3_2 = d_in[28];
    const void* b3_2 = d_in[29];

    int*   dflag = (int*)d_ws;
    float* base  = (float*)d_ws + 16;       // buffers start 64 B in (sized for fp32 worst case)
    float* S0   = base;                     // 20000*128
    float* S1   = base + 2560000;           // 20000*128
    float* AGG1 = S1;                       // fallback only
    float* E0   = base;                     // 10000*128
    float* E1   = base + 1280000;           // 10000*128
    float* AGG2 = base + 1280000;           // fallback only
    float* P3a  = base;                     // 60*128
    float* P3b  = base + 7680;              // 60*128
    float* AGG3 = base + 15360;             // fallback only

    // CSR region after dense peak: [rpA | rpB | curAB | pairsA | pairsB]
    int* I = (int*)(base + 5560000);
    const size_t WS_NEEDED = 64 + 22240000ull + 240008ull + 4960000ull; // ~27.44 MB

    const size_t OUT1_OFF = 0;
    const size_t OUT2_OFF = (size_t)N_DOC * DD;                       // 1,280,000
    const size_t OUT3_OFF = OUT2_OFF + (size_t)N_DOC * (DD + D_WEMB); // 5,560,000

    dim3 blk(256);
    detect_kernel<<<1, 256, 0, stream>>>((const unsigned*)f1, dflag);

    if (ws_size >= WS_NEEDED) {
        // ================= CSR gather path (bf16 intermediates when isb) =================
        // ---------------- type 1 (words): A=A11 (20000), B=A01 (10000) ----------------
        {
            int* rpA = I; int* rpB = rpA + (N_WORD + 1); int* cur = rpB + (N_DOC + 1);
            int2* pA = (int2*)(cur + N_WORD + N_DOC); int2* pB = pA + E11;
            build2(stream, a11r, a11c, a11v, N_WORD, E11,
                   a01r, a01c, a01v, N_DOC, E01, rpA, rpB, cur, pA, pB, dflag);
            spmm_gather<false, 128><<<row_grid(N_WORD), blk, 0, stream>>>(
                rpA, pA, f1, DD, 1, S0, DD, 0, 1, N_WORD, dflag);     // S0 = A11@f1
            gemm_tile<true><<<(N_WORD + 63) / 64, 256, 0, stream>>>(
                S0, W1_2, b1_2, S1, N_WORD, dflag);                   // S1 = relu(S0)@W+b
            spmm_gather<false, 128><<<row_grid(N_WORD), blk, 0, stream>>>(
                rpA, pA, S1, DD, 1, S0, DD, 0, 1, N_WORD, dflag);     // S0 = A11@S1
            spmm_norm128<true><<<row_grid(N_DOC), blk, 0, stream>>>(
                rpB, pB, S0, 1, d_out, OUT1_OFF, N_DOC, dflag);       // out1 = norm(A01@relu(S0))
        }
        // ---------------- type 2 (entities): A=A22 (10000), B=A02 (10000) ----------------
        {
            int* rpA = I; int* rpB = rpA + (N_ENT + 1); int* cur = rpB + (N_DOC + 1);
            int2* pA = (int2*)(cur + N_ENT + N_DOC); int2* pB = pA + E22;
            build2(stream, a22r, a22c, a22v, N_ENT, E22,
                   a02r, a02c, a02v, N_DOC, E02, rpA, rpB, cur, pA, pB, dflag);
            spmm_gather<false, 128><<<row_grid(N_ENT), blk, 0, stream>>>(
                rpA, pA, f2, DD, 1, E0, DD, 0, 1, N_ENT, dflag);      // E0 = A22@f2
            gemm_tile<true><<<(N_ENT + 63) / 64, 256, 0, stream>>>(
                E0, W2_2, b2_2, E1, N_ENT, dflag);                    // E1 = relu(E0)@W+b
            spmm_gather<false, 128><<<row_grid(N_ENT), blk, 0, stream>>>(
                rpA, pA, E1, DD, 1, E0, DD, 0, 1, N_ENT, dflag);      // E0 = A22@E1
            spmm2_norm<<<row_grid(N_DOC), blk, 0, stream>>>(
                rpB, pB, E0, 1, wemb, 1, d_out, OUT2_OFF, N_DOC, dflag); // out2 fused
        }
        // ---------------- type 3 (POS): A=A33 (60), B=A03 (10000) ----------------
        {
            int* rpA = I; int* rpB = rpA + (N_POS + 1); int* cur = rpB + (N_DOC + 1);
            int2* pA = (int2*)(cur + N_POS + N_DOC); int2* pB = pA + E33;
            build2(stream, a33r, a33c, a33v, N_POS, E33,
                   a03r, a03c, a03v, N_DOC, E03, rpA, rpB, cur, pA, pB, dflag);
            rowpar_gemm<false, 60><<<N_POS, 128, 0, stream>>>(
                f3, 1, W3, b3, P3a, 1, dflag);                        // P3a = f3@W3+b3
            spmm_gather<false, 128><<<row_grid(N_POS), blk, 0, stream>>>(
                rpA, pA, P3a, DD, 1, P3b, DD, 0, 1, N_POS, dflag);    // P3b = A33@P3a
            rowpar_gemm<true, 128><<<N_POS, 128, 0, stream>>>(
                P3b, 1, W3_2, b3_2, P3a, 1, dflag);                   // P3a = relu(P3b)@W+b
            spmm_gather<false, 128><<<row_grid(N_POS), blk, 0, stream>>>(
                rpA, pA, P3a, DD, 1, P3b, DD, 0, 1, N_POS, dflag);    // P3b = A33@P3a
            spmm_norm128<true><<<row_grid(N_DOC), blk, 0, stream>>>(
                rpB, pB, P3b, 1, d_out, OUT3_OFF, N_DOC, dflag);      // out3 = norm(A03@relu(P3b))
        }
    } else {
        // ================= fallback: atomic-scatter path (fp32 ws) =================
        hipMemsetAsync(S0, 0, (size_t)N_WORD * DD * 4, stream);
        spmm_kernel<false><<<spmm_grid(E11), blk, 0, stream>>>(
            a11r, a11c, a11v, f1, DD, 1, S0, DD, 0, DD, E11, dflag);
        gemm128_kernel<true><<<(N_WORD + 63) / 64, 256, 0, stream>>>(
            S0, W1_2, b1_2, S1, N_WORD, dflag);
        hipMemsetAsync(S0, 0, (size_t)N_WORD * DD * 4, stream);
        spmm_kernel<false><<<spmm_grid(E11), blk, 0, stream>>>(
            a11r, a11c, a11v, S1, DD, 0, S0, DD, 0, DD, E11, dflag);
        hipMemsetAsync(AGG1, 0, (size_t)N_DOC * DD * 4, stream);
        spmm_kernel<true><<<spmm_grid(E01), blk, 0, stream>>>(
            a01r, a01c, a01v, S0, DD, 0, AGG1, DD, 0, DD, E01, dflag);
        l2norm_kernel<<<row_grid(N_DOC), blk, 0, stream>>>(
            AGG1, DD, d_out, OUT1_OFF, N_DOC, dflag);

        hipMemsetAsync(E0, 0, (size_t)N_ENT * DD * 4, stream);
        spmm_kernel<false><<<spmm_grid(E22), blk, 0, stream>>>(
            a22r, a22c, a22v, f2, DD, 1, E0, DD, 0, DD, E22, dflag);
        gemm128_kernel<true><<<(N_ENT + 63) / 64, 256, 0, stream>>>(
            E0, W2_2, b2_2, E1, N_ENT, dflag);
        hipMemsetAsync(E0, 0, (size_t)N_ENT * DD * 4, stream);
        spmm_kernel<false><<<spmm_grid(E22), blk, 0, stream>>>(
            a22r, a22c, a22v, E1, DD, 0, E0, DD, 0, DD, E22, dflag);
        hipMemsetAsync(AGG2, 0, (size_t)N_DOC * (DD + D_WEMB) * 4, stream);
        spmm_kernel<true><<<spmm_grid(E02), blk, 0, stream>>>(
            a02r, a02c, a02v, E0, DD, 0, AGG2, DD + D_WEMB, 0, DD, E02, dflag);
        spmm_kernel<false><<<spmm_grid(E02), blk, 0, stream>>>(
            a02r, a02c, a02v, wemb, D_WEMB, 1, AGG2, DD + D_WEMB, DD, D_WEMB, E02, dflag);
        l2norm_kernel<<<row_grid(N_DOC), blk, 0, stream>>>(
            AGG2, DD + D_WEMB, d_out, OUT2_OFF, N_DOC, dflag);

        gemm_kernel<false, 60><<<1, 128, 0, stream>>>(f3, 1, W3, b3, P3a, N_POS, dflag);
        hipMemsetAsync(P3b, 0, (size_t)N_POS * DD * 4, stream);
        spmm_kernel<false><<<spmm_grid(E33), blk, 0, stream>>>(
            a33r, a33c, a33v, P3a, DD, 0, P3b, DD, 0, DD, E33, dflag);
        gemm128_kernel<true><<<1, 256, 0, stream>>>(
            P3b, W3_2, b3_2, P3a, N_POS, dflag);
        hipMemsetAsync(P3b, 0, (size_t)N_POS * DD * 4, stream);
        spmm_kernel<false><<<spmm_grid(E33), blk, 0, stream>>>(
            a33r, a33c, a33v, P3a, DD, 0, P3b, DD, 0, DD, E33, dflag);
        hipMemsetAsync(AGG3, 0, (size_t)N_DOC * DD * 4, stream);
        spmm_kernel<true><<<spmm_grid(E03), blk, 0, stream>>>(
            a03r, a03c, a03v, P3b, DD, 0, AGG3, DD, 0, DD, E03, dflag);
        l2norm_kernel<<<row_grid(N_DOC), blk, 0, stream>>>(
            AGG3, DD, d_out, OUT3_OFF, N_DOC, dflag);
    }
}

// Round 11
// 617.067 us; speedup vs baseline: 1.0599x; 1.0599x over previous
//
#include <hip/hip_runtime.h>
#include <hip/hip_bf16.h>

typedef __hip_bfloat16 bf16;

#define N_DOC   10000
#define N_WORD  20000
#define N_ENT   10000
#define N_POS   60
#define DD      128
#define D_WEMB  300
#define E11     320000
#define E22     160000
#define E33     3600
#define E01     300000
#define E02     100000
#define E03     150000

// Runtime dtype flag (ws[0]): 1 if float inputs are packed bf16, 0 if fp32.
// When flag==1, ws intermediates are ALSO stored bf16 (fp32 accumulate, bf16 store).
__device__ __forceinline__ float loadf(const void* p, size_t i, int isb) {
    return isb ? __bfloat162float(((const bf16*)p)[i])
               : ((const float*)p)[i];
}
__device__ __forceinline__ float b2f(unsigned u16) {
    union { unsigned v; float f; } x; x.v = u16 << 16; return x.f;
}
__device__ __forceinline__ unsigned f2b(float f) {
    bf16 h = __float2bfloat16(f);
    union { bf16 h; unsigned short u; } x; x.h = h; return (unsigned)x.u;
}
__device__ __forceinline__ void storef(void* p, size_t i, int asb, float v) {
    if (asb) ((unsigned short*)p)[i] = (unsigned short)f2b(v);
    else     ((float*)p)[i] = v;
}

// Detect input dtype from a randn fp32-or-bf16 buffer (see R2 notes).
__global__ void detect_kernel(const unsigned* __restrict__ probe, int* __restrict__ flag) {
    __shared__ int cnt;
    if (threadIdx.x == 0) cnt = 0;
    __syncthreads();
    int insane = 0;
    for (int i = threadIdx.x; i < 1024; i += 256) {
        float x = __uint_as_float(probe[i]);
        float a = fabsf(x);
        if (!(a > 1e-10f && a < 1e10f)) insane++;
    }
    atomicAdd(&cnt, insane);
    __syncthreads();
    if (threadIdx.x == 0) *flag = (cnt > 512) ? 1 : 0;
}

// ======================= fused 2-matrix CSR build =======================
__global__ void hist2_kernel(const int* __restrict__ rowsA, int nEA,
                             const int* __restrict__ rowsB, int nEB,
                             int nA, int* __restrict__ cnt) {
    int i = blockIdx.x * blockDim.x + threadIdx.x;
    if (i < nEA) atomicAdd(cnt + rowsA[i], 1);
    else if (i < nEA + nEB) atomicAdd(cnt + nA + rowsB[i - nEA], 1);
}

// Exclusive scan (1024 threads, wave shfl-scan + cross-wave LDS).
__device__ void scan_ex(const int* __restrict__ cnt, int* __restrict__ rp, int n) {
    __shared__ int wsum[16];
    __shared__ int carry;
    int t = threadIdx.x, lane = t & 63, w = t >> 6;
    if (t == 0) carry = 0;
    __syncthreads();
    for (int base = 0; base < n; base += 1024) {
        int i = base + t;
        int x = (i < n) ? cnt[i] : 0;
        int s = x;
        #pragma unroll
        for (int off = 1; off < 64; off <<= 1) {
            int y = __shfl_up(s, off);
            if (lane >= off) s += y;
        }
        if (lane == 63) wsum[w] = s;
        __syncthreads();
        if (w == 0) {
            int v = (lane < 16) ? wsum[lane] : 0;
            #pragma unroll
            for (int off = 1; off < 16; off <<= 1) {
                int y = __shfl_up(v, off);
                if (lane >= off) v += y;
            }
            if (lane < 16) wsum[lane] = v;
        }
        __syncthreads();
        int woff = (w > 0) ? wsum[w - 1] : 0;
        if (i < n) rp[i] = carry + woff + s - x;
        __syncthreads();
        if (t == 0) carry += wsum[15];
        __syncthreads();
    }
    if (t == 0) rp[n] = carry;
}

__global__ __launch_bounds__(1024) void scan2_kernel(
        const int* __restrict__ cntA, int* __restrict__ rpA, int nA,
        const int* __restrict__ cntB, int* __restrict__ rpB, int nB) {
    scan_ex(cntA, rpA, nA);
    __syncthreads();
    scan_ex(cntB, rpB, nB);
}

__global__ void copy2_kernel(const int* __restrict__ rpA, const int* __restrict__ rpB,
                             int nA, int nB, int* __restrict__ cur) {
    int i = blockIdx.x * blockDim.x + threadIdx.x;
    if (i < nA) cur[i] = rpA[i];
    else if (i < nA + nB) cur[i] = rpB[i - nA];
}

__global__ void scatter2_kernel(const int* __restrict__ rowsA, const int* __restrict__ colsA,
                                const void* __restrict__ valsA, int nEA,
                                const int* __restrict__ rowsB, const int* __restrict__ colsB,
                                const void* __restrict__ valsB, int nEB,
                                int nA, int* __restrict__ cur,
                                int2* __restrict__ pairsA, int2* __restrict__ pairsB,
                                const int* __restrict__ dflag) {
    int i = blockIdx.x * blockDim.x + threadIdx.x;
    int isb = *dflag;
    if (i < nEA) {
        int p = atomicAdd(cur + rowsA[i], 1);
        pairsA[p] = make_int2(colsA[i], __float_as_int(loadf(valsA, i, isb)));
    } else if (i < nEA + nEB) {
        int k = i - nEA;
        int p = atomicAdd(cur + nA + rowsB[k], 1);
        pairsB[p] = make_int2(colsB[k], __float_as_int(loadf(valsB, k, isb)));
    }
}

// ======================= gather SpMM (no atomics) =======================
// dst[row, 0..D) = sum_e vals[e] * act(src[cols[e], 0..D)); one wave/row.
// 2-edge unroll, dual accumulators. src/dst dtype follow *dflag when flagged.
template<bool RELU, int D>
__global__ void spmm_gather(const int* __restrict__ rowptr, const int2* __restrict__ pairs,
                            const void* __restrict__ src, int sstride, int src_flagged,
                            void* __restrict__ dst, int dstride, int doff, int dst_flagged,
                            int n, const int* __restrict__ dflag) {
    constexpr int PAIRS = D / 2;
    constexpr int NS = (PAIRS + 63) / 64;
    int row = blockIdx.x * (blockDim.x >> 6) + (threadIdx.x >> 6);
    if (row >= n) return;
    int isb  = *dflag;
    int sisb = src_flagged ? isb : 0;
    int disb = dst_flagged ? isb : 0;
    int lane = threadIdx.x & 63;
    int e0 = rowptr[row], e1 = rowptr[row + 1];
    float2 acc[NS], acc2[NS];
    #pragma unroll
    for (int s = 0; s < NS; ++s) { acc[s] = make_float2(0.f, 0.f); acc2[s] = make_float2(0.f, 0.f); }
    if (sisb) {
        int e = e0;
        for (; e + 2 <= e1; e += 2) {
            int2 p0 = pairs[e], p1 = pairs[e + 1];
            float v0 = __int_as_float(p0.y), v1 = __int_as_float(p1.y);
            const unsigned* s0 = (const unsigned*)((const bf16*)src + (size_t)p0.x * sstride);
            const unsigned* s1 = (const unsigned*)((const bf16*)src + (size_t)p1.x * sstride);
            #pragma unroll
            for (int s = 0; s < NS; ++s) {
                int pi = lane + 64 * s;
                if (pi < PAIRS) {
                    unsigned u0 = s0[pi], u1 = s1[pi];
                    float a0 = b2f(u0 & 0xffffu), a1 = b2f(u0 >> 16);
                    float c0 = b2f(u1 & 0xffffu), c1 = b2f(u1 >> 16);
                    if (RELU) { a0 = fmaxf(a0, 0.f); a1 = fmaxf(a1, 0.f);
                                c0 = fmaxf(c0, 0.f); c1 = fmaxf(c1, 0.f); }
                    acc[s].x  = fmaf(v0, a0, acc[s].x);
                    acc[s].y  = fmaf(v0, a1, acc[s].y);
                    acc2[s].x = fmaf(v1, c0, acc2[s].x);
                    acc2[s].y = fmaf(v1, c1, acc2[s].y);
                }
            }
        }
        if (e < e1) {
            int2 p = pairs[e];
            float v = __int_as_float(p.y);
            const unsigned* sp = (const unsigned*)((const bf16*)src + (size_t)p.x * sstride);
            #pragma unroll
            for (int s = 0; s < NS; ++s) {
                int pi = lane + 64 * s;
                if (pi < PAIRS) {
                    unsigned u = sp[pi];
                    float x0 = b2f(u & 0xffffu), x1 = b2f(u >> 16);
                    if (RELU) { x0 = fmaxf(x0, 0.f); x1 = fmaxf(x1, 0.f); }
                    acc[s].x = fmaf(v, x0, acc[s].x);
                    acc[s].y = fmaf(v, x1, acc[s].y);
                }
            }
        }
    } else {
        int e = e0;
        for (; e + 2 <= e1; e += 2) {
            int2 p0 = pairs[e], p1 = pairs[e + 1];
            float v0 = __int_as_float(p0.y), v1 = __int_as_float(p1.y);
            const float2* s0 = (const float2*)((const float*)src + (size_t)p0.x * sstride);
            const float2* s1 = (const float2*)((const float*)src + (size_t)p1.x * sstride);
            #pragma unroll
            for (int s = 0; s < NS; ++s) {
                int pi = lane + 64 * s;
                if (pi < PAIRS) {
                    float2 x = s0[pi], y = s1[pi];
                    if (RELU) { x.x = fmaxf(x.x, 0.f); x.y = fmaxf(x.y, 0.f);
                                y.x = fmaxf(y.x, 0.f); y.y = fmaxf(y.y, 0.f); }
                    acc[s].x  = fmaf(v0, x.x, acc[s].x);
                    acc[s].y  = fmaf(v0, x.y, acc[s].y);
                    acc2[s].x = fmaf(v1, y.x, acc2[s].x);
                    acc2[s].y = fmaf(v1, y.y, acc2[s].y);
                }
            }
        }
        if (e < e1) {
            int2 p = pairs[e];
            float v = __int_as_float(p.y);
            const float2* sp = (const float2*)((const float*)src + (size_t)p.x * sstride);
            #pragma unroll
            for (int s = 0; s < NS; ++s) {
                int pi = lane + 64 * s;
                if (pi < PAIRS) {
                    float2 x = sp[pi];
                    if (RELU) { x.x = fmaxf(x.x, 0.f); x.y = fmaxf(x.y, 0.f); }
                    acc[s].x = fmaf(v, x.x, acc[s].x);
                    acc[s].y = fmaf(v, x.y, acc[s].y);
                }
            }
        }
    }
    if (disb) {
        unsigned* dp = (unsigned*)((bf16*)dst + (size_t)row * dstride + doff);
        #pragma unroll
        for (int s = 0; s < NS; ++s) {
            int pi = lane + 64 * s;
            if (pi < PAIRS)
                dp[pi] = f2b(acc[s].x + acc2[s].x) | (f2b(acc[s].y + acc2[s].y) << 16);
        }
    } else {
        float2* dp = (float2*)((float*)dst + (size_t)row * dstride + doff);
        #pragma unroll
        for (int s = 0; s < NS; ++s) {
            int pi = lane + 64 * s;
            if (pi < PAIRS) dp[pi] = make_float2(acc[s].x + acc2[s].x, acc[s].y + acc2[s].y);
        }
    }
}

// ===== fused doc-agg + L2-norm, D=128: agg row held in regs, normed, stored to out =====
template<bool RELU>
__global__ void spmm_norm128(const int* __restrict__ rowptr, const int2* __restrict__ pairs,
                             const void* __restrict__ src, int src_flagged,
                             void* __restrict__ out, size_t elem_off,
                             int n, const int* __restrict__ dflag) {
    int row = blockIdx.x * (blockDim.x >> 6) + (threadIdx.x >> 6);
    if (row >= n) return;
    int isb  = *dflag;
    int sisb = src_flagged ? isb : 0;
    int lane = threadIdx.x & 63;
    int e0 = rowptr[row], e1 = rowptr[row + 1];
    float2 acc = make_float2(0.f, 0.f), acc2 = make_float2(0.f, 0.f);
    if (sisb) {
        int e = e0;
        for (; e + 2 <= e1; e += 2) {
            int2 p0 = pairs[e], p1 = pairs[e + 1];
            float v0 = __int_as_float(p0.y), v1 = __int_as_float(p1.y);
            unsigned u0 = ((const unsigned*)((const bf16*)src + (size_t)p0.x * DD))[lane];
            unsigned u1 = ((const unsigned*)((const bf16*)src + (size_t)p1.x * DD))[lane];
            float a0 = b2f(u0 & 0xffffu), a1 = b2f(u0 >> 16);
            float c0 = b2f(u1 & 0xffffu), c1 = b2f(u1 >> 16);
            if (RELU) { a0 = fmaxf(a0, 0.f); a1 = fmaxf(a1, 0.f);
                        c0 = fmaxf(c0, 0.f); c1 = fmaxf(c1, 0.f); }
            acc.x  = fmaf(v0, a0, acc.x);  acc.y  = fmaf(v0, a1, acc.y);
            acc2.x = fmaf(v1, c0, acc2.x); acc2.y = fmaf(v1, c1, acc2.y);
        }
        if (e < e1) {
            int2 p = pairs[e];
            float v = __int_as_float(p.y);
            unsigned u = ((const unsigned*)((const bf16*)src + (size_t)p.x * DD))[lane];
            float x0 = b2f(u & 0xffffu), x1 = b2f(u >> 16);
            if (RELU) { x0 = fmaxf(x0, 0.f); x1 = fmaxf(x1, 0.f); }
            acc.x = fmaf(v, x0, acc.x); acc.y = fmaf(v, x1, acc.y);
        }
    } else {
        int e = e0;
        for (; e + 2 <= e1; e += 2) {
            int2 p0 = pairs[e], p1 = pairs[e + 1];
            float v0 = __int_as_float(p0.y), v1 = __int_as_float(p1.y);
            float2 x = ((const float2*)((const float*)src + (size_t)p0.x * DD))[lane];
            float2 y = ((const float2*)((const float*)src + (size_t)p1.x * DD))[lane];
            if (RELU) { x.x = fmaxf(x.x, 0.f); x.y = fmaxf(x.y, 0.f);
                        y.x = fmaxf(y.x, 0.f); y.y = fmaxf(y.y, 0.f); }
            acc.x  = fmaf(v0, x.x, acc.x);  acc.y  = fmaf(v0, x.y, acc.y);
            acc2.x = fmaf(v1, y.x, acc2.x); acc2.y = fmaf(v1, y.y, acc2.y);
        }
        if (e < e1) {
            int2 p = pairs[e];
            float v = __int_as_float(p.y);
            float2 x = ((const float2*)((const float*)src + (size_t)p.x * DD))[lane];
            if (RELU) { x.x = fmaxf(x.x, 0.f); x.y = fmaxf(x.y, 0.f); }
            acc.x = fmaf(v, x.x, acc.x); acc.y = fmaf(v, x.y, acc.y);
        }
    }
    float tx = acc.x + acc2.x, ty = acc.y + acc2.y;
    float ss = tx * tx + ty * ty;
    #pragma unroll
    for (int off = 32; off > 0; off >>= 1) ss += __shfl_down(ss, off);
    ss = __shfl(ss, 0);
    float inv = 1.0f / (sqrtf(ss) + 1e-9f);
    size_t base = elem_off + (size_t)row * DD;
    if (isb) {
        ((unsigned*)((bf16*)out + base))[lane] = f2b(tx * inv) | (f2b(ty * inv) << 16);
    } else {
        ((float2*)((float*)out + base))[lane] = make_float2(tx * inv, ty * inv);
    }
}

// ===== fused type-2 doc-agg (A02@relu(E0) ++ A02@wemb) + L2-norm over 428 cols =====
__global__ void spmm2_norm(const int* __restrict__ rowptr, const int2* __restrict__ pairs,
                           const void* __restrict__ src1, int s1_flagged,
                           const void* __restrict__ src2, int s2_flagged,
                           void* __restrict__ out, size_t elem_off,
                           int n, const int* __restrict__ dflag) {
    constexpr int P2 = D_WEMB / 2;   // 150
    int row = blockIdx.x * (blockDim.x >> 6) + (threadIdx.x >> 6);
    if (row >= n) return;
    int isb = *dflag;
    int s1b = s1_flagged ? isb : 0;
    int s2b = s2_flagged ? isb : 0;
    int lane = threadIdx.x & 63;
    int e0 = rowptr[row], e1 = rowptr[row + 1];
    float2 a1 = make_float2(0.f, 0.f);
    float2 a2[3];
    #pragma unroll
    for (int s = 0; s < 3; ++s) a2[s] = make_float2(0.f, 0.f);
    for (int e = e0; e < e1; ++e) {
        int2 p = pairs[e];
        float v = __int_as_float(p.y);
        float x0, x1;
        if (s1b) {
            unsigned u = ((const unsigned*)((const bf16*)src1 + (size_t)p.x * DD))[lane];
            x0 = b2f(u & 0xffffu); x1 = b2f(u >> 16);
        } else {
            float2 x = ((const float2*)((const float*)src1 + (size_t)p.x * DD))[lane];
            x0 = x.x; x1 = x.y;
        }
        x0 = fmaxf(x0, 0.f); x1 = fmaxf(x1, 0.f);
        a1.x = fmaf(v, x0, a1.x); a1.y = fmaf(v, x1, a1.y);
        if (s2b) {
            const unsigned* sp = (const unsigned*)((const bf16*)src2 + (size_t)p.x * D_WEMB);
            #pragma unroll
            for (int s = 0; s < 3; ++s) {
                int pi = lane + 64 * s;
                if (pi < P2) {
                    unsigned u = sp[pi];
                    a2[s].x = fmaf(v, b2f(u & 0xffffu), a2[s].x);
                    a2[s].y = fmaf(v, b2f(u >> 16),     a2[s].y);
                }
            }
        } else {
            const float2* sp = (const float2*)((const float*)src2 + (size_t)p.x * D_WEMB);
            #pragma unroll
            for (int s = 0; s < 3; ++s) {
                int pi = lane + 64 * s;
                if (pi < P2) {
                    float2 x = sp[pi];
                    a2[s].x = fmaf(v, x.x, a2[s].x);
                    a2[s].y = fmaf(v, x.y, a2[s].y);
                }
            }
        }
    }
    float ss = a1.x * a1.x + a1.y * a1.y;
    #pragma unroll
    for (int s = 0; s < 3; ++s) {
        int pi = lane + 64 * s;
        if (pi < P2) ss += a2[s].x * a2[s].x + a2[s].y * a2[s].y;
    }
    #pragma unroll
    for (int off = 32; off > 0; off >>= 1) ss += __shfl_down(ss, off);
    ss = __shfl(ss, 0);
    float inv = 1.0f / (sqrtf(ss) + 1e-9f);
    size_t base = elem_off + (size_t)row * (DD + D_WEMB);
    if (isb) {
        ((unsigned*)((bf16*)out + base))[lane] = f2b(a1.x * inv) | (f2b(a1.y * inv) << 16);
        unsigned* o2 = (unsigned*)((bf16*)out + base + DD);
        #pragma unroll
        for (int s = 0; s < 3; ++s) {
            int pi = lane + 64 * s;
            if (pi < P2) o2[pi] = f2b(a2[s].x * inv) | (f2b(a2[s].y * inv) << 16);
        }
    } else {
        ((float2*)((float*)out + base))[lane] = make_float2(a1.x * inv, a1.y * inv);
        float2* o2 = (float2*)((float*)out + base + DD);
        #pragma unroll
        for (int s = 0; s < 3; ++s) {
            int pi = lane + 64 * s;
            if (pi < P2) o2[pi] = make_float2(a2[s].x * inv, a2[s].y * inv);
        }
    }
}

// ======================= atomic SpMM (ws_size fallback only) =======================
template<bool RELU>
__global__ void spmm_kernel(const int* __restrict__ rows, const int* __restrict__ cols,
                            const void* __restrict__ vals,
                            const void* __restrict__ src, int sstride, int src_flagged,
                            float* __restrict__ dst, int dstride, int doff,
                            int d, int nE, const int* __restrict__ dflag) {
    int e = blockIdx.x * (blockDim.x >> 6) + (threadIdx.x >> 6);
    if (e >= nE) return;
    int isb  = *dflag;
    int sisb = src_flagged ? isb : 0;
    int lane = threadIdx.x & 63;
    int r = rows[e];
    int c = cols[e];
    float v = loadf(vals, e, isb);
    size_t sbase = (size_t)c * sstride;
    float* dp = dst + (size_t)r * dstride + doff;
    if (sisb) {
        const unsigned* sp = (const unsigned*)((const bf16*)src + sbase);
        for (int j = 2 * lane; j < d; j += 128) {
            unsigned u = sp[j >> 1];
            float x0 = b2f(u & 0xffffu);
            float x1 = b2f(u >> 16);
            if (RELU) { x0 = fmaxf(x0, 0.f); x1 = fmaxf(x1, 0.f); }
            atomicAdd(dp + j,     v * x0);
            atomicAdd(dp + j + 1, v * x1);
        }
    } else {
        const float2* sp = (const float2*)((const float*)src + sbase);
        for (int j = 2 * lane; j < d; j += 128) {
            float2 x = sp[j >> 1];
            if (RELU) { x.x = fmaxf(x.x, 0.f); x.y = fmaxf(x.y, 0.f); }
            atomicAdd(dp + j,     v * x.x);
            atomicAdd(dp + j + 1, v * x.y);
        }
    }
}

// ======================= dense GEMMs =======================
// out[n x 128] = act(X[n x 128]) @ W[128 x 128] + b.
// 32-col W tile in 16 KB LDS; 2-D grid (row tiles PADDED to mult of 8, 4 col tiles).
// With gridDim.x % 8 == 0, the 4 col-tile blocks of a row tile have linear ids
// congruent mod 8 -> same XCD (round-robin dispatch) -> X served once from HBM,
// 3x from that XCD's L2, and the four 64 B write chunks/row merge into full lines.
template<bool RELU>
__global__ __launch_bounds__(256) void gemm_tile(
        const void* __restrict__ X, const void* __restrict__ W,
        const void* __restrict__ b, void* __restrict__ out, int n,
        const int* __restrict__ dflag) {
    __shared__ float Wl[128 * 32];
    if (blockIdx.x * 64 >= n) return;             // pad block (uniform exit, pre-barrier)
    int isb = *dflag;
    int tid = threadIdx.x;
    int jc = blockIdx.y * 32;
    if (isb) {
        const uint2* Wg = (const uint2*)W;        // 4 bf16 per uint2, row = 32 uint2
        float4* Wl4 = (float4*)Wl;
        for (int vidx = tid; vidx < 1024; vidx += 256) {
            int k = vidx >> 3, jl4 = vidx & 7;
            uint2 u = Wg[k * 32 + (jc >> 2) + jl4];
            float4 vv;
            vv.x = b2f(u.x & 0xffffu);
            vv.y = b2f(u.x >> 16);
            vv.z = b2f(u.y & 0xffffu);
            vv.w = b2f(u.y >> 16);
            Wl4[vidx] = vv;
        }
    } else {
        const float4* Wg = (const float4*)W;      // row = 32 float4
        float4* Wl4 = (float4*)Wl;
        for (int vidx = tid; vidx < 1024; vidx += 256) {
            int k = vidx >> 3, jl4 = vidx & 7;
            Wl4[vidx] = Wg[k * 32 + (jc >> 2) + jl4];
        }
    }
    __syncthreads();
    int j = tid & 31;
    int g = tid >> 5;
    float bj = loadf(b, jc + j, isb);
    int i0 = blockIdx.x * 64 + g * 8;
    float a[8];
    #pragma unroll
    for (int r = 0; r < 8; ++r) a[r] = bj;
    if (isb) {
        const uint2* xp = (const uint2*)((const bf16*)X + (size_t)i0 * 128);
        #pragma unroll 2
        for (int k4 = 0; k4 < 32; ++k4) {
            float w0 = Wl[(4 * k4 + 0) * 32 + j];
            float w1 = Wl[(4 * k4 + 1) * 32 + j];
            float w2 = Wl[(4 * k4 + 2) * 32 + j];
            float w3 = Wl[(4 * k4 + 3) * 32 + j];
            #pragma unroll
            for (int r = 0; r < 8; ++r) {
                uint2 u = xp[r * 32 + k4];
                float vx = b2f(u.x & 0xffffu), vy = b2f(u.x >> 16);
                float vz = b2f(u.y & 0xffffu), vw = b2f(u.y >> 16);
                if (RELU) {
                    vx = fmaxf(vx, 0.f); vy = fmaxf(vy, 0.f);
                    vz = fmaxf(vz, 0.f); vw = fmaxf(vw, 0.f);
                }
                a[r] = fmaf(vw, w3, fmaf(vz, w2, fmaf(vy, w1, fmaf(vx, w0, a[r]))));
            }
        }
    } else {
        const float4* xp = (const float4*)((const float*)X + (size_t)i0 * 128);
        #pragma unroll 2
        for (int k4 = 0; k4 < 32; ++k4) {
            float w0 = Wl[(4 * k4 + 0) * 32 + j];
            float w1 = Wl[(4 * k4 + 1) * 32 + j];
            float w2 = Wl[(4 * k4 + 2) * 32 + j];
            float w3 = Wl[(4 * k4 + 3) * 32 + j];
            #pragma unroll
            for (int r = 0; r < 8; ++r) {
                float4 v = xp[r * 32 + k4];
                if (RELU) {
                    v.x = fmaxf(v.x, 0.f); v.y = fmaxf(v.y, 0.f);
                    v.z = fmaxf(v.z, 0.f); v.w = fmaxf(v.w, 0.f);
                }
                a[r] = fmaf(v.w, w3, fmaf(v.z, w2, fmaf(v.y, w1, fmaf(v.x, w0, a[r]))));
            }
        }
    }
    #pragma unroll
    for (int r = 0; r < 8; ++r) {
        int i = i0 + r;
        if (i < n) storef(out, (size_t)i * 128 + jc + j, isb, a[r]);
    }
}

// Legacy big-LDS GEMM (fallback path only; fp32 ws).
template<bool RELU>
__global__ __launch_bounds__(256) void gemm128_kernel(
        const float* __restrict__ X, const void* __restrict__ W,
        const void* __restrict__ b, float* __restrict__ out, int n,
        const int* __restrict__ dflag) {
    __shared__ float Wl[128 * 128];
    int isb = *dflag;
    int tid = threadIdx.x;
    if (isb) {
        const uint2* Wg = (const uint2*)W;
        float4* Wl4 = (float4*)Wl;
        for (int idx = tid; idx < 4096; idx += 256) {
            uint2 u = Wg[idx];
            float4 vv;
            vv.x = b2f(u.x & 0xffffu);
            vv.y = b2f(u.x >> 16);
            vv.z = b2f(u.y & 0xffffu);
            vv.w = b2f(u.y >> 16);
            Wl4[idx] = vv;
        }
    } else {
        const float4* Wg = (const float4*)W;
        float4* Wl4 = (float4*)Wl;
        for (int idx = tid; idx < 4096; idx += 256) Wl4[idx] = Wg[idx];
    }
    __syncthreads();
    int j = tid & 127;
    int h = tid >> 7;
    float bj = loadf(b, j, isb);
    int row0 = blockIdx.x * 64 + h * 32;
    for (int q = 0; q < 8; ++q) {
        int gi = row0 + q * 4;
        if (gi >= n) break;
        const float4* x0 = (const float4*)(X + (size_t)gi * 128);
        const float4* x1 = x0 + 32;
        const float4* x2 = x1 + 32;
        const float4* x3 = x2 + 32;
        float a0 = bj, a1 = bj, a2 = bj, a3 = bj;
        #pragma unroll 4
        for (int k4 = 0; k4 < 32; ++k4) {
            float4 v0 = x0[k4], v1 = x1[k4], v2 = x2[k4], v3 = x3[k4];
            if (RELU) {
                v0.x = fmaxf(v0.x, 0.f); v0.y = fmaxf(v0.y, 0.f); v0.z = fmaxf(v0.z, 0.f); v0.w = fmaxf(v0.w, 0.f);
                v1.x = fmaxf(v1.x, 0.f); v1.y = fmaxf(v1.y, 0.f); v1.z = fmaxf(v1.z, 0.f); v1.w = fmaxf(v1.w, 0.f);
                v2.x = fmaxf(v2.x, 0.f); v2.y = fmaxf(v2.y, 0.f); v2.z = fmaxf(v2.z, 0.f); v2.w = fmaxf(v2.w, 0.f);
                v3.x = fmaxf(v3.x, 0.f); v3.y = fmaxf(v3.y, 0.f); v3.z = fmaxf(v3.z, 0.f); v3.w = fmaxf(v3.w, 0.f);
            }
            float w0 = Wl[(4 * k4 + 0) * 128 + j];
            float w1 = Wl[(4 * k4 + 1) * 128 + j];
            float w2 = Wl[(4 * k4 + 2) * 128 + j];
            float w3 = Wl[(4 * k4 + 3) * 128 + j];
            a0 = fmaf(v0.w, w3, fmaf(v0.z, w2, fmaf(v0.y, w1, fmaf(v0.x, w0, a0))));
            a1 = fmaf(v1.w, w3, fmaf(v1.z, w2, fmaf(v1.y, w1, fmaf(v1.x, w0, a1))));
            a2 = fmaf(v2.w, w3, fmaf(v2.z, w2, fmaf(v2.y, w1, fmaf(v2.x, w0, a2))));
            a3 = fmaf(v3.w, w3, fmaf(v3.z, w2, fmaf(v3.y, w1, fmaf(v3.x, w0, a3))));
        }
        float* o = out + (size_t)gi * 128 + j;
        o[0] = a0; o[128] = a1; o[256] = a2; o[384] = a3;
    }
}

// Row-parallel tiny GEMM (type-3, n=60): one block per row, 128 threads.
template<bool RELU, int K>
__global__ void rowpar_gemm(const void* __restrict__ X, int x_flagged,
                            const void* __restrict__ W, const void* __restrict__ b,
                            void* __restrict__ out, int out_flagged,
                            const int* __restrict__ dflag) {
    __shared__ float xr[K];
    int isb  = *dflag;
    int xisb = x_flagged ? isb : 0;
    int oisb = out_flagged ? isb : 0;
    int row = blockIdx.x;
    int j = threadIdx.x;
    if (j < K) {
        float x = loadf(X, (size_t)row * K + j, xisb);
        if (RELU) x = fmaxf(x, 0.f);
        xr[j] = x;
    }
    __syncthreads();
    float acc = loadf(b, j, isb);
    #pragma unroll 8
    for (int k = 0; k < K; ++k)
        acc = fmaf(xr[k], loadf(W, (size_t)k * 128 + j, isb), acc);
    storef(out, (size_t)row * 128 + j, oisb, acc);
}

// Generic small GEMM (fallback path only).
template<bool RELU, int K>
__global__ void gemm_kernel(const void* __restrict__ X, int x_flagged,
                            const void* __restrict__ W,
                            const void* __restrict__ b,
                            float* __restrict__ out, int n,
                            const int* __restrict__ dflag) {
    __shared__ float Wl[K * 128];
    int isb  = *dflag;
    int xisb = x_flagged ? isb : 0;
    int j = threadIdx.x;
    for (int idx = j; idx < K * 128; idx += 128)
        Wl[idx] = loadf(W, idx, isb);
    __syncthreads();
    float bj = loadf(b, j, isb);
    int row0 = blockIdx.x * 64;
    for (int i0 = 0; i0 < 64; i0 += 4) {
        int i = row0 + i0;
        if (i >= n) break;
        size_t r0 = (size_t)i * K;
        float a0 = bj, a1 = bj, a2 = bj, a3 = bj;
        for (int k = 0; k < K; ++k) {
            float w = Wl[k * 128 + j];
            float v0 = loadf(X, r0 + k, xisb);
            float v1 = loadf(X, r0 + K + k, xisb);
            float v2 = loadf(X, r0 + 2 * K + k, xisb);
            float v3 = loadf(X, r0 + 3 * K + k, xisb);
            if (RELU) {
                v0 = fmaxf(v0, 0.f); v1 = fmaxf(v1, 0.f);
                v2 = fmaxf(v2, 0.f); v3 = fmaxf(v3, 0.f);
            }
            a0 = fmaf(v0, w, a0);
            a1 = fmaf(v1, w, a1);
            a2 = fmaf(v2, w, a2);
            a3 = fmaf(v3, w, a3);
        }
        float* o = out + (size_t)i * 128 + j;
        o[0] = a0; o[128] = a1; o[256] = a2; o[384] = a3;
    }
}

// L2-norm (fallback path only).
__global__ void l2norm_kernel(const float* __restrict__ agg, int d,
                              void* __restrict__ out, size_t elem_off, int n,
                              const int* __restrict__ dflag) {
    int row = blockIdx.x * (blockDim.x >> 6) + (threadIdx.x >> 6);
    if (row >= n) return;
    int isb  = *dflag;
    int lane = threadIdx.x & 63;
    const float2* a2 = (const float2*)(agg + (size_t)row * d);
    float ss = 0.f;
    for (int j = 2 * lane; j < d; j += 128) {
        float2 x = a2[j >> 1];
        ss += x.x * x.x + x.y * x.y;
    }
    #pragma unroll
    for (int off = 32; off > 0; off >>= 1) ss += __shfl_down(ss, off);
    ss = __shfl(ss, 0);
    float inv = 1.0f / (sqrtf(ss) + 1e-9f);
    size_t bbase = elem_off + (size_t)row * d;
    if (isb) {
        unsigned* o = (unsigned*)((bf16*)out + bbase);
        for (int j = 2 * lane; j < d; j += 128) {
            float2 x = a2[j >> 1];
            o[j >> 1] = f2b(x.x * inv) | (f2b(x.y * inv) << 16);
        }
    } else {
        float2* o = (float2*)((float*)out + bbase);
        for (int j = 2 * lane; j < d; j += 128) {
            float2 x = a2[j >> 1];
            o[j >> 1] = make_float2(x.x * inv, x.y * inv);
        }
    }
}

static inline int spmm_grid(int nE) { return (nE + 3) / 4; }
static inline int row_grid(int n)   { return (n + 3) / 4; }
static inline int pad8(int x)       { return (x + 7) & ~7; }

// Fused per-phase CSR build for two matrices A,B sharing one cursor block.
static void build2(hipStream_t stream,
                   const int* rowsA, const int* colsA, const void* valsA, int nA, int nEA,
                   const int* rowsB, const int* colsB, const void* valsB, int nB, int nEB,
                   int* rpA, int* rpB, int* curAB, int2* pairsA, int2* pairsB,
                   const int* dflag) {
    int nE = nEA + nEB;
    hipMemsetAsync(curAB, 0, (size_t)(nA + nB) * 4, stream);
    hist2_kernel<<<(nE + 255) / 256, 256, 0, stream>>>(rowsA, nEA, rowsB, nEB, nA, curAB);
    scan2_kernel<<<1, 1024, 0, stream>>>(curAB, rpA, nA, curAB + nA, rpB, nB);
    copy2_kernel<<<(nA + nB + 255) / 256, 256, 0, stream>>>(rpA, rpB, nA, nB, curAB);
    scatter2_kernel<<<(nE + 255) / 256, 256, 0, stream>>>(
        rowsA, colsA, valsA, nEA, rowsB, colsB, valsB, nEB, nA, curAB, pairsA, pairsB, dflag);
}

extern "C" void kernel_launch(void* const* d_in, const int* in_sizes, int n_in,
                              void* d_out, int out_size, void* d_ws, size_t ws_size,
                              hipStream_t stream) {
    const void* f1   = d_in[0];
    const void* f2   = d_in[1];
    const void* f3   = d_in[2];
    const void* wemb = d_in[3];
    const int*  a11r = (const int*)d_in[4];
    const int*  a11c = (const int*)d_in[5];
    const void* a11v = d_in[6];
    const int*  a22r = (const int*)d_in[7];
    const int*  a22c = (const int*)d_in[8];
    const void* a22v = d_in[9];
    const int*  a33r = (const int*)d_in[10];
    const int*  a33c = (const int*)d_in[11];
    const void* a33v = d_in[12];
    const int*  a01r = (const int*)d_in[13];
    const int*  a01c = (const int*)d_in[14];
    const void* a01v = d_in[15];
    const int*  a02r = (const int*)d_in[16];
    const int*  a02c = (const int*)d_in[17];
    const void* a02v = d_in[18];
    const int*  a03r = (const int*)d_in[19];
    const int*  a03c = (const int*)d_in[20];
    const void* a03v = d_in[21];
    const void* W3   = d_in[22];
    const void* b3   = d_in[23];
    const void* W1_2 = d_in[24];
    const void* b1_2 = d_in[25];
    const void* W2_2 = d_in[26];
    const void* b2_2 = d_in[27];
    const void* W3_2 = d_in[28];
    const void* b3_2 = d_in[29];

    int*   dflag = (int*)d_ws;
    float* base  = (float*)d_ws + 16;       // buffers start 64 B in (sized for fp32 worst case)
    float* S0   = base;                     // 20000*128
    float* S1   = base + 2560000;           // 20000*128
    float* AGG1 = S1;                       // fallback only
    float* E0   = base;                     // 10000*128
    float* E1   = base + 1280000;           // 10000*128
    float* AGG2 = base + 1280000;           // fallback only
    float* P3a  = base;                     // 60*128
    float* P3b  = base + 7680;              // 60*128
    float* AGG3 = base + 15360;             // fallback only

    // CSR region after dense peak: [rpA | rpB | curAB | pairsA | pairsB]
    int* I = (int*)(base + 5560000);
    const size_t WS_NEEDED = 64 + 22240000ull + 240008ull + 4960000ull; // ~27.44 MB

    const size_t OUT1_OFF = 0;
    const size_t OUT2_OFF = (size_t)N_DOC * DD;                       // 1,280,000
    const size_t OUT3_OFF = OUT2_OFF + (size_t)N_DOC * (DD + D_WEMB); // 5,560,000

    dim3 blk(256);
    detect_kernel<<<1, 256, 0, stream>>>((const unsigned*)f1, dflag);

    if (ws_size >= WS_NEEDED) {
        // ================= CSR gather path (bf16 intermediates when isb) =================
        // ---------------- type 1 (words): A=A11 (20000), B=A01 (10000) ----------------
        {
            int* rpA = I; int* rpB = rpA + (N_WORD + 1); int* cur = rpB + (N_DOC + 1);
            int2* pA = (int2*)(cur + N_WORD + N_DOC); int2* pB = pA + E11;
            build2(stream, a11r, a11c, a11v, N_WORD, E11,
                   a01r, a01c, a01v, N_DOC, E01, rpA, rpB, cur, pA, pB, dflag);
            spmm_gather<false, 128><<<row_grid(N_WORD), blk, 0, stream>>>(
                rpA, pA, f1, DD, 1, S0, DD, 0, 1, N_WORD, dflag);     // S0 = A11@f1
            gemm_tile<true><<<dim3(pad8((N_WORD + 63) / 64), 4), 256, 0, stream>>>(
                S0, W1_2, b1_2, S1, N_WORD, dflag);                   // S1 = relu(S0)@W+b
            spmm_gather<false, 128><<<row_grid(N_WORD), blk, 0, stream>>>(
                rpA, pA, S1, DD, 1, S0, DD, 0, 1, N_WORD, dflag);     // S0 = A11@S1
            spmm_norm128<true><<<row_grid(N_DOC), blk, 0, stream>>>(
                rpB, pB, S0, 1, d_out, OUT1_OFF, N_DOC, dflag);       // out1 = norm(A01@relu(S0))
        }
        // ---------------- type 2 (entities): A=A22 (10000), B=A02 (10000) ----------------
        {
            int* rpA = I; int* rpB = rpA + (N_ENT + 1); int* cur = rpB + (N_DOC + 1);
            int2* pA = (int2*)(cur + N_ENT + N_DOC); int2* pB = pA + E22;
            build2(stream, a22r, a22c, a22v, N_ENT, E22,
                   a02r, a02c, a02v, N_DOC, E02, rpA, rpB, cur, pA, pB, dflag);
            spmm_gather<false, 128><<<row_grid(N_ENT), blk, 0, stream>>>(
                rpA, pA, f2, DD, 1, E0, DD, 0, 1, N_ENT, dflag);      // E0 = A22@f2
            gemm_tile<true><<<dim3(pad8((N_ENT + 63) / 64), 4), 256, 0, stream>>>(
                E0, W2_2, b2_2, E1, N_ENT, dflag);                    // E1 = relu(E0)@W+b
            spmm_gather<false, 128><<<row_grid(N_ENT), blk, 0, stream>>>(
                rpA, pA, E1, DD, 1, E0, DD, 0, 1, N_ENT, dflag);      // E0 = A22@E1
            spmm2_norm<<<row_grid(N_DOC), blk, 0, stream>>>(
                rpB, pB, E0, 1, wemb, 1, d_out, OUT2_OFF, N_DOC, dflag); // out2 fused
        }
        // ---------------- type 3 (POS): A=A33 (60), B=A03 (10000) ----------------
        {
            int* rpA = I; int* rpB = rpA + (N_POS + 1); int* cur = rpB + (N_DOC + 1);
            int2* pA = (int2*)(cur + N_POS + N_DOC); int2* pB = pA + E33;
            build2(stream, a33r, a33c, a33v, N_POS, E33,
                   a03r, a03c, a03v, N_DOC, E03, rpA, rpB, cur, pA, pB, dflag);
            rowpar_gemm<false, 60><<<N_POS, 128, 0, stream>>>(
                f3, 1, W3, b3, P3a, 1, dflag);                        // P3a = f3@W3+b3
            spmm_gather<false, 128><<<row_grid(N_POS), blk, 0, stream>>>(
                rpA, pA, P3a, DD, 1, P3b, DD, 0, 1, N_POS, dflag);    // P3b = A33@P3a
            rowpar_gemm<true, 128><<<N_POS, 128, 0, stream>>>(
                P3b, 1, W3_2, b3_2, P3a, 1, dflag);                   // P3a = relu(P3b)@W+b
            spmm_gather<false, 128><<<row_grid(N_POS), blk, 0, stream>>>(
                rpA, pA, P3a, DD, 1, P3b, DD, 0, 1, N_POS, dflag);    // P3b = A33@P3a
            spmm_norm128<true><<<row_grid(N_DOC), blk, 0, stream>>>(
                rpB, pB, P3b, 1, d_out, OUT3_OFF, N_DOC, dflag);      // out3 = norm(A03@relu(P3b))
        }
    } else {
        // ================= fallback: atomic-scatter path (fp32 ws) =================
        hipMemsetAsync(S0, 0, (size_t)N_WORD * DD * 4, stream);
        spmm_kernel<false><<<spmm_grid(E11), blk, 0, stream>>>(
            a11r, a11c, a11v, f1, DD, 1, S0, DD, 0, DD, E11, dflag);
        gemm128_kernel<true><<<(N_WORD + 63) / 64, 256, 0, stream>>>(
            S0, W1_2, b1_2, S1, N_WORD, dflag);
        hipMemsetAsync(S0, 0, (size_t)N_WORD * DD * 4, stream);
        spmm_kernel<false><<<spmm_grid(E11), blk, 0, stream>>>(
            a11r, a11c, a11v, S1, DD, 0, S0, DD, 0, DD, E11, dflag);
        hipMemsetAsync(AGG1, 0, (size_t)N_DOC * DD * 4, stream);
        spmm_kernel<true><<<spmm_grid(E01), blk, 0, stream>>>(
            a01r, a01c, a01v, S0, DD, 0, AGG1, DD, 0, DD, E01, dflag);
        l2norm_kernel<<<row_grid(N_DOC), blk, 0, stream>>>(
            AGG1, DD, d_out, OUT1_OFF, N_DOC, dflag);

        hipMemsetAsync(E0, 0, (size_t)N_ENT * DD * 4, stream);
        spmm_kernel<false><<<spmm_grid(E22), blk, 0, stream>>>(
            a22r, a22c, a22v, f2, DD, 1, E0, DD, 0, DD, E22, dflag);
        gemm128_kernel<true><<<(N_ENT + 63) / 64, 256, 0, stream>>>(
            E0, W2_2, b2_2, E1, N_ENT, dflag);
        hipMemsetAsync(E0, 0, (size_t)N_ENT * DD * 4, stream);
        spmm_kernel<false><<<spmm_grid(E22), blk, 0, stream>>>(
            a22r, a22c, a22v, E1, DD, 0, E0, DD, 0, DD, E22, dflag);
        hipMemsetAsync(AGG2, 0, (size_t)N_DOC * (DD + D_WEMB) * 4, stream);
        spmm_kernel<true><<<spmm_grid(E02), blk, 0, stream>>>(
            a02r, a02c, a02v, E0, DD, 0, AGG2, DD + D_WEMB, 0, DD, E02, dflag);
        spmm_kernel<false><<<spmm_grid(E02), blk, 0, stream>>>(
            a02r, a02c, a02v, wemb, D_WEMB, 1, AGG2, DD + D_WEMB, DD, D_WEMB, E02, dflag);
        l2norm_kernel<<<row_grid(N_DOC), blk, 0, stream>>>(
            AGG2, DD + D_WEMB, d_out, OUT2_OFF, N_DOC, dflag);

        gemm_kernel<false, 60><<<1, 128, 0, stream>>>(f3, 1, W3, b3, P3a, N_POS, dflag);
        hipMemsetAsync(P3b, 0, (size_t)N_POS * DD * 4, stream);
        spmm_kernel<false><<<spmm_grid(E33), blk, 0, stream>>>(
            a33r, a33c, a33v, P3a, DD, 0, P3b, DD, 0, DD, E33, dflag);
        gemm128_kernel<true><<<1, 256, 0, stream>>>(
            P3b, W3_2, b3_2, P3a, N_POS, dflag);
        hipMemsetAsync(P3b, 0, (size_t)N_POS * DD * 4, stream);
        spmm_kernel<false><<<spmm_grid(E33), blk, 0, stream>>>(
            a33r, a33c, a33v, P3a, DD, 0, P3b, DD, 0, DD, E33, dflag);
        hipMemsetAsync(AGG3, 0, (size_t)N_DOC * DD * 4, stream);
        spmm_kernel<true><<<spmm_grid(E03), blk, 0, stream>>>(
            a03r, a03c, a03v, P3b, DD, 0, AGG3, DD, 0, DD, E03, dflag);
        l2norm_kernel<<<row_grid(N_DOC), blk, 0, stream>>>(
            AGG3, DD, d_out, OUT3_OFF, N_DOC, dflag);
    }
}

// Round 12
// 587.517 us; speedup vs baseline: 1.1132x; 1.0503x over previous
//
#include <hip/hip_runtime.h>
#include <hip/hip_bf16.h>

typedef __hip_bfloat16 bf16;

#define N_DOC   10000
#define N_WORD  20000
#define N_ENT   10000
#define N_POS   60
#define DD      128
#define D_WEMB  300
#define E11     320000
#define E22     160000
#define E33     3600
#define E01     300000
#define E02     100000
#define E03     150000

// Runtime dtype flag (ws[0]): 1 if float inputs are packed bf16, 0 if fp32.
__device__ __forceinline__ float loadf(const void* p, size_t i, int isb) {
    return isb ? __bfloat162float(((const bf16*)p)[i])
               : ((const float*)p)[i];
}
__device__ __forceinline__ float b2f(unsigned u16) {
    union { unsigned v; float f; } x; x.v = u16 << 16; return x.f;
}
__device__ __forceinline__ unsigned f2b(float f) {
    bf16 h = __float2bfloat16(f);
    union { bf16 h; unsigned short u; } x; x.h = h; return (unsigned)x.u;
}
__device__ __forceinline__ void storef(void* p, size_t i, int asb, float v) {
    if (asb) ((unsigned short*)p)[i] = (unsigned short)f2b(v);
    else     ((float*)p)[i] = v;
}

// Detect input dtype from a randn fp32-or-bf16 buffer (see R2 notes).
__global__ void detect_kernel(const unsigned* __restrict__ probe, int* __restrict__ flag) {
    __shared__ int cnt;
    if (threadIdx.x == 0) cnt = 0;
    __syncthreads();
    int insane = 0;
    for (int i = threadIdx.x; i < 1024; i += 256) {
        float x = __uint_as_float(probe[i]);
        float a = fabsf(x);
        if (!(a > 1e-10f && a < 1e10f)) insane++;
    }
    atomicAdd(&cnt, insane);
    __syncthreads();
    if (threadIdx.x == 0) *flag = (cnt > 512) ? 1 : 0;
}

// ======================= fused 2-matrix CSR build =======================
__global__ void hist2_kernel(const int* __restrict__ rowsA, int nEA,
                             const int* __restrict__ rowsB, int nEB,
                             int nA, int* __restrict__ cnt) {
    int i = blockIdx.x * blockDim.x + threadIdx.x;
    if (i < nEA) atomicAdd(cnt + rowsA[i], 1);
    else if (i < nEA + nEB) atomicAdd(cnt + nA + rowsB[i - nEA], 1);
}

// Exclusive scan (1024 threads, wave shfl-scan + cross-wave LDS).
__device__ void scan_ex(const int* __restrict__ cnt, int* __restrict__ rp, int n) {
    __shared__ int wsum[16];
    __shared__ int carry;
    int t = threadIdx.x, lane = t & 63, w = t >> 6;
    if (t == 0) carry = 0;
    __syncthreads();
    for (int base = 0; base < n; base += 1024) {
        int i = base + t;
        int x = (i < n) ? cnt[i] : 0;
        int s = x;
        #pragma unroll
        for (int off = 1; off < 64; off <<= 1) {
            int y = __shfl_up(s, off);
            if (lane >= off) s += y;
        }
        if (lane == 63) wsum[w] = s;
        __syncthreads();
        if (w == 0) {
            int v = (lane < 16) ? wsum[lane] : 0;
            #pragma unroll
            for (int off = 1; off < 16; off <<= 1) {
                int y = __shfl_up(v, off);
                if (lane >= off) v += y;
            }
            if (lane < 16) wsum[lane] = v;
        }
        __syncthreads();
        int woff = (w > 0) ? wsum[w - 1] : 0;
        if (i < n) rp[i] = carry + woff + s - x;
        __syncthreads();
        if (t == 0) carry += wsum[15];
        __syncthreads();
    }
    if (t == 0) rp[n] = carry;
}

__global__ __launch_bounds__(1024) void scan2_kernel(
        const int* __restrict__ cntA, int* __restrict__ rpA, int nA,
        const int* __restrict__ cntB, int* __restrict__ rpB, int nB) {
    scan_ex(cntA, rpA, nA);
    __syncthreads();
    scan_ex(cntB, rpB, nB);
}

__global__ void copy2_kernel(const int* __restrict__ rpA, const int* __restrict__ rpB,
                             int nA, int nB, int* __restrict__ cur) {
    int i = blockIdx.x * blockDim.x + threadIdx.x;
    if (i < nA) cur[i] = rpA[i];
    else if (i < nA + nB) cur[i] = rpB[i - nA];
}

__global__ void scatter2_kernel(const int* __restrict__ rowsA, const int* __restrict__ colsA,
                                const void* __restrict__ valsA, int nEA,
                                const int* __restrict__ rowsB, const int* __restrict__ colsB,
                                const void* __restrict__ valsB, int nEB,
                                int nA, int* __restrict__ cur,
                                int2* __restrict__ pairsA, int2* __restrict__ pairsB,
                                const int* __restrict__ dflag) {
    int i = blockIdx.x * blockDim.x + threadIdx.x;
    int isb = *dflag;
    if (i < nEA) {
        int p = atomicAdd(cur + rowsA[i], 1);
        pairsA[p] = make_int2(colsA[i], __float_as_int(loadf(valsA, i, isb)));
    } else if (i < nEA + nEB) {
        int k = i - nEA;
        int p = atomicAdd(cur + nA + rowsB[k], 1);
        pairsB[p] = make_int2(colsB[k], __float_as_int(loadf(valsB, k, isb)));
    }
}

// ======================= gather SpMM, D=128, 4-edge unroll =======================
// dst[row,:] = sum_e v*act(src[col_e,:]); one wave/row; 4 outstanding row loads.
template<bool RELU>
__global__ void spmm_gather128(const int* __restrict__ rowptr, const int2* __restrict__ pairs,
                               const void* __restrict__ src, int src_flagged,
                               void* __restrict__ dst, int dst_flagged,
                               int n, const int* __restrict__ dflag) {
    int row = blockIdx.x * 4 + (threadIdx.x >> 6);
    if (row >= n) return;
    int isb  = *dflag;
    int sisb = src_flagged ? isb : 0;
    int disb = dst_flagged ? isb : 0;
    int lane = threadIdx.x & 63;
    int e0 = rowptr[row], e1 = rowptr[row + 1];
    float ax = 0.f, ay = 0.f, bx = 0.f, by = 0.f;
    float cx = 0.f, cy = 0.f, dx = 0.f, dy = 0.f;
    int e = e0;
    if (sisb) {
        const bf16* sb = (const bf16*)src;
        for (; e + 4 <= e1; e += 4) {
            int2 p0 = pairs[e], p1 = pairs[e+1], p2 = pairs[e+2], p3 = pairs[e+3];
            unsigned u0 = ((const unsigned*)(sb + (size_t)p0.x * 128))[lane];
            unsigned u1 = ((const unsigned*)(sb + (size_t)p1.x * 128))[lane];
            unsigned u2 = ((const unsigned*)(sb + (size_t)p2.x * 128))[lane];
            unsigned u3 = ((const unsigned*)(sb + (size_t)p3.x * 128))[lane];
            float v0 = __int_as_float(p0.y), v1 = __int_as_float(p1.y);
            float v2 = __int_as_float(p2.y), v3 = __int_as_float(p3.y);
            float x0 = b2f(u0 & 0xffffu), x1 = b2f(u0 >> 16);
            float y0 = b2f(u1 & 0xffffu), y1 = b2f(u1 >> 16);
            float z0 = b2f(u2 & 0xffffu), z1 = b2f(u2 >> 16);
            float w0 = b2f(u3 & 0xffffu), w1 = b2f(u3 >> 16);
            if (RELU) {
                x0 = fmaxf(x0, 0.f); x1 = fmaxf(x1, 0.f);
                y0 = fmaxf(y0, 0.f); y1 = fmaxf(y1, 0.f);
                z0 = fmaxf(z0, 0.f); z1 = fmaxf(z1, 0.f);
                w0 = fmaxf(w0, 0.f); w1 = fmaxf(w1, 0.f);
            }
            ax = fmaf(v0, x0, ax); ay = fmaf(v0, x1, ay);
            bx = fmaf(v1, y0, bx); by = fmaf(v1, y1, by);
            cx = fmaf(v2, z0, cx); cy = fmaf(v2, z1, cy);
            dx = fmaf(v3, w0, dx); dy = fmaf(v3, w1, dy);
        }
        for (; e < e1; ++e) {
            int2 p = pairs[e];
            float v = __int_as_float(p.y);
            unsigned u = ((const unsigned*)(sb + (size_t)p.x * 128))[lane];
            float x0 = b2f(u & 0xffffu), x1 = b2f(u >> 16);
            if (RELU) { x0 = fmaxf(x0, 0.f); x1 = fmaxf(x1, 0.f); }
            ax = fmaf(v, x0, ax); ay = fmaf(v, x1, ay);
        }
    } else {
        const float* sf = (const float*)src;
        for (; e + 4 <= e1; e += 4) {
            int2 p0 = pairs[e], p1 = pairs[e+1], p2 = pairs[e+2], p3 = pairs[e+3];
            float2 x = ((const float2*)(sf + (size_t)p0.x * 128))[lane];
            float2 y = ((const float2*)(sf + (size_t)p1.x * 128))[lane];
            float2 z = ((const float2*)(sf + (size_t)p2.x * 128))[lane];
            float2 w = ((const float2*)(sf + (size_t)p3.x * 128))[lane];
            float v0 = __int_as_float(p0.y), v1 = __int_as_float(p1.y);
            float v2 = __int_as_float(p2.y), v3 = __int_as_float(p3.y);
            if (RELU) {
                x.x = fmaxf(x.x, 0.f); x.y = fmaxf(x.y, 0.f);
                y.x = fmaxf(y.x, 0.f); y.y = fmaxf(y.y, 0.f);
                z.x = fmaxf(z.x, 0.f); z.y = fmaxf(z.y, 0.f);
                w.x = fmaxf(w.x, 0.f); w.y = fmaxf(w.y, 0.f);
            }
            ax = fmaf(v0, x.x, ax); ay = fmaf(v0, x.y, ay);
            bx = fmaf(v1, y.x, bx); by = fmaf(v1, y.y, by);
            cx = fmaf(v2, z.x, cx); cy = fmaf(v2, z.y, cy);
            dx = fmaf(v3, w.x, dx); dy = fmaf(v3, w.y, dy);
        }
        for (; e < e1; ++e) {
            int2 p = pairs[e];
            float v = __int_as_float(p.y);
            float2 x = ((const float2*)(sf + (size_t)p.x * 128))[lane];
            if (RELU) { x.x = fmaxf(x.x, 0.f); x.y = fmaxf(x.y, 0.f); }
            ax = fmaf(v, x.x, ax); ay = fmaf(v, x.y, ay);
        }
    }
    float tx = (ax + bx) + (cx + dx);
    float ty = (ay + by) + (cy + dy);
    if (disb) {
        ((unsigned*)((bf16*)dst + (size_t)row * 128))[lane] = f2b(tx) | (f2b(ty) << 16);
    } else {
        ((float2*)((float*)dst + (size_t)row * 128))[lane] = make_float2(tx, ty);
    }
}

// ===== fused doc-agg + L2-norm, D=128, 4-edge unroll =====
template<bool RELU>
__global__ void spmm_norm128(const int* __restrict__ rowptr, const int2* __restrict__ pairs,
                             const void* __restrict__ src, int src_flagged,
                             void* __restrict__ out, size_t elem_off,
                             int n, const int* __restrict__ dflag) {
    int row = blockIdx.x * 4 + (threadIdx.x >> 6);
    if (row >= n) return;
    int isb  = *dflag;
    int sisb = src_flagged ? isb : 0;
    int lane = threadIdx.x & 63;
    int e0 = rowptr[row], e1 = rowptr[row + 1];
    float ax = 0.f, ay = 0.f, bx = 0.f, by = 0.f;
    float cx = 0.f, cy = 0.f, dx = 0.f, dy = 0.f;
    int e = e0;
    if (sisb) {
        const bf16* sb = (const bf16*)src;
        for (; e + 4 <= e1; e += 4) {
            int2 p0 = pairs[e], p1 = pairs[e+1], p2 = pairs[e+2], p3 = pairs[e+3];
            unsigned u0 = ((const unsigned*)(sb + (size_t)p0.x * 128))[lane];
            unsigned u1 = ((const unsigned*)(sb + (size_t)p1.x * 128))[lane];
            unsigned u2 = ((const unsigned*)(sb + (size_t)p2.x * 128))[lane];
            unsigned u3 = ((const unsigned*)(sb + (size_t)p3.x * 128))[lane];
            float v0 = __int_as_float(p0.y), v1 = __int_as_float(p1.y);
            float v2 = __int_as_float(p2.y), v3 = __int_as_float(p3.y);
            float x0 = b2f(u0 & 0xffffu), x1 = b2f(u0 >> 16);
            float y0 = b2f(u1 & 0xffffu), y1 = b2f(u1 >> 16);
            float z0 = b2f(u2 & 0xffffu), z1 = b2f(u2 >> 16);
            float w0 = b2f(u3 & 0xffffu), w1 = b2f(u3 >> 16);
            if (RELU) {
                x0 = fmaxf(x0, 0.f); x1 = fmaxf(x1, 0.f);
                y0 = fmaxf(y0, 0.f); y1 = fmaxf(y1, 0.f);
                z0 = fmaxf(z0, 0.f); z1 = fmaxf(z1, 0.f);
                w0 = fmaxf(w0, 0.f); w1 = fmaxf(w1, 0.f);
            }
            ax = fmaf(v0, x0, ax); ay = fmaf(v0, x1, ay);
            bx = fmaf(v1, y0, bx); by = fmaf(v1, y1, by);
            cx = fmaf(v2, z0, cx); cy = fmaf(v2, z1, cy);
            dx = fmaf(v3, w0, dx); dy = fmaf(v3, w1, dy);
        }
        for (; e < e1; ++e) {
            int2 p = pairs[e];
            float v = __int_as_float(p.y);
            unsigned u = ((const unsigned*)(sb + (size_t)p.x * 128))[lane];
            float x0 = b2f(u & 0xffffu), x1 = b2f(u >> 16);
            if (RELU) { x0 = fmaxf(x0, 0.f); x1 = fmaxf(x1, 0.f); }
            ax = fmaf(v, x0, ax); ay = fmaf(v, x1, ay);
        }
    } else {
        const float* sf = (const float*)src;
        for (; e + 4 <= e1; e += 4) {
            int2 p0 = pairs[e], p1 = pairs[e+1], p2 = pairs[e+2], p3 = pairs[e+3];
            float2 x = ((const float2*)(sf + (size_t)p0.x * 128))[lane];
            float2 y = ((const float2*)(sf + (size_t)p1.x * 128))[lane];
            float2 z = ((const float2*)(sf + (size_t)p2.x * 128))[lane];
            float2 w = ((const float2*)(sf + (size_t)p3.x * 128))[lane];
            float v0 = __int_as_float(p0.y), v1 = __int_as_float(p1.y);
            float v2 = __int_as_float(p2.y), v3 = __int_as_float(p3.y);
            if (RELU) {
                x.x = fmaxf(x.x, 0.f); x.y = fmaxf(x.y, 0.f);
                y.x = fmaxf(y.x, 0.f); y.y = fmaxf(y.y, 0.f);
                z.x = fmaxf(z.x, 0.f); z.y = fmaxf(z.y, 0.f);
                w.x = fmaxf(w.x, 0.f); w.y = fmaxf(w.y, 0.f);
            }
            ax = fmaf(v0, x.x, ax); ay = fmaf(v0, x.y, ay);
            bx = fmaf(v1, y.x, bx); by = fmaf(v1, y.y, by);
            cx = fmaf(v2, z.x, cx); cy = fmaf(v2, z.y, cy);
            dx = fmaf(v3, w.x, dx); dy = fmaf(v3, w.y, dy);
        }
        for (; e < e1; ++e) {
            int2 p = pairs[e];
            float v = __int_as_float(p.y);
            float2 x = ((const float2*)(sf + (size_t)p.x * 128))[lane];
            if (RELU) { x.x = fmaxf(x.x, 0.f); x.y = fmaxf(x.y, 0.f); }
            ax = fmaf(v, x.x, ax); ay = fmaf(v, x.y, ay);
        }
    }
    float tx = (ax + bx) + (cx + dx);
    float ty = (ay + by) + (cy + dy);
    float ss = tx * tx + ty * ty;
    #pragma unroll
    for (int off = 32; off > 0; off >>= 1) ss += __shfl_down(ss, off);
    ss = __shfl(ss, 0);
    float inv = 1.0f / (sqrtf(ss) + 1e-9f);
    size_t base = elem_off + (size_t)row * 128;
    if (isb) {
        ((unsigned*)((bf16*)out + base))[lane] = f2b(tx * inv) | (f2b(ty * inv) << 16);
    } else {
        ((float2*)((float*)out + base))[lane] = make_float2(tx * inv, ty * inv);
    }
}

// ===== fused type-2 doc-agg (A02@relu(E0) ++ A02@wemb) + L2-norm, 2-edge unroll =====
__global__ void spmm2_norm(const int* __restrict__ rowptr, const int2* __restrict__ pairs,
                           const void* __restrict__ src1, int s1_flagged,
                           const void* __restrict__ src2, int s2_flagged,
                           void* __restrict__ out, size_t elem_off,
                           int n, const int* __restrict__ dflag) {
    constexpr int P2 = D_WEMB / 2;   // 150
    int row = blockIdx.x * 4 + (threadIdx.x >> 6);
    if (row >= n) return;
    int isb = *dflag;
    int s1b = s1_flagged ? isb : 0;
    int s2b = s2_flagged ? isb : 0;
    int lane = threadIdx.x & 63;
    int e0 = rowptr[row], e1 = rowptr[row + 1];
    float2 a1 = make_float2(0.f, 0.f), b1 = make_float2(0.f, 0.f);
    float2 a2[3], b2v[3];
    #pragma unroll
    for (int s = 0; s < 3; ++s) { a2[s] = make_float2(0.f, 0.f); b2v[s] = make_float2(0.f, 0.f); }
    int e = e0;
    for (; e + 2 <= e1; e += 2) {
        int2 p0 = pairs[e], p1 = pairs[e + 1];
        float v0 = __int_as_float(p0.y), v1 = __int_as_float(p1.y);
        float x0, x1, y0, y1;
        if (s1b) {
            unsigned u0 = ((const unsigned*)((const bf16*)src1 + (size_t)p0.x * DD))[lane];
            unsigned u1 = ((const unsigned*)((const bf16*)src1 + (size_t)p1.x * DD))[lane];
            x0 = b2f(u0 & 0xffffu); x1 = b2f(u0 >> 16);
            y0 = b2f(u1 & 0xffffu); y1 = b2f(u1 >> 16);
        } else {
            float2 x = ((const float2*)((const float*)src1 + (size_t)p0.x * DD))[lane];
            float2 y = ((const float2*)((const float*)src1 + (size_t)p1.x * DD))[lane];
            x0 = x.x; x1 = x.y; y0 = y.x; y1 = y.y;
        }
        x0 = fmaxf(x0, 0.f); x1 = fmaxf(x1, 0.f);
        y0 = fmaxf(y0, 0.f); y1 = fmaxf(y1, 0.f);
        a1.x = fmaf(v0, x0, a1.x); a1.y = fmaf(v0, x1, a1.y);
        b1.x = fmaf(v1, y0, b1.x); b1.y = fmaf(v1, y1, b1.y);
        if (s2b) {
            const unsigned* s0p = (const unsigned*)((const bf16*)src2 + (size_t)p0.x * D_WEMB);
            const unsigned* s1p = (const unsigned*)((const bf16*)src2 + (size_t)p1.x * D_WEMB);
            #pragma unroll
            for (int s = 0; s < 3; ++s) {
                int pi = lane + 64 * s;
                if (pi < P2) {
                    unsigned u0 = s0p[pi], u1 = s1p[pi];
                    a2[s].x  = fmaf(v0, b2f(u0 & 0xffffu), a2[s].x);
                    a2[s].y  = fmaf(v0, b2f(u0 >> 16),     a2[s].y);
                    b2v[s].x = fmaf(v1, b2f(u1 & 0xffffu), b2v[s].x);
                    b2v[s].y = fmaf(v1, b2f(u1 >> 16),     b2v[s].y);
                }
            }
        } else {
            const float2* s0p = (const float2*)((const float*)src2 + (size_t)p0.x * D_WEMB);
            const float2* s1p = (const float2*)((const float*)src2 + (size_t)p1.x * D_WEMB);
            #pragma unroll
            for (int s = 0; s < 3; ++s) {
                int pi = lane + 64 * s;
                if (pi < P2) {
                    float2 x = s0p[pi], y = s1p[pi];
                    a2[s].x  = fmaf(v0, x.x, a2[s].x);
                    a2[s].y  = fmaf(v0, x.y, a2[s].y);
                    b2v[s].x = fmaf(v1, y.x, b2v[s].x);
                    b2v[s].y = fmaf(v1, y.y, b2v[s].y);
                }
            }
        }
    }
    if (e < e1) {
        int2 p = pairs[e];
        float v = __int_as_float(p.y);
        float x0, x1;
        if (s1b) {
            unsigned u = ((const unsigned*)((const bf16*)src1 + (size_t)p.x * DD))[lane];
            x0 = b2f(u & 0xffffu); x1 = b2f(u >> 16);
        } else {
            float2 x = ((const float2*)((const float*)src1 + (size_t)p.x * DD))[lane];
            x0 = x.x; x1 = x.y;
        }
        x0 = fmaxf(x0, 0.f); x1 = fmaxf(x1, 0.f);
        a1.x = fmaf(v, x0, a1.x); a1.y = fmaf(v, x1, a1.y);
        if (s2b) {
            const unsigned* sp = (const unsigned*)((const bf16*)src2 + (size_t)p.x * D_WEMB);
            #pragma unroll
            for (int s = 0; s < 3; ++s) {
                int pi = lane + 64 * s;
                if (pi < P2) {
                    unsigned u = sp[pi];
                    a2[s].x = fmaf(v, b2f(u & 0xffffu), a2[s].x);
                    a2[s].y = fmaf(v, b2f(u >> 16),     a2[s].y);
                }
            }
        } else {
            const float2* sp = (const float2*)((const float*)src2 + (size_t)p.x * D_WEMB);
            #pragma unroll
            for (int s = 0; s < 3; ++s) {
                int pi = lane + 64 * s;
                if (pi < P2) {
                    float2 x = sp[pi];
                    a2[s].x = fmaf(v, x.x, a2[s].x);
                    a2[s].y = fmaf(v, x.y, a2[s].y);
                }
            }
        }
    }
    float t1x = a1.x + b1.x, t1y = a1.y + b1.y;
    float t2x[3], t2y[3];
    #pragma unroll
    for (int s = 0; s < 3; ++s) { t2x[s] = a2[s].x + b2v[s].x; t2y[s] = a2[s].y + b2v[s].y; }
    float ss = t1x * t1x + t1y * t1y;
    #pragma unroll
    for (int s = 0; s < 3; ++s) {
        int pi = lane + 64 * s;
        if (pi < P2) ss += t2x[s] * t2x[s] + t2y[s] * t2y[s];
    }
    #pragma unroll
    for (int off = 32; off > 0; off >>= 1) ss += __shfl_down(ss, off);
    ss = __shfl(ss, 0);
    float inv = 1.0f / (sqrtf(ss) + 1e-9f);
    size_t base = elem_off + (size_t)row * (DD + D_WEMB);
    if (isb) {
        ((unsigned*)((bf16*)out + base))[lane] = f2b(t1x * inv) | (f2b(t1y * inv) << 16);
        unsigned* o2 = (unsigned*)((bf16*)out + base + DD);
        #pragma unroll
        for (int s = 0; s < 3; ++s) {
            int pi = lane + 64 * s;
            if (pi < P2) o2[pi] = f2b(t2x[s] * inv) | (f2b(t2y[s] * inv) << 16);
        }
    } else {
        ((float2*)((float*)out + base))[lane] = make_float2(t1x * inv, t1y * inv);
        float2* o2 = (float2*)((float*)out + base + DD);
        #pragma unroll
        for (int s = 0; s < 3; ++s) {
            int pi = lane + 64 * s;
            if (pi < P2) o2[pi] = make_float2(t2x[s] * inv, t2y[s] * inv);
        }
    }
}

// ======================= atomic SpMM (ws_size fallback only) =======================
template<bool RELU>
__global__ void spmm_kernel(const int* __restrict__ rows, const int* __restrict__ cols,
                            const void* __restrict__ vals,
                            const void* __restrict__ src, int sstride, int src_flagged,
                            float* __restrict__ dst, int dstride, int doff,
                            int d, int nE, const int* __restrict__ dflag) {
    int e = blockIdx.x * (blockDim.x >> 6) + (threadIdx.x >> 6);
    if (e >= nE) return;
    int isb  = *dflag;
    int sisb = src_flagged ? isb : 0;
    int lane = threadIdx.x & 63;
    int r = rows[e];
    int c = cols[e];
    float v = loadf(vals, e, isb);
    size_t sbase = (size_t)c * sstride;
    float* dp = dst + (size_t)r * dstride + doff;
    if (sisb) {
        const unsigned* sp = (const unsigned*)((const bf16*)src + sbase);
        for (int j = 2 * lane; j < d; j += 128) {
            unsigned u = sp[j >> 1];
            float x0 = b2f(u & 0xffffu);
            float x1 = b2f(u >> 16);
            if (RELU) { x0 = fmaxf(x0, 0.f); x1 = fmaxf(x1, 0.f); }
            atomicAdd(dp + j,     v * x0);
            atomicAdd(dp + j + 1, v * x1);
        }
    } else {
        const float2* sp = (const float2*)((const float*)src + sbase);
        for (int j = 2 * lane; j < d; j += 128) {
            float2 x = sp[j >> 1];
            if (RELU) { x.x = fmaxf(x.x, 0.f); x.y = fmaxf(x.y, 0.f); }
            atomicAdd(dp + j,     v * x.x);
            atomicAdd(dp + j + 1, v * x.y);
        }
    }
}

// ======================= dense GEMMs =======================
// out[n x 128] = act(X[n x 128]) @ W[128 x 128] + b.  X is ALWAYS fp32 (gather
// writes gemm inputs fp32 -> no unpack in the hot loop). out/W/b follow *dflag.
// 2-D grid (row tiles padded to mult of 8, 4 col tiles) -> XCD-local X reuse.
template<bool RELU>
__global__ __launch_bounds__(256) void gemm_tile(
        const float* __restrict__ X, const void* __restrict__ W,
        const void* __restrict__ b, void* __restrict__ out, int n,
        const int* __restrict__ dflag) {
    __shared__ float Wl[128 * 32];
    if (blockIdx.x * 64 >= n) return;             // pad block (uniform exit, pre-barrier)
    int isb = *dflag;
    int tid = threadIdx.x;
    int jc = blockIdx.y * 32;
    if (isb) {
        const uint2* Wg = (const uint2*)W;        // 4 bf16 per uint2, row = 32 uint2
        float4* Wl4 = (float4*)Wl;
        for (int vidx = tid; vidx < 1024; vidx += 256) {
            int k = vidx >> 3, jl4 = vidx & 7;
            uint2 u = Wg[k * 32 + (jc >> 2) + jl4];
            float4 vv;
            vv.x = b2f(u.x & 0xffffu);
            vv.y = b2f(u.x >> 16);
            vv.z = b2f(u.y & 0xffffu);
            vv.w = b2f(u.y >> 16);
            Wl4[vidx] = vv;
        }
    } else {
        const float4* Wg = (const float4*)W;      // row = 32 float4
        float4* Wl4 = (float4*)Wl;
        for (int vidx = tid; vidx < 1024; vidx += 256) {
            int k = vidx >> 3, jl4 = vidx & 7;
            Wl4[vidx] = Wg[k * 32 + (jc >> 2) + jl4];
        }
    }
    __syncthreads();
    int j = tid & 31;
    int g = tid >> 5;
    float bj = loadf(b, jc + j, isb);
    int i0 = blockIdx.x * 64 + g * 8;
    float a[8];
    #pragma unroll
    for (int r = 0; r < 8; ++r) a[r] = bj;
    const float4* xp = (const float4*)(X + (size_t)i0 * 128);
    #pragma unroll 2
    for (int k4 = 0; k4 < 32; ++k4) {
        float w0 = Wl[(4 * k4 + 0) * 32 + j];
        float w1 = Wl[(4 * k4 + 1) * 32 + j];
        float w2 = Wl[(4 * k4 + 2) * 32 + j];
        float w3 = Wl[(4 * k4 + 3) * 32 + j];
        #pragma unroll
        for (int r = 0; r < 8; ++r) {
            float4 v = xp[r * 32 + k4];
            if (RELU) {
                v.x = fmaxf(v.x, 0.f); v.y = fmaxf(v.y, 0.f);
                v.z = fmaxf(v.z, 0.f); v.w = fmaxf(v.w, 0.f);
            }
            a[r] = fmaf(v.w, w3, fmaf(v.z, w2, fmaf(v.y, w1, fmaf(v.x, w0, a[r]))));
        }
    }
    #pragma unroll
    for (int r = 0; r < 8; ++r) {
        int i = i0 + r;
        if (i < n) storef(out, (size_t)i * 128 + jc + j, isb, a[r]);
    }
}

// Legacy big-LDS GEMM (fallback path only; fp32 ws).
template<bool RELU>
__global__ __launch_bounds__(256) void gemm128_kernel(
        const float* __restrict__ X, const void* __restrict__ W,
        const void* __restrict__ b, float* __restrict__ out, int n,
        const int* __restrict__ dflag) {
    __shared__ float Wl[128 * 128];
    int isb = *dflag;
    int tid = threadIdx.x;
    if (isb) {
        const uint2* Wg = (const uint2*)W;
        float4* Wl4 = (float4*)Wl;
        for (int idx = tid; idx < 4096; idx += 256) {
            uint2 u = Wg[idx];
            float4 vv;
            vv.x = b2f(u.x & 0xffffu);
            vv.y = b2f(u.x >> 16);
            vv.z = b2f(u.y & 0xffffu);
            vv.w = b2f(u.y >> 16);
            Wl4[idx] = vv;
        }
    } else {
        const float4* Wg = (const float4*)W;
        float4* Wl4 = (float4*)Wl;
        for (int idx = tid; idx < 4096; idx += 256) Wl4[idx] = Wg[idx];
    }
    __syncthreads();
    int j = tid & 127;
    int h = tid >> 7;
    float bj = loadf(b, j, isb);
    int row0 = blockIdx.x * 64 + h * 32;
    for (int q = 0; q < 8; ++q) {
        int gi = row0 + q * 4;
        if (gi >= n) break;
        const float4* x0 = (const float4*)(X + (size_t)gi * 128);
        const float4* x1 = x0 + 32;
        const float4* x2 = x1 + 32;
        const float4* x3 = x2 + 32;
        float a0 = bj, a1 = bj, a2 = bj, a3 = bj;
        #pragma unroll 4
        for (int k4 = 0; k4 < 32; ++k4) {
            float4 v0 = x0[k4], v1 = x1[k4], v2 = x2[k4], v3 = x3[k4];
            if (RELU) {
                v0.x = fmaxf(v0.x, 0.f); v0.y = fmaxf(v0.y, 0.f); v0.z = fmaxf(v0.z, 0.f); v0.w = fmaxf(v0.w, 0.f);
                v1.x = fmaxf(v1.x, 0.f); v1.y = fmaxf(v1.y, 0.f); v1.z = fmaxf(v1.z, 0.f); v1.w = fmaxf(v1.w, 0.f);
                v2.x = fmaxf(v2.x, 0.f); v2.y = fmaxf(v2.y, 0.f); v2.z = fmaxf(v2.z, 0.f); v2.w = fmaxf(v2.w, 0.f);
                v3.x = fmaxf(v3.x, 0.f); v3.y = fmaxf(v3.y, 0.f); v3.z = fmaxf(v3.z, 0.f); v3.w = fmaxf(v3.w, 0.f);
            }
            float w0 = Wl[(4 * k4 + 0) * 128 + j];
            float w1 = Wl[(4 * k4 + 1) * 128 + j];
            float w2 = Wl[(4 * k4 + 2) * 128 + j];
            float w3 = Wl[(4 * k4 + 3) * 128 + j];
            a0 = fmaf(v0.w, w3, fmaf(v0.z, w2, fmaf(v0.y, w1, fmaf(v0.x, w0, a0))));
            a1 = fmaf(v1.w, w3, fmaf(v1.z, w2, fmaf(v1.y, w1, fmaf(v1.x, w0, a1))));
            a2 = fmaf(v2.w, w3, fmaf(v2.z, w2, fmaf(v2.y, w1, fmaf(v2.x, w0, a2))));
            a3 = fmaf(v3.w, w3, fmaf(v3.z, w2, fmaf(v3.y, w1, fmaf(v3.x, w0, a3))));
        }
        float* o = out + (size_t)gi * 128 + j;
        o[0] = a0; o[128] = a1; o[256] = a2; o[384] = a3;
    }
}

// Row-parallel tiny GEMM (type-3, n=60): one block per row, 128 threads.
template<bool RELU, int K>
__global__ void rowpar_gemm(const void* __restrict__ X, int x_flagged,
                            const void* __restrict__ W, const void* __restrict__ b,
                            void* __restrict__ out, int out_flagged,
                            const int* __restrict__ dflag) {
    __shared__ float xr[K];
    int isb  = *dflag;
    int xisb = x_flagged ? isb : 0;
    int oisb = out_flagged ? isb : 0;
    int row = blockIdx.x;
    int j = threadIdx.x;
    if (j < K) {
        float x = loadf(X, (size_t)row * K + j, xisb);
        if (RELU) x = fmaxf(x, 0.f);
        xr[j] = x;
    }
    __syncthreads();
    float acc = loadf(b, j, isb);
    #pragma unroll 8
    for (int k = 0; k < K; ++k)
        acc = fmaf(xr[k], loadf(W, (size_t)k * 128 + j, isb), acc);
    storef(out, (size_t)row * 128 + j, oisb, acc);
}

// Generic small GEMM (fallback path only).
template<bool RELU, int K>
__global__ void gemm_kernel(const void* __restrict__ X, int x_flagged,
                            const void* __restrict__ W,
                            const void* __restrict__ b,
                            float* __restrict__ out, int n,
                            const int* __restrict__ dflag) {
    __shared__ float Wl[K * 128];
    int isb  = *dflag;
    int xisb = x_flagged ? isb : 0;
    int j = threadIdx.x;
    for (int idx = j; idx < K * 128; idx += 128)
        Wl[idx] = loadf(W, idx, isb);
    __syncthreads();
    float bj = loadf(b, j, isb);
    int row0 = blockIdx.x * 64;
    for (int i0 = 0; i0 < 64; i0 += 4) {
        int i = row0 + i0;
        if (i >= n) break;
        size_t r0 = (size_t)i * K;
        float a0 = bj, a1 = bj, a2 = bj, a3 = bj;
        for (int k = 0; k < K; ++k) {
            float w = Wl[k * 128 + j];
            float v0 = loadf(X, r0 + k, xisb);
            float v1 = loadf(X, r0 + K + k, xisb);
            float v2 = loadf(X, r0 + 2 * K + k, xisb);
            float v3 = loadf(X, r0 + 3 * K + k, xisb);
            if (RELU) {
                v0 = fmaxf(v0, 0.f); v1 = fmaxf(v1, 0.f);
                v2 = fmaxf(v2, 0.f); v3 = fmaxf(v3, 0.f);
            }
            a0 = fmaf(v0, w, a0);
            a1 = fmaf(v1, w, a1);
            a2 = fmaf(v2, w, a2);
            a3 = fmaf(v3, w, a3);
        }
        float* o = out + (size_t)i * 128 + j;
        o[0] = a0; o[128] = a1; o[256] = a2; o[384] = a3;
    }
}

// L2-norm (fallback path only).
__global__ void l2norm_kernel(const float* __restrict__ agg, int d,
                              void* __restrict__ out, size_t elem_off, int n,
                              const int* __restrict__ dflag) {
    int row = blockIdx.x * (blockDim.x >> 6) + (threadIdx.x >> 6);
    if (row >= n) return;
    int isb  = *dflag;
    int lane = threadIdx.x & 63;
    const float2* a2 = (const float2*)(agg + (size_t)row * d);
    float ss = 0.f;
    for (int j = 2 * lane; j < d; j += 128) {
        float2 x = a2[j >> 1];
        ss += x.x * x.x + x.y * x.y;
    }
    #pragma unroll
    for (int off = 32; off > 0; off >>= 1) ss += __shfl_down(ss, off);
    ss = __shfl(ss, 0);
    float inv = 1.0f / (sqrtf(ss) + 1e-9f);
    size_t bbase = elem_off + (size_t)row * d;
    if (isb) {
        unsigned* o = (unsigned*)((bf16*)out + bbase);
        for (int j = 2 * lane; j < d; j += 128) {
            float2 x = a2[j >> 1];
            o[j >> 1] = f2b(x.x * inv) | (f2b(x.y * inv) << 16);
        }
    } else {
        float2* o = (float2*)((float*)out + bbase);
        for (int j = 2 * lane; j < d; j += 128) {
            float2 x = a2[j >> 1];
            o[j >> 1] = make_float2(x.x * inv, x.y * inv);
        }
    }
}

static inline int spmm_grid(int nE) { return (nE + 3) / 4; }
static inline int row_grid(int n)   { return (n + 3) / 4; }
static inline int pad8(int x)       { return (x + 7) & ~7; }

// Fused per-phase CSR build for two matrices A,B sharing one cursor block.
static void build2(hipStream_t stream,
                   const int* rowsA, const int* colsA, const void* valsA, int nA, int nEA,
                   const int* rowsB, const int* colsB, const void* valsB, int nB, int nEB,
                   int* rpA, int* rpB, int* curAB, int2* pairsA, int2* pairsB,
                   const int* dflag) {
    int nE = nEA + nEB;
    hipMemsetAsync(curAB, 0, (size_t)(nA + nB) * 4, stream);
    hist2_kernel<<<(nE + 255) / 256, 256, 0, stream>>>(rowsA, nEA, rowsB, nEB, nA, curAB);
    scan2_kernel<<<1, 1024, 0, stream>>>(curAB, rpA, nA, curAB + nA, rpB, nB);
    copy2_kernel<<<(nA + nB + 255) / 256, 256, 0, stream>>>(rpA, rpB, nA, nB, curAB);
    scatter2_kernel<<<(nE + 255) / 256, 256, 0, stream>>>(
        rowsA, colsA, valsA, nEA, rowsB, colsB, valsB, nEB, nA, curAB, pairsA, pairsB, dflag);
}

extern "C" void kernel_launch(void* const* d_in, const int* in_sizes, int n_in,
                              void* d_out, int out_size, void* d_ws, size_t ws_size,
                              hipStream_t stream) {
    const void* f1   = d_in[0];
    const void* f2   = d_in[1];
    const void* f3   = d_in[2];
    const void* wemb = d_in[3];
    const int*  a11r = (const int*)d_in[4];
    const int*  a11c = (const int*)d_in[5];
    const void* a11v = d_in[6];
    const int*  a22r = (const int*)d_in[7];
    const int*  a22c = (const int*)d_in[8];
    const void* a22v = d_in[9];
    const int*  a33r = (const int*)d_in[10];
    const int*  a33c = (const int*)d_in[11];
    const void* a33v = d_in[12];
    const int*  a01r = (const int*)d_in[13];
    const int*  a01c = (const int*)d_in[14];
    const void* a01v = d_in[15];
    const int*  a02r = (const int*)d_in[16];
    const int*  a02c = (const int*)d_in[17];
    const void* a02v = d_in[18];
    const int*  a03r = (const int*)d_in[19];
    const int*  a03c = (const int*)d_in[20];
    const void* a03v = d_in[21];
    const void* W3   = d_in[22];
    const void* b3   = d_in[23];
    const void* W1_2 = d_in[24];
    const void* b1_2 = d_in[25];
    const void* W2_2 = d_in[26];
    const void* b2_2 = d_in[27];
    const void* W3_2 = d_in[28];
    const void* b3_2 = d_in[29];

    int*   dflag = (int*)d_ws;
    float* base  = (float*)d_ws + 16;       // buffers start 64 B in (sized for fp32 worst case)
    float* S0   = base;                     // 20000*128 (fp32 gemm-in OR bf16 gather-out)
    float* S1   = base + 2560000;           // 20000*128
    float* AGG1 = S1;                       // fallback only
    float* E0   = base;                     // 10000*128
    float* E1   = base + 1280000;           // 10000*128
    float* AGG2 = base + 1280000;           // fallback only
    float* P3a  = base;                     // 60*128
    float* P3b  = base + 7680;              // 60*128
    float* AGG3 = base + 15360;             // fallback only

    // CSR region after dense peak: [rpA | rpB | curAB | pairsA | pairsB]
    int* I = (int*)(base + 5560000);
    const size_t WS_NEEDED = 64 + 22240000ull + 240008ull + 4960000ull; // ~27.44 MB

    const size_t OUT1_OFF = 0;
    const size_t OUT2_OFF = (size_t)N_DOC * DD;                       // 1,280,000
    const size_t OUT3_OFF = OUT2_OFF + (size_t)N_DOC * (DD + D_WEMB); // 5,560,000

    dim3 blk(256);
    detect_kernel<<<1, 256, 0, stream>>>((const unsigned*)f1, dflag);

    if (ws_size >= WS_NEEDED) {
        // ================= CSR gather path =================
        // ---------------- type 1 (words): A=A11 (20000), B=A01 (10000) ----------------
        {
            int* rpA = I; int* rpB = rpA + (N_WORD + 1); int* cur = rpB + (N_DOC + 1);
            int2* pA = (int2*)(cur + N_WORD + N_DOC); int2* pB = pA + E11;
            build2(stream, a11r, a11c, a11v, N_WORD, E11,
                   a01r, a01c, a01v, N_DOC, E01, rpA, rpB, cur, pA, pB, dflag);
            spmm_gather128<false><<<row_grid(N_WORD), blk, 0, stream>>>(
                rpA, pA, f1, 1, S0, 0, N_WORD, dflag);                // S0(fp32) = A11@f1
            gemm_tile<true><<<dim3(pad8((N_WORD + 63) / 64), 4), 256, 0, stream>>>(
                S0, W1_2, b1_2, S1, N_WORD, dflag);                   // S1(bf16) = relu(S0)@W+b
            spmm_gather128<false><<<row_grid(N_WORD), blk, 0, stream>>>(
                rpA, pA, S1, 1, S0, 1, N_WORD, dflag);                // S0(bf16) = A11@S1
            spmm_norm128<true><<<row_grid(N_DOC), blk, 0, stream>>>(
                rpB, pB, S0, 1, d_out, OUT1_OFF, N_DOC, dflag);       // out1 = norm(A01@relu(S0))
        }
        // ---------------- type 2 (entities): A=A22 (10000), B=A02 (10000) ----------------
        {
            int* rpA = I; int* rpB = rpA + (N_ENT + 1); int* cur = rpB + (N_DOC + 1);
            int2* pA = (int2*)(cur + N_ENT + N_DOC); int2* pB = pA + E22;
            build2(stream, a22r, a22c, a22v, N_ENT, E22,
                   a02r, a02c, a02v, N_DOC, E02, rpA, rpB, cur, pA, pB, dflag);
            spmm_gather128<false><<<row_grid(N_ENT), blk, 0, stream>>>(
                rpA, pA, f2, 1, E0, 0, N_ENT, dflag);                 // E0(fp32) = A22@f2
            gemm_tile<true><<<dim3(pad8((N_ENT + 63) / 64), 4), 256, 0, stream>>>(
                E0, W2_2, b2_2, E1, N_ENT, dflag);                    // E1(bf16) = relu(E0)@W+b
            spmm_gather128<false><<<row_grid(N_ENT), blk, 0, stream>>>(
                rpA, pA, E1, 1, E0, 1, N_ENT, dflag);                 // E0(bf16) = A22@E1
            spmm2_norm<<<row_grid(N_DOC), blk, 0, stream>>>(
                rpB, pB, E0, 1, wemb, 1, d_out, OUT2_OFF, N_DOC, dflag); // out2 fused
        }
        // ---------------- type 3 (POS): A=A33 (60), B=A03 (10000) ----------------
        {
            int* rpA = I; int* rpB = rpA + (N_POS + 1); int* cur = rpB + (N_DOC + 1);
            int2* pA = (int2*)(cur + N_POS + N_DOC); int2* pB = pA + E33;
            build2(stream, a33r, a33c, a33v, N_POS, E33,
                   a03r, a03c, a03v, N_DOC, E03, rpA, rpB, cur, pA, pB, dflag);
            rowpar_gemm<false, 60><<<N_POS, 128, 0, stream>>>(
                f3, 1, W3, b3, P3a, 1, dflag);                        // P3a = f3@W3+b3
            spmm_gather128<false><<<row_grid(N_POS), blk, 0, stream>>>(
                rpA, pA, P3a, 1, P3b, 1, N_POS, dflag);               // P3b = A33@P3a
            rowpar_gemm<true, 128><<<N_POS, 128, 0, stream>>>(
                P3b, 1, W3_2, b3_2, P3a, 1, dflag);                   // P3a = relu(P3b)@W+b
            spmm_gather128<false><<<row_grid(N_POS), blk, 0, stream>>>(
                rpA, pA, P3a, 1, P3b, 1, N_POS, dflag);               // P3b = A33@P3a
            spmm_norm128<true><<<row_grid(N_DOC), blk, 0, stream>>>(
                rpB, pB, P3b, 1, d_out, OUT3_OFF, N_DOC, dflag);      // out3 = norm(A03@relu(P3b))
        }
    } else {
        // ================= fallback: atomic-scatter path (fp32 ws) =================
        hipMemsetAsync(S0, 0, (size_t)N_WORD * DD * 4, stream);
        spmm_kernel<false><<<spmm_grid(E11), blk, 0, stream>>>(
            a11r, a11c, a11v, f1, DD, 1, S0, DD, 0, DD, E11, dflag);
        gemm128_kernel<true><<<(N_WORD + 63) / 64, 256, 0, stream>>>(
            S0, W1_2, b1_2, S1, N_WORD, dflag);
        hipMemsetAsync(S0, 0, (size_t)N_WORD * DD * 4, stream);
        spmm_kernel<false><<<spmm_grid(E11), blk, 0, stream>>>(
            a11r, a11c, a11v, S1, DD, 0, S0, DD, 0, DD, E11, dflag);
        hipMemsetAsync(AGG1, 0, (size_t)N_DOC * DD * 4, stream);
        spmm_kernel<true><<<spmm_grid(E01), blk, 0, stream>>>(
            a01r, a01c, a01v, S0, DD, 0, AGG1, DD, 0, DD, E01, dflag);
        l2norm_kernel<<<row_grid(N_DOC), blk, 0, stream>>>(
            AGG1, DD, d_out, OUT1_OFF, N_DOC, dflag);

        hipMemsetAsync(E0, 0, (size_t)N_ENT * DD * 4, stream);
        spmm_kernel<false><<<spmm_grid(E22), blk, 0, stream>>>(
            a22r, a22c, a22v, f2, DD, 1, E0, DD, 0, DD, E22, dflag);
        gemm128_kernel<true><<<(N_ENT + 63) / 64, 256, 0, stream>>>(
            E0, W2_2, b2_2, E1, N_ENT, dflag);
        hipMemsetAsync(E0, 0, (size_t)N_ENT * DD * 4, stream);
        spmm_kernel<false><<<spmm_grid(E22), blk, 0, stream>>>(
            a22r, a22c, a22v, E1, DD, 0, E0, DD, 0, DD, E22, dflag);
        hipMemsetAsync(AGG2, 0, (size_t)N_DOC * (DD + D_WEMB) * 4, stream);
        spmm_kernel<true><<<spmm_grid(E02), blk, 0, stream>>>(
            a02r, a02c, a02v, E0, DD, 0, AGG2, DD + D_WEMB, 0, DD, E02, dflag);
        spmm_kernel<false><<<spmm_grid(E02), blk, 0, stream>>>(
            a02r, a02c, a02v, wemb, D_WEMB, 1, AGG2, DD + D_WEMB, DD, D_WEMB, E02, dflag);
        l2norm_kernel<<<row_grid(N_DOC), blk, 0, stream>>>(
            AGG2, DD + D_WEMB, d_out, OUT2_OFF, N_DOC, dflag);

        gemm_kernel<false, 60><<<1, 128, 0, stream>>>(f3, 1, W3, b3, P3a, N_POS, dflag);
        hipMemsetAsync(P3b, 0, (size_t)N_POS * DD * 4, stream);
        spmm_kernel<false><<<spmm_grid(E33), blk, 0, stream>>>(
            a33r, a33c, a33v, P3a, DD, 0, P3b, DD, 0, DD, E33, dflag);
        gemm128_kernel<true><<<1, 256, 0, stream>>>(
            P3b, W3_2, b3_2, P3a, N_POS, dflag);
        hipMemsetAsync(P3b, 0, (size_t)N_POS * DD * 4, stream);
        spmm_kernel<false><<<spmm_grid(E33), blk, 0, stream>>>(
            a33r, a33c, a33v, P3a, DD, 0, P3b, DD, 0, DD, E33, dflag);
        hipMemsetAsync(AGG3, 0, (size_t)N_DOC * DD * 4, stream);
        spmm_kernel<true><<<spmm_grid(E03), blk, 0, stream>>>(
            a03r, a03c, a03v, P3b, DD, 0, AGG3, DD, 0, DD, E03, dflag);
        l2norm_kernel<<<row_grid(N_DOC), blk, 0, stream>>>(
            AGG3, DD, d_out, OUT3_OFF, N_DOC, dflag);
    }
}

// Round 13
// 515.950 us; speedup vs baseline: 1.2676x; 1.1387x over previous
//
#include <hip/hip_runtime.h>
#include <hip/hip_bf16.h>

typedef __hip_bfloat16 bf16;

#define N_DOC   10000
#define N_WORD  20000
#define N_ENT   10000
#define N_POS   60
#define DD      128
#define D_WEMB  300
#define E11     320000
#define E22     160000
#define E33     3600
#define E01     300000
#define E02     100000
#define E03     150000

// Concatenated row/edge segment offsets for the fused 6-matrix CSR build.
#define ROFF11  0
#define ROFF22  20000
#define ROFF33  30000
#define ROFF01  30060
#define ROFF02  40060
#define ROFF03  50060
#define NROWS   60060
#define EOFF11  0
#define EOFF22  320000
#define EOFF33  480000
#define EOFF01  483600
#define EOFF02  783600
#define EOFF03  883600
#define NEDGES  1033600

// Runtime dtype flag (ws[0]): 1 if float inputs are packed bf16, 0 if fp32.
__device__ __forceinline__ float loadf(const void* p, size_t i, int isb) {
    return isb ? __bfloat162float(((const bf16*)p)[i])
               : ((const float*)p)[i];
}
__device__ __forceinline__ float b2f(unsigned u16) {
    union { unsigned v; float f; } x; x.v = u16 << 16; return x.f;
}
__device__ __forceinline__ unsigned f2b(float f) {
    bf16 h = __float2bfloat16(f);
    union { bf16 h; unsigned short u; } x; x.h = h; return (unsigned)x.u;
}
__device__ __forceinline__ void storef(void* p, size_t i, int asb, float v) {
    if (asb) ((unsigned short*)p)[i] = (unsigned short)f2b(v);
    else     ((float*)p)[i] = v;
}

// Detect input dtype from a randn fp32-or-bf16 buffer (see R2 notes).
__global__ void detect_kernel(const unsigned* __restrict__ probe, int* __restrict__ flag) {
    __shared__ int cnt;
    if (threadIdx.x == 0) cnt = 0;
    __syncthreads();
    int insane = 0;
    for (int i = threadIdx.x; i < 1024; i += 256) {
        float x = __uint_as_float(probe[i]);
        float a = fabsf(x);
        if (!(a > 1e-10f && a < 1e10f)) insane++;
    }
    atomicAdd(&cnt, insane);
    __syncthreads();
    if (threadIdx.x == 0) *flag = (cnt > 512) ? 1 : 0;
}

// ======================= exclusive scan primitive =======================
__device__ void scan_ex(const int* __restrict__ cnt, int* __restrict__ rp, int n) {
    __shared__ int wsum[16];
    __shared__ int carry;
    int t = threadIdx.x, lane = t & 63, w = t >> 6;
    if (t == 0) carry = 0;
    __syncthreads();
    for (int base = 0; base < n; base += 1024) {
        int i = base + t;
        int x = (i < n) ? cnt[i] : 0;
        int s = x;
        #pragma unroll
        for (int off = 1; off < 64; off <<= 1) {
            int y = __shfl_up(s, off);
            if (lane >= off) s += y;
        }
        if (lane == 63) wsum[w] = s;
        __syncthreads();
        if (w == 0) {
            int v = (lane < 16) ? wsum[lane] : 0;
            #pragma unroll
            for (int off = 1; off < 16; off <<= 1) {
                int y = __shfl_up(v, off);
                if (lane >= off) v += y;
            }
            if (lane < 16) wsum[lane] = v;
        }
        __syncthreads();
        int woff = (w > 0) ? wsum[w - 1] : 0;
        if (i < n) rp[i] = carry + woff + s - x;
        __syncthreads();
        if (t == 0) carry += wsum[15];
        __syncthreads();
    }
    if (t == 0) rp[n] = carry;
}

// ======================= fused 6-matrix CSR build (BIG path) =======================
__global__ void hist_all(const int* __restrict__ r11, const int* __restrict__ r22,
                         const int* __restrict__ r33, const int* __restrict__ r01,
                         const int* __restrict__ r02, const int* __restrict__ r03,
                         int* __restrict__ cnt) {
    int i = blockIdx.x * blockDim.x + threadIdx.x;
    if (i >= NEDGES) return;
    int slot;
    if      (i < EOFF22) slot = ROFF11 + r11[i];
    else if (i < EOFF33) slot = ROFF22 + r22[i - EOFF22];
    else if (i < EOFF01) slot = ROFF33 + r33[i - EOFF33];
    else if (i < EOFF02) slot = ROFF01 + r01[i - EOFF01];
    else if (i < EOFF03) slot = ROFF02 + r02[i - EOFF02];
    else                 slot = ROFF03 + r03[i - EOFF03];
    atomicAdd(cnt + slot, 1);
}

__global__ __launch_bounds__(1024) void scan_all(const int* __restrict__ cnt,
                                                 int* __restrict__ G) {
    scan_ex(cnt, G, NROWS);
}

__global__ void copy_all(const int* __restrict__ G, int* __restrict__ cur) {
    int i = blockIdx.x * blockDim.x + threadIdx.x;
    if (i < NROWS) cur[i] = G[i];
}

__global__ void scatter_all(const int* __restrict__ r11, const int* __restrict__ c11, const void* __restrict__ v11,
                            const int* __restrict__ r22, const int* __restrict__ c22, const void* __restrict__ v22,
                            const int* __restrict__ r33, const int* __restrict__ c33, const void* __restrict__ v33,
                            const int* __restrict__ r01, const int* __restrict__ c01, const void* __restrict__ v01,
                            const int* __restrict__ r02, const int* __restrict__ c02, const void* __restrict__ v02,
                            const int* __restrict__ r03, const int* __restrict__ c03, const void* __restrict__ v03,
                            int* __restrict__ cur, int2* __restrict__ pairs,
                            const int* __restrict__ dflag) {
    int i = blockIdx.x * blockDim.x + threadIdx.x;
    if (i >= NEDGES) return;
    int isb = *dflag;
    int slot, col; float val;
    if      (i < EOFF22) { int k = i;          slot = ROFF11 + r11[k]; col = c11[k]; val = loadf(v11, k, isb); }
    else if (i < EOFF01 && i >= EOFF33) { int k = i - EOFF33; slot = ROFF33 + r33[k]; col = c33[k]; val = loadf(v33, k, isb); }
    else if (i < EOFF33) { int k = i - EOFF22; slot = ROFF22 + r22[k]; col = c22[k]; val = loadf(v22, k, isb); }
    else if (i < EOFF02) { int k = i - EOFF01; slot = ROFF01 + r01[k]; col = c01[k]; val = loadf(v01, k, isb); }
    else if (i < EOFF03) { int k = i - EOFF02; slot = ROFF02 + r02[k]; col = c02[k]; val = loadf(v02, k, isb); }
    else                 { int k = i - EOFF03; slot = ROFF03 + r03[k]; col = c03[k]; val = loadf(v03, k, isb); }
    int p = atomicAdd(cur + slot, 1);
    pairs[p] = make_int2(col, __float_as_int(val));
}

// ======================= fused 2-matrix CSR build (mid path) =======================
__global__ void hist2_kernel(const int* __restrict__ rowsA, int nEA,
                             const int* __restrict__ rowsB, int nEB,
                             int nA, int* __restrict__ cnt) {
    int i = blockIdx.x * blockDim.x + threadIdx.x;
    if (i < nEA) atomicAdd(cnt + rowsA[i], 1);
    else if (i < nEA + nEB) atomicAdd(cnt + nA + rowsB[i - nEA], 1);
}

__global__ __launch_bounds__(1024) void scan2_kernel(
        const int* __restrict__ cntA, int* __restrict__ rpA, int nA,
        const int* __restrict__ cntB, int* __restrict__ rpB, int nB) {
    scan_ex(cntA, rpA, nA);
    __syncthreads();
    scan_ex(cntB, rpB, nB);
}

__global__ void copy2_kernel(const int* __restrict__ rpA, const int* __restrict__ rpB,
                             int nA, int nB, int* __restrict__ cur) {
    int i = blockIdx.x * blockDim.x + threadIdx.x;
    if (i < nA) cur[i] = rpA[i];
    else if (i < nA + nB) cur[i] = rpB[i - nA];
}

__global__ void scatter2_kernel(const int* __restrict__ rowsA, const int* __restrict__ colsA,
                                const void* __restrict__ valsA, int nEA,
                                const int* __restrict__ rowsB, const int* __restrict__ colsB,
                                const void* __restrict__ valsB, int nEB,
                                int nA, int* __restrict__ cur,
                                int2* __restrict__ pairsA, int2* __restrict__ pairsB,
                                const int* __restrict__ dflag) {
    int i = blockIdx.x * blockDim.x + threadIdx.x;
    int isb = *dflag;
    if (i < nEA) {
        int p = atomicAdd(cur + rowsA[i], 1);
        pairsA[p] = make_int2(colsA[i], __float_as_int(loadf(valsA, i, isb)));
    } else if (i < nEA + nEB) {
        int k = i - nEA;
        int p = atomicAdd(cur + nA + rowsB[k], 1);
        pairsB[p] = make_int2(colsB[k], __float_as_int(loadf(valsB, k, isb)));
    }
}

// ======================= gather bodies =======================
template<bool RELU>
__device__ __forceinline__ void gather128_body(
        const int* __restrict__ rp, const int2* __restrict__ pairs,
        const void* __restrict__ src, int sisb,
        void* __restrict__ dst, int disb, int row, int lane) {
    int e0 = rp[row], e1 = rp[row + 1];
    float ax = 0.f, ay = 0.f, bx = 0.f, by = 0.f;
    float cx = 0.f, cy = 0.f, dx = 0.f, dy = 0.f;
    int e = e0;
    if (sisb) {
        const bf16* sb = (const bf16*)src;
        for (; e + 4 <= e1; e += 4) {
            int2 p0 = pairs[e], p1 = pairs[e+1], p2 = pairs[e+2], p3 = pairs[e+3];
            unsigned u0 = ((const unsigned*)(sb + (size_t)p0.x * 128))[lane];
            unsigned u1 = ((const unsigned*)(sb + (size_t)p1.x * 128))[lane];
            unsigned u2 = ((const unsigned*)(sb + (size_t)p2.x * 128))[lane];
            unsigned u3 = ((const unsigned*)(sb + (size_t)p3.x * 128))[lane];
            float v0 = __int_as_float(p0.y), v1 = __int_as_float(p1.y);
            float v2 = __int_as_float(p2.y), v3 = __int_as_float(p3.y);
            float x0 = b2f(u0 & 0xffffu), x1 = b2f(u0 >> 16);
            float y0 = b2f(u1 & 0xffffu), y1 = b2f(u1 >> 16);
            float z0 = b2f(u2 & 0xffffu), z1 = b2f(u2 >> 16);
            float w0 = b2f(u3 & 0xffffu), w1 = b2f(u3 >> 16);
            if (RELU) {
                x0 = fmaxf(x0, 0.f); x1 = fmaxf(x1, 0.f);
                y0 = fmaxf(y0, 0.f); y1 = fmaxf(y1, 0.f);
                z0 = fmaxf(z0, 0.f); z1 = fmaxf(z1, 0.f);
                w0 = fmaxf(w0, 0.f); w1 = fmaxf(w1, 0.f);
            }
            ax = fmaf(v0, x0, ax); ay = fmaf(v0, x1, ay);
            bx = fmaf(v1, y0, bx); by = fmaf(v1, y1, by);
            cx = fmaf(v2, z0, cx); cy = fmaf(v2, z1, cy);
            dx = fmaf(v3, w0, dx); dy = fmaf(v3, w1, dy);
        }
        for (; e < e1; ++e) {
            int2 p = pairs[e];
            float v = __int_as_float(p.y);
            unsigned u = ((const unsigned*)(sb + (size_t)p.x * 128))[lane];
            float x0 = b2f(u & 0xffffu), x1 = b2f(u >> 16);
            if (RELU) { x0 = fmaxf(x0, 0.f); x1 = fmaxf(x1, 0.f); }
            ax = fmaf(v, x0, ax); ay = fmaf(v, x1, ay);
        }
    } else {
        const float* sf = (const float*)src;
        for (; e + 4 <= e1; e += 4) {
            int2 p0 = pairs[e], p1 = pairs[e+1], p2 = pairs[e+2], p3 = pairs[e+3];
            float2 x = ((const float2*)(sf + (size_t)p0.x * 128))[lane];
            float2 y = ((const float2*)(sf + (size_t)p1.x * 128))[lane];
            float2 z = ((const float2*)(sf + (size_t)p2.x * 128))[lane];
            float2 w = ((const float2*)(sf + (size_t)p3.x * 128))[lane];
            float v0 = __int_as_float(p0.y), v1 = __int_as_float(p1.y);
            float v2 = __int_as_float(p2.y), v3 = __int_as_float(p3.y);
            if (RELU) {
                x.x = fmaxf(x.x, 0.f); x.y = fmaxf(x.y, 0.f);
                y.x = fmaxf(y.x, 0.f); y.y = fmaxf(y.y, 0.f);
                z.x = fmaxf(z.x, 0.f); z.y = fmaxf(z.y, 0.f);
                w.x = fmaxf(w.x, 0.f); w.y = fmaxf(w.y, 0.f);
            }
            ax = fmaf(v0, x.x, ax); ay = fmaf(v0, x.y, ay);
            bx = fmaf(v1, y.x, bx); by = fmaf(v1, y.y, by);
            cx = fmaf(v2, z.x, cx); cy = fmaf(v2, z.y, cy);
            dx = fmaf(v3, w.x, dx); dy = fmaf(v3, w.y, dy);
        }
        for (; e < e1; ++e) {
            int2 p = pairs[e];
            float v = __int_as_float(p.y);
            float2 x = ((const float2*)(sf + (size_t)p.x * 128))[lane];
            if (RELU) { x.x = fmaxf(x.x, 0.f); x.y = fmaxf(x.y, 0.f); }
            ax = fmaf(v, x.x, ax); ay = fmaf(v, x.y, ay);
        }
    }
    float tx = (ax + bx) + (cx + dx);
    float ty = (ay + by) + (cy + dy);
    if (disb) {
        ((unsigned*)((bf16*)dst + (size_t)row * 128))[lane] = f2b(tx) | (f2b(ty) << 16);
    } else {
        ((float2*)((float*)dst + (size_t)row * 128))[lane] = make_float2(tx, ty);
    }
}

template<bool RELU>
__device__ __forceinline__ void norm128_body(
        const int* __restrict__ rp, const int2* __restrict__ pairs,
        const void* __restrict__ src, int sisb,
        void* __restrict__ out, size_t elem_off, int row, int lane, int isb) {
    int e0 = rp[row], e1 = rp[row + 1];
    float ax = 0.f, ay = 0.f, bx = 0.f, by = 0.f;
    float cx = 0.f, cy = 0.f, dx = 0.f, dy = 0.f;
    int e = e0;
    if (sisb) {
        const bf16* sb = (const bf16*)src;
        for (; e + 4 <= e1; e += 4) {
            int2 p0 = pairs[e], p1 = pairs[e+1], p2 = pairs[e+2], p3 = pairs[e+3];
            unsigned u0 = ((const unsigned*)(sb + (size_t)p0.x * 128))[lane];
            unsigned u1 = ((const unsigned*)(sb + (size_t)p1.x * 128))[lane];
            unsigned u2 = ((const unsigned*)(sb + (size_t)p2.x * 128))[lane];
            unsigned u3 = ((const unsigned*)(sb + (size_t)p3.x * 128))[lane];
            float v0 = __int_as_float(p0.y), v1 = __int_as_float(p1.y);
            float v2 = __int_as_float(p2.y), v3 = __int_as_float(p3.y);
            float x0 = b2f(u0 & 0xffffu), x1 = b2f(u0 >> 16);
            float y0 = b2f(u1 & 0xffffu), y1 = b2f(u1 >> 16);
            float z0 = b2f(u2 & 0xffffu), z1 = b2f(u2 >> 16);
            float w0 = b2f(u3 & 0xffffu), w1 = b2f(u3 >> 16);
            if (RELU) {
                x0 = fmaxf(x0, 0.f); x1 = fmaxf(x1, 0.f);
                y0 = fmaxf(y0, 0.f); y1 = fmaxf(y1, 0.f);
                z0 = fmaxf(z0, 0.f); z1 = fmaxf(z1, 0.f);
                w0 = fmaxf(w0, 0.f); w1 = fmaxf(w1, 0.f);
            }
            ax = fmaf(v0, x0, ax); ay = fmaf(v0, x1, ay);
            bx = fmaf(v1, y0, bx); by = fmaf(v1, y1, by);
            cx = fmaf(v2, z0, cx); cy = fmaf(v2, z1, cy);
            dx = fmaf(v3, w0, dx); dy = fmaf(v3, w1, dy);
        }
        for (; e < e1; ++e) {
            int2 p = pairs[e];
            float v = __int_as_float(p.y);
            unsigned u = ((const unsigned*)(sb + (size_t)p.x * 128))[lane];
            float x0 = b2f(u & 0xffffu), x1 = b2f(u >> 16);
            if (RELU) { x0 = fmaxf(x0, 0.f); x1 = fmaxf(x1, 0.f); }
            ax = fmaf(v, x0, ax); ay = fmaf(v, x1, ay);
        }
    } else {
        const float* sf = (const float*)src;
        for (; e + 4 <= e1; e += 4) {
            int2 p0 = pairs[e], p1 = pairs[e+1], p2 = pairs[e+2], p3 = pairs[e+3];
            float2 x = ((const float2*)(sf + (size_t)p0.x * 128))[lane];
            float2 y = ((const float2*)(sf + (size_t)p1.x * 128))[lane];
            float2 z = ((const float2*)(sf + (size_t)p2.x * 128))[lane];
            float2 w = ((const float2*)(sf + (size_t)p3.x * 128))[lane];
            float v0 = __int_as_float(p0.y), v1 = __int_as_float(p1.y);
            float v2 = __int_as_float(p2.y), v3 = __int_as_float(p3.y);
            if (RELU) {
                x.x = fmaxf(x.x, 0.f); x.y = fmaxf(x.y, 0.f);
                y.x = fmaxf(y.x, 0.f); y.y = fmaxf(y.y, 0.f);
                z.x = fmaxf(z.x, 0.f); z.y = fmaxf(z.y, 0.f);
                w.x = fmaxf(w.x, 0.f); w.y = fmaxf(w.y, 0.f);
            }
            ax = fmaf(v0, x.x, ax); ay = fmaf(v0, x.y, ay);
            bx = fmaf(v1, y.x, bx); by = fmaf(v1, y.y, by);
            cx = fmaf(v2, z.x, cx); cy = fmaf(v2, z.y, cy);
            dx = fmaf(v3, w.x, dx); dy = fmaf(v3, w.y, dy);
        }
        for (; e < e1; ++e) {
            int2 p = pairs[e];
            float v = __int_as_float(p.y);
            float2 x = ((const float2*)(sf + (size_t)p.x * 128))[lane];
            if (RELU) { x.x = fmaxf(x.x, 0.f); x.y = fmaxf(x.y, 0.f); }
            ax = fmaf(v, x.x, ax); ay = fmaf(v, x.y, ay);
        }
    }
    float tx = (ax + bx) + (cx + dx);
    float ty = (ay + by) + (cy + dy);
    float ss = tx * tx + ty * ty;
    #pragma unroll
    for (int off = 32; off > 0; off >>= 1) ss += __shfl_down(ss, off);
    ss = __shfl(ss, 0);
    float inv = 1.0f / (sqrtf(ss) + 1e-9f);
    size_t base = elem_off + (size_t)row * 128;
    if (isb) {
        ((unsigned*)((bf16*)out + base))[lane] = f2b(tx * inv) | (f2b(ty * inv) << 16);
    } else {
        ((float2*)((float*)out + base))[lane] = make_float2(tx * inv, ty * inv);
    }
}

__device__ __forceinline__ void norm428_body(
        const int* __restrict__ rp, const int2* __restrict__ pairs,
        const void* __restrict__ src1, int s1b,
        const void* __restrict__ src2, int s2b,
        void* __restrict__ out, size_t elem_off, int row, int lane, int isb) {
    constexpr int P2 = D_WEMB / 2;   // 150
    int e0 = rp[row], e1 = rp[row + 1];
    float2 a1 = make_float2(0.f, 0.f), b1 = make_float2(0.f, 0.f);
    float2 a2[3], b2v[3];
    #pragma unroll
    for (int s = 0; s < 3; ++s) { a2[s] = make_float2(0.f, 0.f); b2v[s] = make_float2(0.f, 0.f); }
    int e = e0;
    for (; e + 2 <= e1; e += 2) {
        int2 p0 = pairs[e], p1 = pairs[e + 1];
        float v0 = __int_as_float(p0.y), v1 = __int_as_float(p1.y);
        float x0, x1, y0, y1;
        if (s1b) {
            unsigned u0 = ((const unsigned*)((const bf16*)src1 + (size_t)p0.x * DD))[lane];
            unsigned u1 = ((const unsigned*)((const bf16*)src1 + (size_t)p1.x * DD))[lane];
            x0 = b2f(u0 & 0xffffu); x1 = b2f(u0 >> 16);
            y0 = b2f(u1 & 0xffffu); y1 = b2f(u1 >> 16);
        } else {
            float2 x = ((const float2*)((const float*)src1 + (size_t)p0.x * DD))[lane];
            float2 y = ((const float2*)((const float*)src1 + (size_t)p1.x * DD))[lane];
            x0 = x.x; x1 = x.y; y0 = y.x; y1 = y.y;
        }
        x0 = fmaxf(x0, 0.f); x1 = fmaxf(x1, 0.f);
        y0 = fmaxf(y0, 0.f); y1 = fmaxf(y1, 0.f);
        a1.x = fmaf(v0, x0, a1.x); a1.y = fmaf(v0, x1, a1.y);
        b1.x = fmaf(v1, y0, b1.x); b1.y = fmaf(v1, y1, b1.y);
        if (s2b) {
            const unsigned* s0p = (const unsigned*)((const bf16*)src2 + (size_t)p0.x * D_WEMB);
            const unsigned* s1p = (const unsigned*)((const bf16*)src2 + (size_t)p1.x * D_WEMB);
            #pragma unroll
            for (int s = 0; s < 3; ++s) {
                int pi = lane + 64 * s;
                if (pi < P2) {
                    unsigned u0 = s0p[pi], u1 = s1p[pi];
                    a2[s].x  = fmaf(v0, b2f(u0 & 0xffffu), a2[s].x);
                    a2[s].y  = fmaf(v0, b2f(u0 >> 16),     a2[s].y);
                    b2v[s].x = fmaf(v1, b2f(u1 & 0xffffu), b2v[s].x);
                    b2v[s].y = fmaf(v1, b2f(u1 >> 16),     b2v[s].y);
                }
            }
        } else {
            const float2* s0p = (const float2*)((const float*)src2 + (size_t)p0.x * D_WEMB);
            const float2* s1p = (const float2*)((const float*)src2 + (size_t)p1.x * D_WEMB);
            #pragma unroll
            for (int s = 0; s < 3; ++s) {
                int pi = lane + 64 * s;
                if (pi < P2) {
                    float2 x = s0p[pi], y = s1p[pi];
                    a2[s].x  = fmaf(v0, x.x, a2[s].x);
                    a2[s].y  = fmaf(v0, x.y, a2[s].y);
                    b2v[s].x = fmaf(v1, y.x, b2v[s].x);
                    b2v[s].y = fmaf(v1, y.y, b2v[s].y);
                }
            }
        }
    }
    if (e < e1) {
        int2 p = pairs[e];
        float v = __int_as_float(p.y);
        float x0, x1;
        if (s1b) {
            unsigned u = ((const unsigned*)((const bf16*)src1 + (size_t)p.x * DD))[lane];
            x0 = b2f(u & 0xffffu); x1 = b2f(u >> 16);
        } else {
            float2 x = ((const float2*)((const float*)src1 + (size_t)p.x * DD))[lane];
            x0 = x.x; x1 = x.y;
        }
        x0 = fmaxf(x0, 0.f); x1 = fmaxf(x1, 0.f);
        a1.x = fmaf(v, x0, a1.x); a1.y = fmaf(v, x1, a1.y);
        if (s2b) {
            const unsigned* sp = (const unsigned*)((const bf16*)src2 + (size_t)p.x * D_WEMB);
            #pragma unroll
            for (int s = 0; s < 3; ++s) {
                int pi = lane + 64 * s;
                if (pi < P2) {
                    unsigned u = sp[pi];
                    a2[s].x = fmaf(v, b2f(u & 0xffffu), a2[s].x);
                    a2[s].y = fmaf(v, b2f(u >> 16),     a2[s].y);
                }
            }
        } else {
            const float2* sp = (const float2*)((const float*)src2 + (size_t)p.x * D_WEMB);
            #pragma unroll
            for (int s = 0; s < 3; ++s) {
                int pi = lane + 64 * s;
                if (pi < P2) {
                    float2 x = sp[pi];
                    a2[s].x = fmaf(v, x.x, a2[s].x);
                    a2[s].y = fmaf(v, x.y, a2[s].y);
                }
            }
        }
    }
    float t1x = a1.x + b1.x, t1y = a1.y + b1.y;
    float t2x[3], t2y[3];
    #pragma unroll
    for (int s = 0; s < 3; ++s) { t2x[s] = a2[s].x + b2v[s].x; t2y[s] = a2[s].y + b2v[s].y; }
    float ss = t1x * t1x + t1y * t1y;
    #pragma unroll
    for (int s = 0; s < 3; ++s) {
        int pi = lane + 64 * s;
        if (pi < P2) ss += t2x[s] * t2x[s] + t2y[s] * t2y[s];
    }
    #pragma unroll
    for (int off = 32; off > 0; off >>= 1) ss += __shfl_down(ss, off);
    ss = __shfl(ss, 0);
    float inv = 1.0f / (sqrtf(ss) + 1e-9f);
    size_t base = elem_off + (size_t)row * (DD + D_WEMB);
    if (isb) {
        ((unsigned*)((bf16*)out + base))[lane] = f2b(t1x * inv) | (f2b(t1y * inv) << 16);
        unsigned* o2 = (unsigned*)((bf16*)out + base + DD);
        #pragma unroll
        for (int s = 0; s < 3; ++s) {
            int pi = lane + 64 * s;
            if (pi < P2) o2[pi] = f2b(t2x[s] * inv) | (f2b(t2y[s] * inv) << 16);
        }
    } else {
        ((float2*)((float*)out + base))[lane] = make_float2(t1x * inv, t1y * inv);
        float2* o2 = (float2*)((float*)out + base + DD);
        #pragma unroll
        for (int s = 0; s < 3; ++s) {
            int pi = lane + 64 * s;
            if (pi < P2) o2[pi] = make_float2(t2x[s] * inv, t2y[s] * inv);
        }
    }
}

// ======================= gather kernels =======================
// Single-task (mid path + type-3 chain).
template<bool RELU>
__global__ void spmm_gather128(const int* __restrict__ rowptr, const int2* __restrict__ pairs,
                               const void* __restrict__ src, int src_flagged,
                               void* __restrict__ dst, int dst_flagged,
                               int n, const int* __restrict__ dflag) {
    int row = blockIdx.x * 4 + (threadIdx.x >> 6);
    if (row >= n) return;
    int isb = *dflag;
    gather128_body<RELU>(rowptr, pairs, src, src_flagged ? isb : 0,
                         dst, dst_flagged ? isb : 0, row, threadIdx.x & 63);
}

// Two-task batch (BIG path hops).
template<bool RELU>
__global__ void spmm_gather128_b2(const int* __restrict__ G, const int2* __restrict__ pairs,
                                  int roff1, const void* __restrict__ src1, void* __restrict__ dst1, int n1, int B1,
                                  int roff2, const void* __restrict__ src2, void* __restrict__ dst2, int n2,
                                  int src_flagged, int dst_flagged, const int* __restrict__ dflag) {
    int isb = *dflag;
    int sisb = src_flagged ? isb : 0;
    int disb = dst_flagged ? isb : 0;
    int lane = threadIdx.x & 63;
    int b = blockIdx.x;
    if (b < B1) {
        int row = b * 4 + (threadIdx.x >> 6);
        if (row >= n1) return;
        gather128_body<RELU>(G + roff1, pairs, src1, sisb, dst1, disb, row, lane);
    } else {
        int row = (b - B1) * 4 + (threadIdx.x >> 6);
        if (row >= n2) return;
        gather128_body<RELU>(G + roff2, pairs, src2, sisb, dst2, disb, row, lane);
    }
}

// Mid-path norm kernels.
template<bool RELU>
__global__ void spmm_norm128(const int* __restrict__ rowptr, const int2* __restrict__ pairs,
                             const void* __restrict__ src, int src_flagged,
                             void* __restrict__ out, size_t elem_off,
                             int n, const int* __restrict__ dflag) {
    int row = blockIdx.x * 4 + (threadIdx.x >> 6);
    if (row >= n) return;
    int isb = *dflag;
    norm128_body<RELU>(rowptr, pairs, src, src_flagged ? isb : 0, out, elem_off,
                       row, threadIdx.x & 63, isb);
}

__global__ void spmm2_norm(const int* __restrict__ rowptr, const int2* __restrict__ pairs,
                           const void* __restrict__ src1, int s1_flagged,
                           const void* __restrict__ src2, int s2_flagged,
                           void* __restrict__ out, size_t elem_off,
                           int n, const int* __restrict__ dflag) {
    int row = blockIdx.x * 4 + (threadIdx.x >> 6);
    if (row >= n) return;
    int isb = *dflag;
    norm428_body(rowptr, pairs, src1, s1_flagged ? isb : 0, src2, s2_flagged ? isb : 0,
                 out, elem_off, row, threadIdx.x & 63, isb);
}

// BIG path: all 3 output norms in ONE launch. Blocks [0,2500)=out1, [2500,5000)=out2,
// [5000,7500)=out3. Per-block uniform branch.
__global__ void final_norm_all(const int* __restrict__ G, const int2* __restrict__ pairs,
                               const void* __restrict__ s1, const void* __restrict__ e0b,
                               const void* __restrict__ wemb, const void* __restrict__ p3b,
                               void* __restrict__ out,
                               size_t off1, size_t off2, size_t off3,
                               const int* __restrict__ dflag) {
    int isb = *dflag;
    int lane = threadIdx.x & 63;
    int b = blockIdx.x;
    if (b < 2500) {
        int row = b * 4 + (threadIdx.x >> 6);
        if (row >= N_DOC) return;
        norm128_body<true>(G + ROFF01, pairs, s1, isb, out, off1, row, lane, isb);
    } else if (b < 5000) {
        int row = (b - 2500) * 4 + (threadIdx.x >> 6);
        if (row >= N_DOC) return;
        norm428_body(G + ROFF02, pairs, e0b, isb, wemb, isb, out, off2, row, lane, isb);
    } else {
        int row = (b - 5000) * 4 + (threadIdx.x >> 6);
        if (row >= N_DOC) return;
        norm128_body<true>(G + ROFF03, pairs, p3b, isb, out, off3, row, lane, isb);
    }
}

// ======================= atomic SpMM (deep fallback) =======================
template<bool RELU>
__global__ void spmm_kernel(const int* __restrict__ rows, const int* __restrict__ cols,
                            const void* __restrict__ vals,
                            const void* __restrict__ src, int sstride, int src_flagged,
                            float* __restrict__ dst, int dstride, int doff,
                            int d, int nE, const int* __restrict__ dflag) {
    int e = blockIdx.x * (blockDim.x >> 6) + (threadIdx.x >> 6);
    if (e >= nE) return;
    int isb  = *dflag;
    int sisb = src_flagged ? isb : 0;
    int lane = threadIdx.x & 63;
    int r = rows[e];
    int c = cols[e];
    float v = loadf(vals, e, isb);
    size_t sbase = (size_t)c * sstride;
    float* dp = dst + (size_t)r * dstride + doff;
    if (sisb) {
        const unsigned* sp = (const unsigned*)((const bf16*)src + sbase);
        for (int j = 2 * lane; j < d; j += 128) {
            unsigned u = sp[j >> 1];
            float x0 = b2f(u & 0xffffu);
            float x1 = b2f(u >> 16);
            if (RELU) { x0 = fmaxf(x0, 0.f); x1 = fmaxf(x1, 0.f); }
            atomicAdd(dp + j,     v * x0);
            atomicAdd(dp + j + 1, v * x1);
        }
    } else {
        const float2* sp = (const float2*)((const float*)src + sbase);
        for (int j = 2 * lane; j < d; j += 128) {
            float2 x = sp[j >> 1];
            if (RELU) { x.x = fmaxf(x.x, 0.f); x.y = fmaxf(x.y, 0.f); }
            atomicAdd(dp + j,     v * x.x);
            atomicAdd(dp + j + 1, v * x.y);
        }
    }
}

// ======================= dense GEMMs =======================
// Body: X fp32, out/W/b follow isb. One 32-col tile per block (bx=row tile, by=col tile).
template<bool RELU>
__device__ __forceinline__ void gemm_tile_body(
        const float* __restrict__ X, const void* __restrict__ W,
        const void* __restrict__ b, void* __restrict__ out, int n,
        int bx, int by, int isb, float* Wl) {
    if (bx * 64 >= n) return;                 // pad block; uniform per block
    int tid = threadIdx.x;
    int jc = by * 32;
    if (isb) {
        const uint2* Wg = (const uint2*)W;
        float4* Wl4 = (float4*)Wl;
        for (int vidx = tid; vidx < 1024; vidx += 256) {
            int k = vidx >> 3, jl4 = vidx & 7;
            uint2 u = Wg[k * 32 + (jc >> 2) + jl4];
            float4 vv;
            vv.x = b2f(u.x & 0xffffu);
            vv.y = b2f(u.x >> 16);
            vv.z = b2f(u.y & 0xffffu);
            vv.w = b2f(u.y >> 16);
            Wl4[vidx] = vv;
        }
    } else {
        const float4* Wg = (const float4*)W;
        float4* Wl4 = (float4*)Wl;
        for (int vidx = tid; vidx < 1024; vidx += 256) {
            int k = vidx >> 3, jl4 = vidx & 7;
            Wl4[vidx] = Wg[k * 32 + (jc >> 2) + jl4];
        }
    }
    __syncthreads();
    int j = tid & 31;
    int g = tid >> 5;
    float bj = loadf(b, jc + j, isb);
    int i0 = bx * 64 + g * 8;
    float a[8];
    #pragma unroll
    for (int r = 0; r < 8; ++r) a[r] = bj;
    const float4* xp = (const float4*)(X + (size_t)i0 * 128);
    #pragma unroll 2
    for (int k4 = 0; k4 < 32; ++k4) {
        float w0 = Wl[(4 * k4 + 0) * 32 + j];
        float w1 = Wl[(4 * k4 + 1) * 32 + j];
        float w2 = Wl[(4 * k4 + 2) * 32 + j];
        float w3 = Wl[(4 * k4 + 3) * 32 + j];
        #pragma unroll
        for (int r = 0; r < 8; ++r) {
            float4 v = xp[r * 32 + k4];
            if (RELU) {
                v.x = fmaxf(v.x, 0.f); v.y = fmaxf(v.y, 0.f);
                v.z = fmaxf(v.z, 0.f); v.w = fmaxf(v.w, 0.f);
            }
            a[r] = fmaf(v.w, w3, fmaf(v.z, w2, fmaf(v.y, w1, fmaf(v.x, w0, a[r]))));
        }
    }
    #pragma unroll
    for (int r = 0; r < 8; ++r) {
        int i = i0 + r;
        if (i < n) storef(out, (size_t)i * 128 + jc + j, isb, a[r]);
    }
}

template<bool RELU>
__global__ __launch_bounds__(256) void gemm_tile(
        const float* __restrict__ X, const void* __restrict__ W,
        const void* __restrict__ b, void* __restrict__ out, int n,
        const int* __restrict__ dflag) {
    __shared__ float Wl[128 * 32];
    gemm_tile_body<RELU>(X, W, b, out, n, blockIdx.x, blockIdx.y, *dflag, Wl);
}

// Two-task batched GEMM (BIG path): blocks [0,G1) -> task1, [G1,G1+G2) -> task2.
template<bool RELU>
__global__ __launch_bounds__(256) void gemm_tile_b2(
        const float* __restrict__ X1, const void* __restrict__ W1, const void* __restrict__ b1,
        void* __restrict__ out1, int n1, int G1,
        const float* __restrict__ X2, const void* __restrict__ W2, const void* __restrict__ b2,
        void* __restrict__ out2, int n2,
        const int* __restrict__ dflag) {
    __shared__ float Wl[128 * 32];
    int isb = *dflag;
    if ((int)blockIdx.x < G1)
        gemm_tile_body<RELU>(X1, W1, b1, out1, n1, blockIdx.x, blockIdx.y, isb, Wl);
    else
        gemm_tile_body<RELU>(X2, W2, b2, out2, n2, blockIdx.x - G1, blockIdx.y, isb, Wl);
}

// Legacy big-LDS GEMM (deep fallback only; fp32 ws).
template<bool RELU>
__global__ __launch_bounds__(256) void gemm128_kernel(
        const float* __restrict__ X, const void* __restrict__ W,
        const void* __restrict__ b, float* __restrict__ out, int n,
        const int* __restrict__ dflag) {
    __shared__ float Wl[128 * 128];
    int isb = *dflag;
    int tid = threadIdx.x;
    if (isb) {
        const uint2* Wg = (const uint2*)W;
        float4* Wl4 = (float4*)Wl;
        for (int idx = tid; idx < 4096; idx += 256) {
            uint2 u = Wg[idx];
            float4 vv;
            vv.x = b2f(u.x & 0xffffu);
            vv.y = b2f(u.x >> 16);
            vv.z = b2f(u.y & 0xffffu);
            vv.w = b2f(u.y >> 16);
            Wl4[idx] = vv;
        }
    } else {
        const float4* Wg = (const float4*)W;
        float4* Wl4 = (float4*)Wl;
        for (int idx = tid; idx < 4096; idx += 256) Wl4[idx] = Wg[idx];
    }
    __syncthreads();
    int j = tid & 127;
    int h = tid >> 7;
    float bj = loadf(b, j, isb);
    int row0 = blockIdx.x * 64 + h * 32;
    for (int q = 0; q < 8; ++q) {
        int gi = row0 + q * 4;
        if (gi >= n) break;
        const float4* x0 = (const float4*)(X + (size_t)gi * 128);
        const float4* x1 = x0 + 32;
        const float4* x2 = x1 + 32;
        const float4* x3 = x2 + 32;
        float a0 = bj, a1 = bj, a2 = bj, a3 = bj;
        #pragma unroll 4
        for (int k4 = 0; k4 < 32; ++k4) {
            float4 v0 = x0[k4], v1 = x1[k4], v2 = x2[k4], v3 = x3[k4];
            if (RELU) {
                v0.x = fmaxf(v0.x, 0.f); v0.y = fmaxf(v0.y, 0.f); v0.z = fmaxf(v0.z, 0.f); v0.w = fmaxf(v0.w, 0.f);
                v1.x = fmaxf(v1.x, 0.f); v1.y = fmaxf(v1.y, 0.f); v1.z = fmaxf(v1.z, 0.f); v1.w = fmaxf(v1.w, 0.f);
                v2.x = fmaxf(v2.x, 0.f); v2.y = fmaxf(v2.y, 0.f); v2.z = fmaxf(v2.z, 0.f); v2.w = fmaxf(v2.w, 0.f);
                v3.x = fmaxf(v3.x, 0.f); v3.y = fmaxf(v3.y, 0.f); v3.z = fmaxf(v3.z, 0.f); v3.w = fmaxf(v3.w, 0.f);
            }
            float w0 = Wl[(4 * k4 + 0) * 128 + j];
            float w1 = Wl[(4 * k4 + 1) * 128 + j];
            float w2 = Wl[(4 * k4 + 2) * 128 + j];
            float w3 = Wl[(4 * k4 + 3) * 128 + j];
            a0 = fmaf(v0.w, w3, fmaf(v0.z, w2, fmaf(v0.y, w1, fmaf(v0.x, w0, a0))));
            a1 = fmaf(v1.w, w3, fmaf(v1.z, w2, fmaf(v1.y, w1, fmaf(v1.x, w0, a1))));
            a2 = fmaf(v2.w, w3, fmaf(v2.z, w2, fmaf(v2.y, w1, fmaf(v2.x, w0, a2))));
            a3 = fmaf(v3.w, w3, fmaf(v3.z, w2, fmaf(v3.y, w1, fmaf(v3.x, w0, a3))));
        }
        float* o = out + (size_t)gi * 128 + j;
        o[0] = a0; o[128] = a1; o[256] = a2; o[384] = a3;
    }
}

// Row-parallel tiny GEMM (type-3, n=60): one block per row, 128 threads.
template<bool RELU, int K>
__global__ void rowpar_gemm(const void* __restrict__ X, int x_flagged,
                            const void* __restrict__ W, const void* __restrict__ b,
                            void* __restrict__ out, int out_flagged,
                            const int* __restrict__ dflag) {
    __shared__ float xr[K];
    int isb  = *dflag;
    int xisb = x_flagged ? isb : 0;
    int oisb = out_flagged ? isb : 0;
    int row = blockIdx.x;
    int j = threadIdx.x;
    if (j < K) {
        float x = loadf(X, (size_t)row * K + j, xisb);
        if (RELU) x = fmaxf(x, 0.f);
        xr[j] = x;
    }
    __syncthreads();
    float acc = loadf(b, j, isb);
    #pragma unroll 8
    for (int k = 0; k < K; ++k)
        acc = fmaf(xr[k], loadf(W, (size_t)k * 128 + j, isb), acc);
    storef(out, (size_t)row * 128 + j, oisb, acc);
}

// Generic small GEMM (deep fallback only).
template<bool RELU, int K>
__global__ void gemm_kernel(const void* __restrict__ X, int x_flagged,
                            const void* __restrict__ W,
                            const void* __restrict__ b,
                            float* __restrict__ out, int n,
                            const int* __restrict__ dflag) {
    __shared__ float Wl[K * 128];
    int isb  = *dflag;
    int xisb = x_flagged ? isb : 0;
    int j = threadIdx.x;
    for (int idx = j; idx < K * 128; idx += 128)
        Wl[idx] = loadf(W, idx, isb);
    __syncthreads();
    float bj = loadf(b, j, isb);
    int row0 = blockIdx.x * 64;
    for (int i0 = 0; i0 < 64; i0 += 4) {
        int i = row0 + i0;
        if (i >= n) break;
        size_t r0 = (size_t)i * K;
        float a0 = bj, a1 = bj, a2 = bj, a3 = bj;
        for (int k = 0; k < K; ++k) {
            float w = Wl[k * 128 + j];
            float v0 = loadf(X, r0 + k, xisb);
            float v1 = loadf(X, r0 + K + k, xisb);
            float v2 = loadf(X, r0 + 2 * K + k, xisb);
            float v3 = loadf(X, r0 + 3 * K + k, xisb);
            if (RELU) {
                v0 = fmaxf(v0, 0.f); v1 = fmaxf(v1, 0.f);
                v2 = fmaxf(v2, 0.f); v3 = fmaxf(v3, 0.f);
            }
            a0 = fmaf(v0, w, a0);
            a1 = fmaf(v1, w, a1);
            a2 = fmaf(v2, w, a2);
            a3 = fmaf(v3, w, a3);
        }
        float* o = out + (size_t)i * 128 + j;
        o[0] = a0; o[128] = a1; o[256] = a2; o[384] = a3;
    }
}

// L2-norm (deep fallback only).
__global__ void l2norm_kernel(const float* __restrict__ agg, int d,
                              void* __restrict__ out, size_t elem_off, int n,
                              const int* __restrict__ dflag) {
    int row = blockIdx.x * (blockDim.x >> 6) + (threadIdx.x >> 6);
    if (row >= n) return;
    int isb  = *dflag;
    int lane = threadIdx.x & 63;
    const float2* a2 = (const float2*)(agg + (size_t)row * d);
    float ss = 0.f;
    for (int j = 2 * lane; j < d; j += 128) {
        float2 x = a2[j >> 1];
        ss += x.x * x.x + x.y * x.y;
    }
    #pragma unroll
    for (int off = 32; off > 0; off >>= 1) ss += __shfl_down(ss, off);
    ss = __shfl(ss, 0);
    float inv = 1.0f / (sqrtf(ss) + 1e-9f);
    size_t bbase = elem_off + (size_t)row * d;
    if (isb) {
        unsigned* o = (unsigned*)((bf16*)out + bbase);
        for (int j = 2 * lane; j < d; j += 128) {
            float2 x = a2[j >> 1];
            o[j >> 1] = f2b(x.x * inv) | (f2b(x.y * inv) << 16);
        }
    } else {
        float2* o = (float2*)((float*)out + bbase);
        for (int j = 2 * lane; j < d; j += 128) {
            float2 x = a2[j >> 1];
            o[j >> 1] = make_float2(x.x * inv, x.y * inv);
        }
    }
}

static inline int spmm_grid(int nE) { return (nE + 3) / 4; }
static inline int row_grid(int n)   { return (n + 3) / 4; }
static inline int pad8(int x)       { return (x + 7) & ~7; }

// Mid-path per-phase CSR build.
static void build2(hipStream_t stream,
                   const int* rowsA, const int* colsA, const void* valsA, int nA, int nEA,
                   const int* rowsB, const int* colsB, const void* valsB, int nB, int nEB,
                   int* rpA, int* rpB, int* curAB, int2* pairsA, int2* pairsB,
                   const int* dflag) {
    int nE = nEA + nEB;
    hipMemsetAsync(curAB, 0, (size_t)(nA + nB) * 4, stream);
    hist2_kernel<<<(nE + 255) / 256, 256, 0, stream>>>(rowsA, nEA, rowsB, nEB, nA, curAB);
    scan2_kernel<<<1, 1024, 0, stream>>>(curAB, rpA, nA, curAB + nA, rpB, nB);
    copy2_kernel<<<(nA + nB + 255) / 256, 256, 0, stream>>>(rpA, rpB, nA, nB, curAB);
    scatter2_kernel<<<(nE + 255) / 256, 256, 0, stream>>>(
        rowsA, colsA, valsA, nEA, rowsB, colsB, valsB, nEB, nA, curAB, pairsA, pairsB, dflag);
}

extern "C" void kernel_launch(void* const* d_in, const int* in_sizes, int n_in,
                              void* d_out, int out_size, void* d_ws, size_t ws_size,
                              hipStream_t stream) {
    const void* f1   = d_in[0];
    const void* f2   = d_in[1];
    const void* f3   = d_in[2];
    const void* wemb = d_in[3];
    const int*  a11r = (const int*)d_in[4];
    const int*  a11c = (const int*)d_in[5];
    const void* a11v = d_in[6];
    const int*  a22r = (const int*)d_in[7];
    const int*  a22c = (const int*)d_in[8];
    const void* a22v = d_in[9];
    const int*  a33r = (const int*)d_in[10];
    const int*  a33c = (const int*)d_in[11];
    const void* a33v = d_in[12];
    const int*  a01r = (const int*)d_in[13];
    const int*  a01c = (const int*)d_in[14];
    const void* a01v = d_in[15];
    const int*  a02r = (const int*)d_in[16];
    const int*  a02c = (const int*)d_in[17];
    const void* a02v = d_in[18];
    const int*  a03r = (const int*)d_in[19];
    const int*  a03c = (const int*)d_in[20];
    const void* a03v = d_in[21];
    const void* W3   = d_in[22];
    const void* b3   = d_in[23];
    const void* W1_2 = d_in[24];
    const void* b1_2 = d_in[25];
    const void* W2_2 = d_in[26];
    const void* b2_2 = d_in[27];
    const void* W3_2 = d_in[28];
    const void* b3_2 = d_in[29];

    int*   dflag = (int*)d_ws;
    float* base  = (float*)d_ws + 16;

    const size_t OUT1_OFF = 0;
    const size_t OUT2_OFF = (size_t)N_DOC * DD;                       // 1,280,000
    const size_t OUT3_OFF = OUT2_OFF + (size_t)N_DOC * (DD + D_WEMB); // 5,560,000

    dim3 blk(256);
    detect_kernel<<<1, 256, 0, stream>>>((const unsigned*)f1, dflag);

    // BIG layout (fp32-world worst case): S0 2.56M | S1 2.56M | E0 1.28M | E1 1.28M |
    // P3a/P3b 7680+7680 | ints: G 60061 + cur 60060 + pairs 2*NEDGES
    const size_t BF_S0 = 0, BF_S1 = 2560000, BF_E0 = 5120000, BF_E1 = 6400000;
    const size_t BF_P3A = 7680000, BF_P3B = 7687680, BF_INT = 7695360;
    const size_t BIG_INTS = 60061ull + 60060ull + 2ull * NEDGES;      // 2,187,321
    const size_t WS_BIG = 64 + (BF_INT + BIG_INTS + 8) * 4;           // ~39.5 MB
    const size_t WS_MID = 64 + 22240000ull + 240008ull + 4960000ull;  // ~27.44 MB

    if (ws_size >= WS_BIG) {
        // ======================= BIG batched path =======================
        float* S0  = base + BF_S0;   // fp32 hop1 out / bf16 hop2 out
        float* S1  = base + BF_S1;
        float* E0  = base + BF_E0;
        float* E1  = base + BF_E1;
        float* P3a = base + BF_P3A;
        float* P3b = base + BF_P3B;
        int*   G    = (int*)(base + BF_INT);          // NROWS+1 global scan
        int*   cur  = G + (NROWS + 1);                // NROWS cursors
        int2*  pairs = (int2*)(cur + NROWS + 1);      // +1 pad keeps 8B alignment

        // ---- fused build (5 dispatches) ----
        hipMemsetAsync(cur, 0, (size_t)NROWS * 4, stream);
        hist_all<<<(NEDGES + 255) / 256, 256, 0, stream>>>(
            a11r, a22r, a33r, a01r, a02r, a03r, cur);
        scan_all<<<1, 1024, 0, stream>>>(cur, G);
        copy_all<<<(NROWS + 255) / 256, 256, 0, stream>>>(G, cur);
        scatter_all<<<(NEDGES + 255) / 256, 256, 0, stream>>>(
            a11r, a11c, a11v, a22r, a22c, a22v, a33r, a33c, a33v,
            a01r, a01c, a01v, a02r, a02c, a02v, a03r, a03c, a03v,
            cur, pairs, dflag);

        // ---- type-3 first dense layer (independent; tiny) ----
        rowpar_gemm<false, 60><<<N_POS, 128, 0, stream>>>(
            f3, 1, W3, b3, P3a, 1, dflag);                              // P3a = f3@W3+b3

        // ---- hop1 batch: S0 = A11@f1, E0 = A22@f2 (fp32 out) ----
        {
            int B1 = row_grid(N_WORD), B2 = row_grid(N_ENT);
            spmm_gather128_b2<false><<<B1 + B2, blk, 0, stream>>>(
                G, pairs, ROFF11, f1, S0, N_WORD, B1,
                ROFF22, f2, E0, N_ENT, 1, 0, dflag);
        }
        // ---- gemm batch: S1 = relu(S0)@W1_2+b, E1 = relu(E0)@W2_2+b ----
        {
            int G1 = pad8((N_WORD + 63) / 64), G2 = pad8((N_ENT + 63) / 64);
            gemm_tile_b2<true><<<dim3(G1 + G2, 4), 256, 0, stream>>>(
                S0, W1_2, b1_2, S1, N_WORD, G1,
                E0, W2_2, b2_2, E1, N_ENT, dflag);
        }
        // ---- hop2 batch: S0b = A11@S1, E0b = A22@E1 (flagged out) ----
        {
            int B1 = row_grid(N_WORD), B2 = row_grid(N_ENT);
            spmm_gather128_b2<false><<<B1 + B2, blk, 0, stream>>>(
                G, pairs, ROFF11, S1, S0, N_WORD, B1,
                ROFF22, E1, E0, N_ENT, 1, 1, dflag);
        }
        // ---- type-3 chain (tiny) ----
        spmm_gather128<false><<<row_grid(N_POS), blk, 0, stream>>>(
            G + ROFF33, pairs, P3a, 1, P3b, 1, N_POS, dflag);           // P3b = A33@P3a
        rowpar_gemm<true, 128><<<N_POS, 128, 0, stream>>>(
            P3b, 1, W3_2, b3_2, P3a, 1, dflag);                         // P3a = relu(P3b)@W+b
        spmm_gather128<false><<<row_grid(N_POS), blk, 0, stream>>>(
            G + ROFF33, pairs, P3a, 1, P3b, 1, N_POS, dflag);           // P3b = A33@P3a

        // ---- all three output norms in ONE launch ----
        final_norm_all<<<7500, blk, 0, stream>>>(
            G, pairs, S0, E0, wemb, P3b, d_out, OUT1_OFF, OUT2_OFF, OUT3_OFF, dflag);
    } else if (ws_size >= WS_MID) {
        // ======================= mid path (R12 structure) =======================
        float* S0   = base;
        float* S1   = base + 2560000;
        float* E0   = base;
        float* E1   = base + 1280000;
        float* P3a  = base;
        float* P3b  = base + 7680;
        int* I = (int*)(base + 5560000);
        // type 1
        {
            int* rpA = I; int* rpB = rpA + (N_WORD + 1); int* cur = rpB + (N_DOC + 1);
            int2* pA = (int2*)(cur + N_WORD + N_DOC); int2* pB = pA + E11;
            build2(stream, a11r, a11c, a11v, N_WORD, E11,
                   a01r, a01c, a01v, N_DOC, E01, rpA, rpB, cur, pA, pB, dflag);
            spmm_gather128<false><<<row_grid(N_WORD), blk, 0, stream>>>(
                rpA, pA, f1, 1, S0, 0, N_WORD, dflag);
            gemm_tile<true><<<dim3(pad8((N_WORD + 63) / 64), 4), 256, 0, stream>>>(
                S0, W1_2, b1_2, S1, N_WORD, dflag);
            spmm_gather128<false><<<row_grid(N_WORD), blk, 0, stream>>>(
                rpA, pA, S1, 1, S0, 1, N_WORD, dflag);
            spmm_norm128<true><<<row_grid(N_DOC), blk, 0, stream>>>(
                rpB, pB, S0, 1, d_out, OUT1_OFF, N_DOC, dflag);
        }
        // type 2
        {
            int* rpA = I; int* rpB = rpA + (N_ENT + 1); int* cur = rpB + (N_DOC + 1);
            int2* pA = (int2*)(cur + N_ENT + N_DOC); int2* pB = pA + E22;
            build2(stream, a22r, a22c, a22v, N_ENT, E22,
                   a02r, a02c, a02v, N_DOC, E02, rpA, rpB, cur, pA, pB, dflag);
            spmm_gather128<false><<<row_grid(N_ENT), blk, 0, stream>>>(
                rpA, pA, f2, 1, E0, 0, N_ENT, dflag);
            gemm_tile<true><<<dim3(pad8((N_ENT + 63) / 64), 4), 256, 0, stream>>>(
                E0, W2_2, b2_2, E1, N_ENT, dflag);
            spmm_gather128<false><<<row_grid(N_ENT), blk, 0, stream>>>(
                rpA, pA, E1, 1, E0, 1, N_ENT, dflag);
            spmm2_norm<<<row_grid(N_DOC), blk, 0, stream>>>(
                rpB, pB, E0, 1, wemb, 1, d_out, OUT2_OFF, N_DOC, dflag);
        }
        // type 3
        {
            int* rpA = I; int* rpB = rpA + (N_POS + 1); int* cur = rpB + (N_DOC + 1);
            int2* pA = (int2*)(cur + N_POS + N_DOC); int2* pB = pA + E33;
            build2(stream, a33r, a33c, a33v, N_POS, E33,
                   a03r, a03c, a03v, N_DOC, E03, rpA, rpB, cur, pA, pB, dflag);
            rowpar_gemm<false, 60><<<N_POS, 128, 0, stream>>>(
                f3, 1, W3, b3, P3a, 1, dflag);
            spmm_gather128<false><<<row_grid(N_POS), blk, 0, stream>>>(
                rpA, pA, P3a, 1, P3b, 1, N_POS, dflag);
            rowpar_gemm<true, 128><<<N_POS, 128, 0, stream>>>(
                P3b, 1, W3_2, b3_2, P3a, 1, dflag);
            spmm_gather128<false><<<row_grid(N_POS), blk, 0, stream>>>(
                rpA, pA, P3a, 1, P3b, 1, N_POS, dflag);
            spmm_norm128<true><<<row_grid(N_DOC), blk, 0, stream>>>(
                rpB, pB, P3b, 1, d_out, OUT3_OFF, N_DOC, dflag);
        }
    } else {
        // ======================= deep fallback: atomic path =======================
        float* S0   = base;
        float* S1   = base + 2560000;
        float* AGG1 = S1;
        float* E0   = base;
        float* E1   = base + 1280000;
        float* AGG2 = base + 1280000;
        float* P3a  = base;
        float* P3b  = base + 7680;
        float* AGG3 = base + 15360;
        hipMemsetAsync(S0, 0, (size_t)N_WORD * DD * 4, stream);
        spmm_kernel<false><<<spmm_grid(E11), blk, 0, stream>>>(
            a11r, a11c, a11v, f1, DD, 1, S0, DD, 0, DD, E11, dflag);
        gemm128_kernel<true><<<(N_WORD + 63) / 64, 256, 0, stream>>>(
            S0, W1_2, b1_2, S1, N_WORD, dflag);
        hipMemsetAsync(S0, 0, (size_t)N_WORD * DD * 4, stream);
        spmm_kernel<false><<<spmm_grid(E11), blk, 0, stream>>>(
            a11r, a11c, a11v, S1, DD, 0, S0, DD, 0, DD, E11, dflag);
        hipMemsetAsync(AGG1, 0, (size_t)N_DOC * DD * 4, stream);
        spmm_kernel<true><<<spmm_grid(E01), blk, 0, stream>>>(
            a01r, a01c, a01v, S0, DD, 0, AGG1, DD, 0, DD, E01, dflag);
        l2norm_kernel<<<row_grid(N_DOC), blk, 0, stream>>>(
            AGG1, DD, d_out, OUT1_OFF, N_DOC, dflag);

        hipMemsetAsync(E0, 0, (size_t)N_ENT * DD * 4, stream);
        spmm_kernel<false><<<spmm_grid(E22), blk, 0, stream>>>(
            a22r, a22c, a22v, f2, DD, 1, E0, DD, 0, DD, E22, dflag);
        gemm128_kernel<true><<<(N_ENT + 63) / 64, 256, 0, stream>>>(
            E0, W2_2, b2_2, E1, N_ENT, dflag);
        hipMemsetAsync(E0, 0, (size_t)N_ENT * DD * 4, stream);
        spmm_kernel<false><<<spmm_grid(E22), blk, 0, stream>>>(
            a22r, a22c, a22v, E1, DD, 0, E0, DD, 0, DD, E22, dflag);
        hipMemsetAsync(AGG2, 0, (size_t)N_DOC * (DD + D_WEMB) * 4, stream);
        spmm_kernel<true><<<spmm_grid(E02), blk, 0, stream>>>(
            a02r, a02c, a02v, E0, DD, 0, AGG2, DD + D_WEMB, 0, DD, E02, dflag);
        spmm_kernel<false><<<spmm_grid(E02), blk, 0, stream>>>(
            a02r, a02c, a02v, wemb, D_WEMB, 1, AGG2, DD + D_WEMB, DD, D_WEMB, E02, dflag);
        l2norm_kernel<<<row_grid(N_DOC), blk, 0, stream>>>(
            AGG2, DD + D_WEMB, d_out, OUT2_OFF, N_DOC, dflag);

        gemm_kernel<false, 60><<<1, 128, 0, stream>>>(f3, 1, W3, b3, P3a, N_POS, dflag);
        hipMemsetAsync(P3b, 0, (size_t)N_POS * DD * 4, stream);
        spmm_kernel<false><<<spmm_grid(E33), blk, 0, stream>>>(
            a33r, a33c, a33v, P3a, DD, 0, P3b, DD, 0, DD, E33, dflag);
        gemm128_kernel<true><<<1, 256, 0, stream>>>(
            P3b, W3_2, b3_2, P3a, N_POS, dflag);
        hipMemsetAsync(P3b, 0, (size_t)N_POS * DD * 4, stream);
        spmm_kernel<false><<<spmm_grid(E33), blk, 0, stream>>>(
            a33r, a33c, a33v, P3a, DD, 0, P3b, DD, 0, DD, E33, dflag);
        hipMemsetAsync(AGG3, 0, (size_t)N_DOC * DD * 4, stream);
        spmm_kernel<true><<<spmm_grid(E03), blk, 0, stream>>>(
            a03r, a03c, a03v, P3b, DD, 0, AGG3, DD, 0, DD, E03, dflag);
        l2norm_kernel<<<row_grid(N_DOC), blk, 0, stream>>>(
            AGG3, DD, d_out, OUT3_OFF, N_DOC, dflag);
    }
}

// Round 14
// 482.078 us; speedup vs baseline: 1.3567x; 1.0703x over previous
//
#include <hip/hip_runtime.h>
#include <hip/hip_bf16.h>

typedef __hip_bfloat16 bf16;

#define N_DOC   10000
#define N_WORD  20000
#define N_ENT   10000
#define N_POS   60
#define DD      128
#define D_WEMB  300
#define E11     320000
#define E22     160000
#define E33     3600
#define E01     300000
#define E02     100000
#define E03     150000

// Concatenated row/edge segment offsets for the fused 6-matrix CSR build.
#define ROFF11  0
#define ROFF22  20000
#define ROFF33  30000
#define ROFF01  30060
#define ROFF02  40060
#define ROFF03  50060
#define NROWS   60060
#define EOFF11  0
#define EOFF22  320000
#define EOFF33  480000
#define EOFF01  483600
#define EOFF02  783600
#define EOFF03  883600
#define NEDGES  1033600

// Runtime dtype flag (ws[0]): 1 if float inputs are packed bf16, 0 if fp32.
__device__ __forceinline__ float loadf(const void* p, size_t i, int isb) {
    return isb ? __bfloat162float(((const bf16*)p)[i])
               : ((const float*)p)[i];
}
__device__ __forceinline__ float b2f(unsigned u16) {
    union { unsigned v; float f; } x; x.v = u16 << 16; return x.f;
}
__device__ __forceinline__ unsigned f2b(float f) {
    bf16 h = __float2bfloat16(f);
    union { bf16 h; unsigned short u; } x; x.h = h; return (unsigned)x.u;
}
__device__ __forceinline__ void storef(void* p, size_t i, int asb, float v) {
    if (asb) ((unsigned short*)p)[i] = (unsigned short)f2b(v);
    else     ((float*)p)[i] = v;
}

// Detect input dtype from a randn fp32-or-bf16 buffer (see R2 notes).
__global__ void detect_kernel(const unsigned* __restrict__ probe, int* __restrict__ flag) {
    __shared__ int cnt;
    if (threadIdx.x == 0) cnt = 0;
    __syncthreads();
    int insane = 0;
    for (int i = threadIdx.x; i < 1024; i += 256) {
        float x = __uint_as_float(probe[i]);
        float a = fabsf(x);
        if (!(a > 1e-10f && a < 1e10f)) insane++;
    }
    atomicAdd(&cnt, insane);
    __syncthreads();
    if (threadIdx.x == 0) *flag = (cnt > 512) ? 1 : 0;
}

// ======================= exclusive scan primitive =======================
__device__ void scan_ex(const int* __restrict__ cnt, int* __restrict__ rp, int n) {
    __shared__ int wsum[16];
    __shared__ int carry;
    int t = threadIdx.x, lane = t & 63, w = t >> 6;
    if (t == 0) carry = 0;
    __syncthreads();
    for (int base = 0; base < n; base += 1024) {
        int i = base + t;
        int x = (i < n) ? cnt[i] : 0;
        int s = x;
        #pragma unroll
        for (int off = 1; off < 64; off <<= 1) {
            int y = __shfl_up(s, off);
            if (lane >= off) s += y;
        }
        if (lane == 63) wsum[w] = s;
        __syncthreads();
        if (w == 0) {
            int v = (lane < 16) ? wsum[lane] : 0;
            #pragma unroll
            for (int off = 1; off < 16; off <<= 1) {
                int y = __shfl_up(v, off);
                if (lane >= off) v += y;
            }
            if (lane < 16) wsum[lane] = v;
        }
        __syncthreads();
        int woff = (w > 0) ? wsum[w - 1] : 0;
        if (i < n) rp[i] = carry + woff + s - x;
        __syncthreads();
        if (t == 0) carry += wsum[15];
        __syncthreads();
    }
    if (t == 0) rp[n] = carry;
}

// ======================= fused 6-matrix CSR build (BIG path) =======================
__global__ void hist_all(const int* __restrict__ r11, const int* __restrict__ r22,
                         const int* __restrict__ r33, const int* __restrict__ r01,
                         const int* __restrict__ r02, const int* __restrict__ r03,
                         int* __restrict__ cnt) {
    int i = blockIdx.x * blockDim.x + threadIdx.x;
    if (i >= NEDGES) return;
    int slot;
    if      (i < EOFF22) slot = ROFF11 + r11[i];
    else if (i < EOFF33) slot = ROFF22 + r22[i - EOFF22];
    else if (i < EOFF01) slot = ROFF33 + r33[i - EOFF33];
    else if (i < EOFF02) slot = ROFF01 + r01[i - EOFF01];
    else if (i < EOFF03) slot = ROFF02 + r02[i - EOFF02];
    else                 slot = ROFF03 + r03[i - EOFF03];
    atomicAdd(cnt + slot, 1);
}

__global__ __launch_bounds__(1024) void scan_all(const int* __restrict__ cnt,
                                                 int* __restrict__ G) {
    scan_ex(cnt, G, NROWS);
}

__global__ void copy_all(const int* __restrict__ G, int* __restrict__ cur) {
    int i = blockIdx.x * blockDim.x + threadIdx.x;
    if (i < NROWS) cur[i] = G[i];
}

__global__ void scatter_all(const int* __restrict__ r11, const int* __restrict__ c11, const void* __restrict__ v11,
                            const int* __restrict__ r22, const int* __restrict__ c22, const void* __restrict__ v22,
                            const int* __restrict__ r33, const int* __restrict__ c33, const void* __restrict__ v33,
                            const int* __restrict__ r01, const int* __restrict__ c01, const void* __restrict__ v01,
                            const int* __restrict__ r02, const int* __restrict__ c02, const void* __restrict__ v02,
                            const int* __restrict__ r03, const int* __restrict__ c03, const void* __restrict__ v03,
                            int* __restrict__ cur, int2* __restrict__ pairs,
                            const int* __restrict__ dflag) {
    int i = blockIdx.x * blockDim.x + threadIdx.x;
    if (i >= NEDGES) return;
    int isb = *dflag;
    int slot, col; float val;
    if      (i < EOFF22) { int k = i;          slot = ROFF11 + r11[k]; col = c11[k]; val = loadf(v11, k, isb); }
    else if (i < EOFF01 && i >= EOFF33) { int k = i - EOFF33; slot = ROFF33 + r33[k]; col = c33[k]; val = loadf(v33, k, isb); }
    else if (i < EOFF33) { int k = i - EOFF22; slot = ROFF22 + r22[k]; col = c22[k]; val = loadf(v22, k, isb); }
    else if (i < EOFF02) { int k = i - EOFF01; slot = ROFF01 + r01[k]; col = c01[k]; val = loadf(v01, k, isb); }
    else if (i < EOFF03) { int k = i - EOFF02; slot = ROFF02 + r02[k]; col = c02[k]; val = loadf(v02, k, isb); }
    else                 { int k = i - EOFF03; slot = ROFF03 + r03[k]; col = c03[k]; val = loadf(v03, k, isb); }
    int p = atomicAdd(cur + slot, 1);
    pairs[p] = make_int2(col, __float_as_int(val));
}

// ======================= fused 2-matrix CSR build (mid path) =======================
__global__ void hist2_kernel(const int* __restrict__ rowsA, int nEA,
                             const int* __restrict__ rowsB, int nEB,
                             int nA, int* __restrict__ cnt) {
    int i = blockIdx.x * blockDim.x + threadIdx.x;
    if (i < nEA) atomicAdd(cnt + rowsA[i], 1);
    else if (i < nEA + nEB) atomicAdd(cnt + nA + rowsB[i - nEA], 1);
}

__global__ __launch_bounds__(1024) void scan2_kernel(
        const int* __restrict__ cntA, int* __restrict__ rpA, int nA,
        const int* __restrict__ cntB, int* __restrict__ rpB, int nB) {
    scan_ex(cntA, rpA, nA);
    __syncthreads();
    scan_ex(cntB, rpB, nB);
}

__global__ void copy2_kernel(const int* __restrict__ rpA, const int* __restrict__ rpB,
                             int nA, int nB, int* __restrict__ cur) {
    int i = blockIdx.x * blockDim.x + threadIdx.x;
    if (i < nA) cur[i] = rpA[i];
    else if (i < nA + nB) cur[i] = rpB[i - nA];
}

__global__ void scatter2_kernel(const int* __restrict__ rowsA, const int* __restrict__ colsA,
                                const void* __restrict__ valsA, int nEA,
                                const int* __restrict__ rowsB, const int* __restrict__ colsB,
                                const void* __restrict__ valsB, int nEB,
                                int nA, int* __restrict__ cur,
                                int2* __restrict__ pairsA, int2* __restrict__ pairsB,
                                const int* __restrict__ dflag) {
    int i = blockIdx.x * blockDim.x + threadIdx.x;
    int isb = *dflag;
    if (i < nEA) {
        int p = atomicAdd(cur + rowsA[i], 1);
        pairsA[p] = make_int2(colsA[i], __float_as_int(loadf(valsA, i, isb)));
    } else if (i < nEA + nEB) {
        int k = i - nEA;
        int p = atomicAdd(cur + nA + rowsB[k], 1);
        pairsB[p] = make_int2(colsB[k], __float_as_int(loadf(valsB, k, isb)));
    }
}

// ======================= gather bodies (8-edge unroll) =======================
template<bool RELU>
__device__ __forceinline__ void gather_accum8(
        const int* __restrict__ rp, const int2* __restrict__ pairs,
        const void* __restrict__ src, int sisb, int row, int lane,
        float& tx, float& ty) {
    int e0 = rp[row], e1 = rp[row + 1];
    float accx[8], accy[8];
    #pragma unroll
    for (int k = 0; k < 8; ++k) { accx[k] = 0.f; accy[k] = 0.f; }
    int e = e0;
    if (sisb) {
        const bf16* sb = (const bf16*)src;
        for (; e + 8 <= e1; e += 8) {
            int2 p[8]; unsigned u[8];
            #pragma unroll
            for (int k = 0; k < 8; ++k) p[k] = pairs[e + k];
            #pragma unroll
            for (int k = 0; k < 8; ++k)
                u[k] = ((const unsigned*)(sb + (size_t)p[k].x * 128))[lane];
            #pragma unroll
            for (int k = 0; k < 8; ++k) {
                float v = __int_as_float(p[k].y);
                float x0 = b2f(u[k] & 0xffffu), x1 = b2f(u[k] >> 16);
                if (RELU) { x0 = fmaxf(x0, 0.f); x1 = fmaxf(x1, 0.f); }
                accx[k] = fmaf(v, x0, accx[k]);
                accy[k] = fmaf(v, x1, accy[k]);
            }
        }
        for (; e + 2 <= e1; e += 2) {
            int2 p0 = pairs[e], p1 = pairs[e + 1];
            unsigned u0 = ((const unsigned*)(sb + (size_t)p0.x * 128))[lane];
            unsigned u1 = ((const unsigned*)(sb + (size_t)p1.x * 128))[lane];
            float v0 = __int_as_float(p0.y), v1 = __int_as_float(p1.y);
            float x0 = b2f(u0 & 0xffffu), x1 = b2f(u0 >> 16);
            float y0 = b2f(u1 & 0xffffu), y1 = b2f(u1 >> 16);
            if (RELU) {
                x0 = fmaxf(x0, 0.f); x1 = fmaxf(x1, 0.f);
                y0 = fmaxf(y0, 0.f); y1 = fmaxf(y1, 0.f);
            }
            accx[0] = fmaf(v0, x0, accx[0]); accy[0] = fmaf(v0, x1, accy[0]);
            accx[1] = fmaf(v1, y0, accx[1]); accy[1] = fmaf(v1, y1, accy[1]);
        }
        if (e < e1) {
            int2 p = pairs[e];
            float v = __int_as_float(p.y);
            unsigned u = ((const unsigned*)(sb + (size_t)p.x * 128))[lane];
            float x0 = b2f(u & 0xffffu), x1 = b2f(u >> 16);
            if (RELU) { x0 = fmaxf(x0, 0.f); x1 = fmaxf(x1, 0.f); }
            accx[0] = fmaf(v, x0, accx[0]); accy[0] = fmaf(v, x1, accy[0]);
        }
    } else {
        const float* sf = (const float*)src;
        for (; e + 8 <= e1; e += 8) {
            int2 p[8]; float2 u[8];
            #pragma unroll
            for (int k = 0; k < 8; ++k) p[k] = pairs[e + k];
            #pragma unroll
            for (int k = 0; k < 8; ++k)
                u[k] = ((const float2*)(sf + (size_t)p[k].x * 128))[lane];
            #pragma unroll
            for (int k = 0; k < 8; ++k) {
                float v = __int_as_float(p[k].y);
                float x0 = u[k].x, x1 = u[k].y;
                if (RELU) { x0 = fmaxf(x0, 0.f); x1 = fmaxf(x1, 0.f); }
                accx[k] = fmaf(v, x0, accx[k]);
                accy[k] = fmaf(v, x1, accy[k]);
            }
        }
        for (; e + 2 <= e1; e += 2) {
            int2 p0 = pairs[e], p1 = pairs[e + 1];
            float2 x = ((const float2*)(sf + (size_t)p0.x * 128))[lane];
            float2 y = ((const float2*)(sf + (size_t)p1.x * 128))[lane];
            float v0 = __int_as_float(p0.y), v1 = __int_as_float(p1.y);
            if (RELU) {
                x.x = fmaxf(x.x, 0.f); x.y = fmaxf(x.y, 0.f);
                y.x = fmaxf(y.x, 0.f); y.y = fmaxf(y.y, 0.f);
            }
            accx[0] = fmaf(v0, x.x, accx[0]); accy[0] = fmaf(v0, x.y, accy[0]);
            accx[1] = fmaf(v1, y.x, accx[1]); accy[1] = fmaf(v1, y.y, accy[1]);
        }
        if (e < e1) {
            int2 p = pairs[e];
            float v = __int_as_float(p.y);
            float2 x = ((const float2*)(sf + (size_t)p.x * 128))[lane];
            if (RELU) { x.x = fmaxf(x.x, 0.f); x.y = fmaxf(x.y, 0.f); }
            accx[0] = fmaf(v, x.x, accx[0]); accy[0] = fmaf(v, x.y, accy[0]);
        }
    }
    tx = ((accx[0] + accx[1]) + (accx[2] + accx[3])) + ((accx[4] + accx[5]) + (accx[6] + accx[7]));
    ty = ((accy[0] + accy[1]) + (accy[2] + accy[3])) + ((accy[4] + accy[5]) + (accy[6] + accy[7]));
}

template<bool RELU>
__device__ __forceinline__ void gather128_body(
        const int* __restrict__ rp, const int2* __restrict__ pairs,
        const void* __restrict__ src, int sisb,
        void* __restrict__ dst, int disb, int row, int lane) {
    float tx, ty;
    gather_accum8<RELU>(rp, pairs, src, sisb, row, lane, tx, ty);
    if (disb) {
        ((unsigned*)((bf16*)dst + (size_t)row * 128))[lane] = f2b(tx) | (f2b(ty) << 16);
    } else {
        ((float2*)((float*)dst + (size_t)row * 128))[lane] = make_float2(tx, ty);
    }
}

template<bool RELU>
__device__ __forceinline__ void norm128_body(
        const int* __restrict__ rp, const int2* __restrict__ pairs,
        const void* __restrict__ src, int sisb,
        void* __restrict__ out, size_t elem_off, int row, int lane, int isb) {
    float tx, ty;
    gather_accum8<RELU>(rp, pairs, src, sisb, row, lane, tx, ty);
    float ss = tx * tx + ty * ty;
    #pragma unroll
    for (int off = 32; off > 0; off >>= 1) ss += __shfl_down(ss, off);
    ss = __shfl(ss, 0);
    float inv = 1.0f / (sqrtf(ss) + 1e-9f);
    size_t base = elem_off + (size_t)row * 128;
    if (isb) {
        ((unsigned*)((bf16*)out + base))[lane] = f2b(tx * inv) | (f2b(ty * inv) << 16);
    } else {
        ((float2*)((float*)out + base))[lane] = make_float2(tx * inv, ty * inv);
    }
}

__device__ __forceinline__ void norm428_body(
        const int* __restrict__ rp, const int2* __restrict__ pairs,
        const void* __restrict__ src1, int s1b,
        const void* __restrict__ src2, int s2b,
        void* __restrict__ out, size_t elem_off, int row, int lane, int isb) {
    constexpr int P2 = D_WEMB / 2;   // 150
    int e0 = rp[row], e1 = rp[row + 1];
    float2 a1 = make_float2(0.f, 0.f), b1 = make_float2(0.f, 0.f);
    float2 a2[3], b2v[3];
    #pragma unroll
    for (int s = 0; s < 3; ++s) { a2[s] = make_float2(0.f, 0.f); b2v[s] = make_float2(0.f, 0.f); }
    int e = e0;
    for (; e + 2 <= e1; e += 2) {
        int2 p0 = pairs[e], p1 = pairs[e + 1];
        float v0 = __int_as_float(p0.y), v1 = __int_as_float(p1.y);
        float x0, x1, y0, y1;
        if (s1b) {
            unsigned u0 = ((const unsigned*)((const bf16*)src1 + (size_t)p0.x * DD))[lane];
            unsigned u1 = ((const unsigned*)((const bf16*)src1 + (size_t)p1.x * DD))[lane];
            x0 = b2f(u0 & 0xffffu); x1 = b2f(u0 >> 16);
            y0 = b2f(u1 & 0xffffu); y1 = b2f(u1 >> 16);
        } else {
            float2 x = ((const float2*)((const float*)src1 + (size_t)p0.x * DD))[lane];
            float2 y = ((const float2*)((const float*)src1 + (size_t)p1.x * DD))[lane];
            x0 = x.x; x1 = x.y; y0 = y.x; y1 = y.y;
        }
        x0 = fmaxf(x0, 0.f); x1 = fmaxf(x1, 0.f);
        y0 = fmaxf(y0, 0.f); y1 = fmaxf(y1, 0.f);
        a1.x = fmaf(v0, x0, a1.x); a1.y = fmaf(v0, x1, a1.y);
        b1.x = fmaf(v1, y0, b1.x); b1.y = fmaf(v1, y1, b1.y);
        if (s2b) {
            const unsigned* s0p = (const unsigned*)((const bf16*)src2 + (size_t)p0.x * D_WEMB);
            const unsigned* s1p = (const unsigned*)((const bf16*)src2 + (size_t)p1.x * D_WEMB);
            #pragma unroll
            for (int s = 0; s < 3; ++s) {
                int pi = lane + 64 * s;
                if (pi < P2) {
                    unsigned u0 = s0p[pi], u1 = s1p[pi];
                    a2[s].x  = fmaf(v0, b2f(u0 & 0xffffu), a2[s].x);
                    a2[s].y  = fmaf(v0, b2f(u0 >> 16),     a2[s].y);
                    b2v[s].x = fmaf(v1, b2f(u1 & 0xffffu), b2v[s].x);
                    b2v[s].y = fmaf(v1, b2f(u1 >> 16),     b2v[s].y);
                }
            }
        } else {
            const float2* s0p = (const float2*)((const float*)src2 + (size_t)p0.x * D_WEMB);
            const float2* s1p = (const float2*)((const float*)src2 + (size_t)p1.x * D_WEMB);
            #pragma unroll
            for (int s = 0; s < 3; ++s) {
                int pi = lane + 64 * s;
                if (pi < P2) {
                    float2 x = s0p[pi], y = s1p[pi];
                    a2[s].x  = fmaf(v0, x.x, a2[s].x);
                    a2[s].y  = fmaf(v0, x.y, a2[s].y);
                    b2v[s].x = fmaf(v1, y.x, b2v[s].x);
                    b2v[s].y = fmaf(v1, y.y, b2v[s].y);
                }
            }
        }
    }
    if (e < e1) {
        int2 p = pairs[e];
        float v = __int_as_float(p.y);
        float x0, x1;
        if (s1b) {
            unsigned u = ((const unsigned*)((const bf16*)src1 + (size_t)p.x * DD))[lane];
            x0 = b2f(u & 0xffffu); x1 = b2f(u >> 16);
        } else {
            float2 x = ((const float2*)((const float*)src1 + (size_t)p.x * DD))[lane];
            x0 = x.x; x1 = x.y;
        }
        x0 = fmaxf(x0, 0.f); x1 = fmaxf(x1, 0.f);
        a1.x = fmaf(v, x0, a1.x); a1.y = fmaf(v, x1, a1.y);
        if (s2b) {
            const unsigned* sp = (const unsigned*)((const bf16*)src2 + (size_t)p.x * D_WEMB);
            #pragma unroll
            for (int s = 0; s < 3; ++s) {
                int pi = lane + 64 * s;
                if (pi < P2) {
                    unsigned u = sp[pi];
                    a2[s].x = fmaf(v, b2f(u & 0xffffu), a2[s].x);
                    a2[s].y = fmaf(v, b2f(u >> 16),     a2[s].y);
                }
            }
        } else {
            const float2* sp = (const float2*)((const float*)src2 + (size_t)p.x * D_WEMB);
            #pragma unroll
            for (int s = 0; s < 3; ++s) {
                int pi = lane + 64 * s;
                if (pi < P2) {
                    float2 x = sp[pi];
                    a2[s].x = fmaf(v, x.x, a2[s].x);
                    a2[s].y = fmaf(v, x.y, a2[s].y);
                }
            }
        }
    }
    float t1x = a1.x + b1.x, t1y = a1.y + b1.y;
    float t2x[3], t2y[3];
    #pragma unroll
    for (int s = 0; s < 3; ++s) { t2x[s] = a2[s].x + b2v[s].x; t2y[s] = a2[s].y + b2v[s].y; }
    float ss = t1x * t1x + t1y * t1y;
    #pragma unroll
    for (int s = 0; s < 3; ++s) {
        int pi = lane + 64 * s;
        if (pi < P2) ss += t2x[s] * t2x[s] + t2y[s] * t2y[s];
    }
    #pragma unroll
    for (int off = 32; off > 0; off >>= 1) ss += __shfl_down(ss, off);
    ss = __shfl(ss, 0);
    float inv = 1.0f / (sqrtf(ss) + 1e-9f);
    size_t base = elem_off + (size_t)row * (DD + D_WEMB);
    if (isb) {
        ((unsigned*)((bf16*)out + base))[lane] = f2b(t1x * inv) | (f2b(t1y * inv) << 16);
        unsigned* o2 = (unsigned*)((bf16*)out + base + DD);
        #pragma unroll
        for (int s = 0; s < 3; ++s) {
            int pi = lane + 64 * s;
            if (pi < P2) o2[pi] = f2b(t2x[s] * inv) | (f2b(t2y[s] * inv) << 16);
        }
    } else {
        ((float2*)((float*)out + base))[lane] = make_float2(t1x * inv, t1y * inv);
        float2* o2 = (float2*)((float*)out + base + DD);
        #pragma unroll
        for (int s = 0; s < 3; ++s) {
            int pi = lane + 64 * s;
            if (pi < P2) o2[pi] = make_float2(t2x[s] * inv, t2y[s] * inv);
        }
    }
}

// ======================= gather kernels =======================
template<bool RELU>
__global__ void spmm_gather128(const int* __restrict__ rowptr, const int2* __restrict__ pairs,
                               const void* __restrict__ src, int src_flagged,
                               void* __restrict__ dst, int dst_flagged,
                               int n, const int* __restrict__ dflag) {
    int row = blockIdx.x * 4 + (threadIdx.x >> 6);
    if (row >= n) return;
    int isb = *dflag;
    gather128_body<RELU>(rowptr, pairs, src, src_flagged ? isb : 0,
                         dst, dst_flagged ? isb : 0, row, threadIdx.x & 63);
}

template<bool RELU>
__global__ void spmm_gather128_b2(const int* __restrict__ G, const int2* __restrict__ pairs,
                                  int roff1, const void* __restrict__ src1, void* __restrict__ dst1, int n1, int B1,
                                  int roff2, const void* __restrict__ src2, void* __restrict__ dst2, int n2,
                                  int src_flagged, int dst_flagged, const int* __restrict__ dflag) {
    int isb = *dflag;
    int sisb = src_flagged ? isb : 0;
    int disb = dst_flagged ? isb : 0;
    int lane = threadIdx.x & 63;
    int b = blockIdx.x;
    if (b < B1) {
        int row = b * 4 + (threadIdx.x >> 6);
        if (row >= n1) return;
        gather128_body<RELU>(G + roff1, pairs, src1, sisb, dst1, disb, row, lane);
    } else {
        int row = (b - B1) * 4 + (threadIdx.x >> 6);
        if (row >= n2) return;
        gather128_body<RELU>(G + roff2, pairs, src2, sisb, dst2, disb, row, lane);
    }
}

template<bool RELU>
__global__ void spmm_norm128(const int* __restrict__ rowptr, const int2* __restrict__ pairs,
                             const void* __restrict__ src, int src_flagged,
                             void* __restrict__ out, size_t elem_off,
                             int n, const int* __restrict__ dflag) {
    int row = blockIdx.x * 4 + (threadIdx.x >> 6);
    if (row >= n) return;
    int isb = *dflag;
    norm128_body<RELU>(rowptr, pairs, src, src_flagged ? isb : 0, out, elem_off,
                       row, threadIdx.x & 63, isb);
}

__global__ void spmm2_norm(const int* __restrict__ rowptr, const int2* __restrict__ pairs,
                           const void* __restrict__ src1, int s1_flagged,
                           const void* __restrict__ src2, int s2_flagged,
                           void* __restrict__ out, size_t elem_off,
                           int n, const int* __restrict__ dflag) {
    int row = blockIdx.x * 4 + (threadIdx.x >> 6);
    if (row >= n) return;
    int isb = *dflag;
    norm428_body(rowptr, pairs, src1, s1_flagged ? isb : 0, src2, s2_flagged ? isb : 0,
                 out, elem_off, row, threadIdx.x & 63, isb);
}

// BIG path: all 3 output norms in ONE launch.
__global__ void final_norm_all(const int* __restrict__ G, const int2* __restrict__ pairs,
                               const void* __restrict__ s1, const void* __restrict__ e0b,
                               const void* __restrict__ wemb, const void* __restrict__ p3b,
                               void* __restrict__ out,
                               size_t off1, size_t off2, size_t off3,
                               const int* __restrict__ dflag) {
    int isb = *dflag;
    int lane = threadIdx.x & 63;
    int b = blockIdx.x;
    if (b < 2500) {
        int row = b * 4 + (threadIdx.x >> 6);
        if (row >= N_DOC) return;
        norm128_body<true>(G + ROFF01, pairs, s1, isb, out, off1, row, lane, isb);
    } else if (b < 5000) {
        int row = (b - 2500) * 4 + (threadIdx.x >> 6);
        if (row >= N_DOC) return;
        norm428_body(G + ROFF02, pairs, e0b, isb, wemb, isb, out, off2, row, lane, isb);
    } else {
        int row = (b - 5000) * 4 + (threadIdx.x >> 6);
        if (row >= N_DOC) return;
        norm128_body<true>(G + ROFF03, pairs, p3b, isb, out, off3, row, lane, isb);
    }
}

// ======================= atomic SpMM (deep fallback) =======================
template<bool RELU>
__global__ void spmm_kernel(const int* __restrict__ rows, const int* __restrict__ cols,
                            const void* __restrict__ vals,
                            const void* __restrict__ src, int sstride, int src_flagged,
                            float* __restrict__ dst, int dstride, int doff,
                            int d, int nE, const int* __restrict__ dflag) {
    int e = blockIdx.x * (blockDim.x >> 6) + (threadIdx.x >> 6);
    if (e >= nE) return;
    int isb  = *dflag;
    int sisb = src_flagged ? isb : 0;
    int lane = threadIdx.x & 63;
    int r = rows[e];
    int c = cols[e];
    float v = loadf(vals, e, isb);
    size_t sbase = (size_t)c * sstride;
    float* dp = dst + (size_t)r * dstride + doff;
    if (sisb) {
        const unsigned* sp = (const unsigned*)((const bf16*)src + sbase);
        for (int j = 2 * lane; j < d; j += 128) {
            unsigned u = sp[j >> 1];
            float x0 = b2f(u & 0xffffu);
            float x1 = b2f(u >> 16);
            if (RELU) { x0 = fmaxf(x0, 0.f); x1 = fmaxf(x1, 0.f); }
            atomicAdd(dp + j,     v * x0);
            atomicAdd(dp + j + 1, v * x1);
        }
    } else {
        const float2* sp = (const float2*)((const float*)src + sbase);
        for (int j = 2 * lane; j < d; j += 128) {
            float2 x = sp[j >> 1];
            if (RELU) { x.x = fmaxf(x.x, 0.f); x.y = fmaxf(x.y, 0.f); }
            atomicAdd(dp + j,     v * x.x);
            atomicAdd(dp + j + 1, v * x.y);
        }
    }
}

// ======================= dense GEMMs =======================
// 64-col tile in 32 KB LDS. 256 threads: j2 = tid&31 -> col PAIR (cols jc+2*j2, +1),
// g = tid>>5 -> 8 row groups x 8 rows. Packed uint/float2 stores -> full-line writes.
// Grid: (pad8(row tiles), 2). X fp32; out/W/b follow isb.
template<bool RELU>
__device__ __forceinline__ void gemm_tile_body(
        const float* __restrict__ X, const void* __restrict__ W,
        const void* __restrict__ b, void* __restrict__ out, int n,
        int bx, int by, int isb, float* Wl /*128*64*/) {
    if (bx * 64 >= n) return;                 // pad block; uniform per block
    int tid = threadIdx.x;
    int jc = by * 64;
    if (isb) {
        const uint2* Wg = (const uint2*)W;    // W row = 32 uint2 (128 bf16)
        float4* Wl4 = (float4*)Wl;            // per k: 16 float4 (64 cols)
        for (int vidx = tid; vidx < 2048; vidx += 256) {
            int k = vidx >> 4, jl4 = vidx & 15;
            uint2 u = Wg[k * 32 + (jc >> 2) + jl4];
            float4 vv;
            vv.x = b2f(u.x & 0xffffu);
            vv.y = b2f(u.x >> 16);
            vv.z = b2f(u.y & 0xffffu);
            vv.w = b2f(u.y >> 16);
            Wl4[vidx] = vv;
        }
    } else {
        const float4* Wg = (const float4*)W;  // W row = 32 float4
        float4* Wl4 = (float4*)Wl;
        for (int vidx = tid; vidx < 2048; vidx += 256) {
            int k = vidx >> 4, jl4 = vidx & 15;
            Wl4[vidx] = Wg[k * 32 + (jc >> 2) + jl4];
        }
    }
    __syncthreads();
    int j2 = tid & 31;
    int g  = tid >> 5;
    float bc0 = loadf(b, jc + 2 * j2, isb);
    float bc1 = loadf(b, jc + 2 * j2 + 1, isb);
    int i0 = bx * 64 + g * 8;
    float a0[8], a1[8];
    #pragma unroll
    for (int r = 0; r < 8; ++r) { a0[r] = bc0; a1[r] = bc1; }
    const float4* xp = (const float4*)(X + (size_t)i0 * 128);
    const float2* Wl2 = (const float2*)Wl;    // per k: 32 float2; pair j2 at k*32+j2
    #pragma unroll 2
    for (int k4 = 0; k4 < 32; ++k4) {
        float2 w0 = Wl2[(4 * k4 + 0) * 32 + j2];
        float2 w1 = Wl2[(4 * k4 + 1) * 32 + j2];
        float2 w2 = Wl2[(4 * k4 + 2) * 32 + j2];
        float2 w3 = Wl2[(4 * k4 + 3) * 32 + j2];
        #pragma unroll
        for (int r = 0; r < 8; ++r) {
            float4 v = xp[r * 32 + k4];
            if (RELU) {
                v.x = fmaxf(v.x, 0.f); v.y = fmaxf(v.y, 0.f);
                v.z = fmaxf(v.z, 0.f); v.w = fmaxf(v.w, 0.f);
            }
            a0[r] = fmaf(v.w, w3.x, fmaf(v.z, w2.x, fmaf(v.y, w1.x, fmaf(v.x, w0.x, a0[r]))));
            a1[r] = fmaf(v.w, w3.y, fmaf(v.z, w2.y, fmaf(v.y, w1.y, fmaf(v.x, w0.y, a1[r]))));
        }
    }
    #pragma unroll
    for (int r = 0; r < 8; ++r) {
        int i = i0 + r;
        if (i < n) {
            if (isb) {
                ((unsigned*)((bf16*)out + (size_t)i * 128 + jc))[j2] =
                    f2b(a0[r]) | (f2b(a1[r]) << 16);
            } else {
                ((float2*)((float*)out + (size_t)i * 128 + jc))[j2] =
                    make_float2(a0[r], a1[r]);
            }
        }
    }
}

template<bool RELU>
__global__ __launch_bounds__(256) void gemm_tile(
        const float* __restrict__ X, const void* __restrict__ W,
        const void* __restrict__ b, void* __restrict__ out, int n,
        const int* __restrict__ dflag) {
    __shared__ float Wl[128 * 64];
    gemm_tile_body<RELU>(X, W, b, out, n, blockIdx.x, blockIdx.y, *dflag, Wl);
}

template<bool RELU>
__global__ __launch_bounds__(256) void gemm_tile_b2(
        const float* __restrict__ X1, const void* __restrict__ W1, const void* __restrict__ b1,
        void* __restrict__ out1, int n1, int G1,
        const float* __restrict__ X2, const void* __restrict__ W2, const void* __restrict__ b2,
        void* __restrict__ out2, int n2,
        const int* __restrict__ dflag) {
    __shared__ float Wl[128 * 64];
    int isb = *dflag;
    if ((int)blockIdx.x < G1)
        gemm_tile_body<RELU>(X1, W1, b1, out1, n1, blockIdx.x, blockIdx.y, isb, Wl);
    else
        gemm_tile_body<RELU>(X2, W2, b2, out2, n2, blockIdx.x - G1, blockIdx.y, isb, Wl);
}

// Legacy big-LDS GEMM (deep fallback only; fp32 ws).
template<bool RELU>
__global__ __launch_bounds__(256) void gemm128_kernel(
        const float* __restrict__ X, const void* __restrict__ W,
        const void* __restrict__ b, float* __restrict__ out, int n,
        const int* __restrict__ dflag) {
    __shared__ float Wl[128 * 128];
    int isb = *dflag;
    int tid = threadIdx.x;
    if (isb) {
        const uint2* Wg = (const uint2*)W;
        float4* Wl4 = (float4*)Wl;
        for (int idx = tid; idx < 4096; idx += 256) {
            uint2 u = Wg[idx];
            float4 vv;
            vv.x = b2f(u.x & 0xffffu);
            vv.y = b2f(u.x >> 16);
            vv.z = b2f(u.y & 0xffffu);
            vv.w = b2f(u.y >> 16);
            Wl4[idx] = vv;
        }
    } else {
        const float4* Wg = (const float4*)W;
        float4* Wl4 = (float4*)Wl;
        for (int idx = tid; idx < 4096; idx += 256) Wl4[idx] = Wg[idx];
    }
    __syncthreads();
    int j = tid & 127;
    int h = tid >> 7;
    float bj = loadf(b, j, isb);
    int row0 = blockIdx.x * 64 + h * 32;
    for (int q = 0; q < 8; ++q) {
        int gi = row0 + q * 4;
        if (gi >= n) break;
        const float4* x0 = (const float4*)(X + (size_t)gi * 128);
        const float4* x1 = x0 + 32;
        const float4* x2 = x1 + 32;
        const float4* x3 = x2 + 32;
        float a0 = bj, a1 = bj, a2 = bj, a3 = bj;
        #pragma unroll 4
        for (int k4 = 0; k4 < 32; ++k4) {
            float4 v0 = x0[k4], v1 = x1[k4], v2 = x2[k4], v3 = x3[k4];
            if (RELU) {
                v0.x = fmaxf(v0.x, 0.f); v0.y = fmaxf(v0.y, 0.f); v0.z = fmaxf(v0.z, 0.f); v0.w = fmaxf(v0.w, 0.f);
                v1.x = fmaxf(v1.x, 0.f); v1.y = fmaxf(v1.y, 0.f); v1.z = fmaxf(v1.z, 0.f); v1.w = fmaxf(v1.w, 0.f);
                v2.x = fmaxf(v2.x, 0.f); v2.y = fmaxf(v2.y, 0.f); v2.z = fmaxf(v2.z, 0.f); v2.w = fmaxf(v2.w, 0.f);
                v3.x = fmaxf(v3.x, 0.f); v3.y = fmaxf(v3.y, 0.f); v3.z = fmaxf(v3.z, 0.f); v3.w = fmaxf(v3.w, 0.f);
            }
            float w0 = Wl[(4 * k4 + 0) * 128 + j];
            float w1 = Wl[(4 * k4 + 1) * 128 + j];
            float w2 = Wl[(4 * k4 + 2) * 128 + j];
            float w3 = Wl[(4 * k4 + 3) * 128 + j];
            a0 = fmaf(v0.w, w3, fmaf(v0.z, w2, fmaf(v0.y, w1, fmaf(v0.x, w0, a0))));
            a1 = fmaf(v1.w, w3, fmaf(v1.z, w2, fmaf(v1.y, w1, fmaf(v1.x, w0, a1))));
            a2 = fmaf(v2.w, w3, fmaf(v2.z, w2, fmaf(v2.y, w1, fmaf(v2.x, w0, a2))));
            a3 = fmaf(v3.w, w3, fmaf(v3.z, w2, fmaf(v3.y, w1, fmaf(v3.x, w0, a3))));
        }
        float* o = out + (size_t)gi * 128 + j;
        o[0] = a0; o[128] = a1; o[256] = a2; o[384] = a3;
    }
}

// Row-parallel tiny GEMM (type-3, n=60): one block per row, 128 threads.
template<bool RELU, int K>
__global__ void rowpar_gemm(const void* __restrict__ X, int x_flagged,
                            const void* __restrict__ W, const void* __restrict__ b,
                            void* __restrict__ out, int out_flagged,
                            const int* __restrict__ dflag) {
    __shared__ float xr[K];
    int isb  = *dflag;
    int xisb = x_flagged ? isb : 0;
    int oisb = out_flagged ? isb : 0;
    int row = blockIdx.x;
    int j = threadIdx.x;
    if (j < K) {
        float x = loadf(X, (size_t)row * K + j, xisb);
        if (RELU) x = fmaxf(x, 0.f);
        xr[j] = x;
    }
    __syncthreads();
    float acc = loadf(b, j, isb);
    #pragma unroll 8
    for (int k = 0; k < K; ++k)
        acc = fmaf(xr[k], loadf(W, (size_t)k * 128 + j, isb), acc);
    storef(out, (size_t)row * 128 + j, oisb, acc);
}

// Generic small GEMM (deep fallback only).
template<bool RELU, int K>
__global__ void gemm_kernel(const void* __restrict__ X, int x_flagged,
                            const void* __restrict__ W,
                            const void* __restrict__ b,
                            float* __restrict__ out, int n,
                            const int* __restrict__ dflag) {
    __shared__ float Wl[K * 128];
    int isb  = *dflag;
    int xisb = x_flagged ? isb : 0;
    int j = threadIdx.x;
    for (int idx = j; idx < K * 128; idx += 128)
        Wl[idx] = loadf(W, idx, isb);
    __syncthreads();
    float bj = loadf(b, j, isb);
    int row0 = blockIdx.x * 64;
    for (int i0 = 0; i0 < 64; i0 += 4) {
        int i = row0 + i0;
        if (i >= n) break;
        size_t r0 = (size_t)i * K;
        float a0 = bj, a1 = bj, a2 = bj, a3 = bj;
        for (int k = 0; k < K; ++k) {
            float w = Wl[k * 128 + j];
            float v0 = loadf(X, r0 + k, xisb);
            float v1 = loadf(X, r0 + K + k, xisb);
            float v2 = loadf(X, r0 + 2 * K + k, xisb);
            float v3 = loadf(X, r0 + 3 * K + k, xisb);
            if (RELU) {
                v0 = fmaxf(v0, 0.f); v1 = fmaxf(v1, 0.f);
                v2 = fmaxf(v2, 0.f); v3 = fmaxf(v3, 0.f);
            }
            a0 = fmaf(v0, w, a0);
            a1 = fmaf(v1, w, a1);
            a2 = fmaf(v2, w, a2);
            a3 = fmaf(v3, w, a3);
        }
        float* o = out + (size_t)i * 128 + j;
        o[0] = a0; o[128] = a1; o[256] = a2; o[384] = a3;
    }
}

// L2-norm (deep fallback only).
__global__ void l2norm_kernel(const float* __restrict__ agg, int d,
                              void* __restrict__ out, size_t elem_off, int n,
                              const int* __restrict__ dflag) {
    int row = blockIdx.x * (blockDim.x >> 6) + (threadIdx.x >> 6);
    if (row >= n) return;
    int isb  = *dflag;
    int lane = threadIdx.x & 63;
    const float2* a2 = (const float2*)(agg + (size_t)row * d);
    float ss = 0.f;
    for (int j = 2 * lane; j < d; j += 128) {
        float2 x = a2[j >> 1];
        ss += x.x * x.x + x.y * x.y;
    }
    #pragma unroll
    for (int off = 32; off > 0; off >>= 1) ss += __shfl_down(ss, off);
    ss = __shfl(ss, 0);
    float inv = 1.0f / (sqrtf(ss) + 1e-9f);
    size_t bbase = elem_off + (size_t)row * d;
    if (isb) {
        unsigned* o = (unsigned*)((bf16*)out + bbase);
        for (int j = 2 * lane; j < d; j += 128) {
            float2 x = a2[j >> 1];
            o[j >> 1] = f2b(x.x * inv) | (f2b(x.y * inv) << 16);
        }
    } else {
        float2* o = (float2*)((float*)out + bbase);
        for (int j = 2 * lane; j < d; j += 128) {
            float2 x = a2[j >> 1];
            o[j >> 1] = make_float2(x.x * inv, x.y * inv);
        }
    }
}

static inline int spmm_grid(int nE) { return (nE + 3) / 4; }
static inline int row_grid(int n)   { return (n + 3) / 4; }
static inline int pad8(int x)       { return (x + 7) & ~7; }

// Mid-path per-phase CSR build.
static void build2(hipStream_t stream,
                   const int* rowsA, const int* colsA, const void* valsA, int nA, int nEA,
                   const int* rowsB, const int* colsB, const void* valsB, int nB, int nEB,
                   int* rpA, int* rpB, int* curAB, int2* pairsA, int2* pairsB,
                   const int* dflag) {
    int nE = nEA + nEB;
    hipMemsetAsync(curAB, 0, (size_t)(nA + nB) * 4, stream);
    hist2_kernel<<<(nE + 255) / 256, 256, 0, stream>>>(rowsA, nEA, rowsB, nEB, nA, curAB);
    scan2_kernel<<<1, 1024, 0, stream>>>(curAB, rpA, nA, curAB + nA, rpB, nB);
    copy2_kernel<<<(nA + nB + 255) / 256, 256, 0, stream>>>(rpA, rpB, nA, nB, curAB);
    scatter2_kernel<<<(nE + 255) / 256, 256, 0, stream>>>(
        rowsA, colsA, valsA, nEA, rowsB, colsB, valsB, nEB, nA, curAB, pairsA, pairsB, dflag);
}

extern "C" void kernel_launch(void* const* d_in, const int* in_sizes, int n_in,
                              void* d_out, int out_size, void* d_ws, size_t ws_size,
                              hipStream_t stream) {
    const void* f1   = d_in[0];
    const void* f2   = d_in[1];
    const void* f3   = d_in[2];
    const void* wemb = d_in[3];
    const int*  a11r = (const int*)d_in[4];
    const int*  a11c = (const int*)d_in[5];
    const void* a11v = d_in[6];
    const int*  a22r = (const int*)d_in[7];
    const int*  a22c = (const int*)d_in[8];
    const void* a22v = d_in[9];
    const int*  a33r = (const int*)d_in[10];
    const int*  a33c = (const int*)d_in[11];
    const void* a33v = d_in[12];
    const int*  a01r = (const int*)d_in[13];
    const int*  a01c = (const int*)d_in[14];
    const void* a01v = d_in[15];
    const int*  a02r = (const int*)d_in[16];
    const int*  a02c = (const int*)d_in[17];
    const void* a02v = d_in[18];
    const int*  a03r = (const int*)d_in[19];
    const int*  a03c = (const int*)d_in[20];
    const void* a03v = d_in[21];
    const void* W3   = d_in[22];
    const void* b3   = d_in[23];
    const void* W1_2 = d_in[24];
    const void* b1_2 = d_in[25];
    const void* W2_2 = d_in[26];
    const void* b2_2 = d_in[27];
    const void* W3_2 = d_in[28];
    const void* b3_2 = d_in[29];

    int*   dflag = (int*)d_ws;
    float* base  = (float*)d_ws + 16;

    const size_t OUT1_OFF = 0;
    const size_t OUT2_OFF = (size_t)N_DOC * DD;                       // 1,280,000
    const size_t OUT3_OFF = OUT2_OFF + (size_t)N_DOC * (DD + D_WEMB); // 5,560,000

    dim3 blk(256);
    detect_kernel<<<1, 256, 0, stream>>>((const unsigned*)f1, dflag);

    const size_t BF_S0 = 0, BF_S1 = 2560000, BF_E0 = 5120000, BF_E1 = 6400000;
    const size_t BF_P3A = 7680000, BF_P3B = 7687680, BF_INT = 7695360;
    const size_t BIG_INTS = 60061ull + 60060ull + 2ull * NEDGES;      // 2,187,321
    const size_t WS_BIG = 64 + (BF_INT + BIG_INTS + 8) * 4;           // ~39.5 MB
    const size_t WS_MID = 64 + 22240000ull + 240008ull + 4960000ull;  // ~27.44 MB

    if (ws_size >= WS_BIG) {
        // ======================= BIG batched path =======================
        float* S0  = base + BF_S0;
        float* S1  = base + BF_S1;
        float* E0  = base + BF_E0;
        float* E1  = base + BF_E1;
        float* P3a = base + BF_P3A;
        float* P3b = base + BF_P3B;
        int*   G    = (int*)(base + BF_INT);
        int*   cur  = G + (NROWS + 1);
        int2*  pairs = (int2*)(cur + NROWS + 1);

        hipMemsetAsync(cur, 0, (size_t)NROWS * 4, stream);
        hist_all<<<(NEDGES + 255) / 256, 256, 0, stream>>>(
            a11r, a22r, a33r, a01r, a02r, a03r, cur);
        scan_all<<<1, 1024, 0, stream>>>(cur, G);
        copy_all<<<(NROWS + 255) / 256, 256, 0, stream>>>(G, cur);
        scatter_all<<<(NEDGES + 255) / 256, 256, 0, stream>>>(
            a11r, a11c, a11v, a22r, a22c, a22v, a33r, a33c, a33v,
            a01r, a01c, a01v, a02r, a02c, a02v, a03r, a03c, a03v,
            cur, pairs, dflag);

        rowpar_gemm<false, 60><<<N_POS, 128, 0, stream>>>(
            f3, 1, W3, b3, P3a, 1, dflag);                              // P3a = f3@W3+b3

        {
            int B1 = row_grid(N_WORD), B2 = row_grid(N_ENT);
            spmm_gather128_b2<false><<<B1 + B2, blk, 0, stream>>>(
                G, pairs, ROFF11, f1, S0, N_WORD, B1,
                ROFF22, f2, E0, N_ENT, 1, 0, dflag);                    // hop1 (fp32 out)
        }
        {
            int G1 = pad8((N_WORD + 63) / 64), G2 = pad8((N_ENT + 63) / 64);
            gemm_tile_b2<true><<<dim3(G1 + G2, 2), 256, 0, stream>>>(
                S0, W1_2, b1_2, S1, N_WORD, G1,
                E0, W2_2, b2_2, E1, N_ENT, dflag);                      // gemm batch
        }
        {
            int B1 = row_grid(N_WORD), B2 = row_grid(N_ENT);
            spmm_gather128_b2<false><<<B1 + B2, blk, 0, stream>>>(
                G, pairs, ROFF11, S1, S0, N_WORD, B1,
                ROFF22, E1, E0, N_ENT, 1, 1, dflag);                    // hop2 (flagged out)
        }
        spmm_gather128<false><<<row_grid(N_POS), blk, 0, stream>>>(
            G + ROFF33, pairs, P3a, 1, P3b, 1, N_POS, dflag);
        rowpar_gemm<true, 128><<<N_POS, 128, 0, stream>>>(
            P3b, 1, W3_2, b3_2, P3a, 1, dflag);
        spmm_gather128<false><<<row_grid(N_POS), blk, 0, stream>>>(
            G + ROFF33, pairs, P3a, 1, P3b, 1, N_POS, dflag);

        final_norm_all<<<7500, blk, 0, stream>>>(
            G, pairs, S0, E0, wemb, P3b, d_out, OUT1_OFF, OUT2_OFF, OUT3_OFF, dflag);
    } else if (ws_size >= WS_MID) {
        // ======================= mid path =======================
        float* S0   = base;
        float* S1   = base + 2560000;
        float* E0   = base;
        float* E1   = base + 1280000;
        float* P3a  = base;
        float* P3b  = base + 7680;
        int* I = (int*)(base + 5560000);
        {
            int* rpA = I; int* rpB = rpA + (N_WORD + 1); int* cur = rpB + (N_DOC + 1);
            int2* pA = (int2*)(cur + N_WORD + N_DOC); int2* pB = pA + E11;
            build2(stream, a11r, a11c, a11v, N_WORD, E11,
                   a01r, a01c, a01v, N_DOC, E01, rpA, rpB, cur, pA, pB, dflag);
            spmm_gather128<false><<<row_grid(N_WORD), blk, 0, stream>>>(
                rpA, pA, f1, 1, S0, 0, N_WORD, dflag);
            gemm_tile<true><<<dim3(pad8((N_WORD + 63) / 64), 2), 256, 0, stream>>>(
                S0, W1_2, b1_2, S1, N_WORD, dflag);
            spmm_gather128<false><<<row_grid(N_WORD), blk, 0, stream>>>(
                rpA, pA, S1, 1, S0, 1, N_WORD, dflag);
            spmm_norm128<true><<<row_grid(N_DOC), blk, 0, stream>>>(
                rpB, pB, S0, 1, d_out, OUT1_OFF, N_DOC, dflag);
        }
        {
            int* rpA = I; int* rpB = rpA + (N_ENT + 1); int* cur = rpB + (N_DOC + 1);
            int2* pA = (int2*)(cur + N_ENT + N_DOC); int2* pB = pA + E22;
            build2(stream, a22r, a22c, a22v, N_ENT, E22,
                   a02r, a02c, a02v, N_DOC, E02, rpA, rpB, cur, pA, pB, dflag);
            spmm_gather128<false><<<row_grid(N_ENT), blk, 0, stream>>>(
                rpA, pA, f2, 1, E0, 0, N_ENT, dflag);
            gemm_tile<true><<<dim3(pad8((N_ENT + 63) / 64), 2), 256, 0, stream>>>(
                E0, W2_2, b2_2, E1, N_ENT, dflag);
            spmm_gather128<false><<<row_grid(N_ENT), blk, 0, stream>>>(
                rpA, pA, E1, 1, E0, 1, N_ENT, dflag);
            spmm2_norm<<<row_grid(N_DOC), blk, 0, stream>>>(
                rpB, pB, E0, 1, wemb, 1, d_out, OUT2_OFF, N_DOC, dflag);
        }
        {
            int* rpA = I; int* rpB = rpA + (N_POS + 1); int* cur = rpB + (N_DOC + 1);
            int2* pA = (int2*)(cur + N_POS + N_DOC); int2* pB = pA + E33;
            build2(stream, a33r, a33c, a33v, N_POS, E33,
                   a03r, a03c, a03v, N_DOC, E03, rpA, rpB, cur, pA, pB, dflag);
            rowpar_gemm<false, 60><<<N_POS, 128, 0, stream>>>(
                f3, 1, W3, b3, P3a, 1, dflag);
            spmm_gather128<false><<<row_grid(N_POS), blk, 0, stream>>>(
                rpA, pA, P3a, 1, P3b, 1, N_POS, dflag);
            rowpar_gemm<true, 128><<<N_POS, 128, 0, stream>>>(
                P3b, 1, W3_2, b3_2, P3a, 1, dflag);
            spmm_gather128<false><<<row_grid(N_POS), blk, 0, stream>>>(
                rpA, pA, P3a, 1, P3b, 1, N_POS, dflag);
            spmm_norm128<true><<<row_grid(N_DOC), blk, 0, stream>>>(
                rpB, pB, P3b, 1, d_out, OUT3_OFF, N_DOC, dflag);
        }
    } else {
        // ======================= deep fallback: atomic path =======================
        float* S0   = base;
        float* S1   = base + 2560000;
        float* AGG1 = S1;
        float* E0   = base;
        float* E1   = base + 1280000;
        float* AGG2 = base + 1280000;
        float* P3a  = base;
        float* P3b  = base + 7680;
        float* AGG3 = base + 15360;
        hipMemsetAsync(S0, 0, (size_t)N_WORD * DD * 4, stream);
        spmm_kernel<false><<<spmm_grid(E11), blk, 0, stream>>>(
            a11r, a11c, a11v, f1, DD, 1, S0, DD, 0, DD, E11, dflag);
        gemm128_kernel<true><<<(N_WORD + 63) / 64, 256, 0, stream>>>(
            S0, W1_2, b1_2, S1, N_WORD, dflag);
        hipMemsetAsync(S0, 0, (size_t)N_WORD * DD * 4, stream);
        spmm_kernel<false><<<spmm_grid(E11), blk, 0, stream>>>(
            a11r, a11c, a11v, S1, DD, 0, S0, DD, 0, DD, E11, dflag);
        hipMemsetAsync(AGG1, 0, (size_t)N_DOC * DD * 4, stream);
        spmm_kernel<true><<<spmm_grid(E01), blk, 0, stream>>>(
            a01r, a01c, a01v, S0, DD, 0, AGG1, DD, 0, DD, E01, dflag);
        l2norm_kernel<<<row_grid(N_DOC), blk, 0, stream>>>(
            AGG1, DD, d_out, OUT1_OFF, N_DOC, dflag);

        hipMemsetAsync(E0, 0, (size_t)N_ENT * DD * 4, stream);
        spmm_kernel<false><<<spmm_grid(E22), blk, 0, stream>>>(
            a22r, a22c, a22v, f2, DD, 1, E0, DD, 0, DD, E22, dflag);
        gemm128_kernel<true><<<(N_ENT + 63) / 64, 256, 0, stream>>>(
            E0, W2_2, b2_2, E1, N_ENT, dflag);
        hipMemsetAsync(E0, 0, (size_t)N_ENT * DD * 4, stream);
        spmm_kernel<false><<<spmm_grid(E22), blk, 0, stream>>>(
            a22r, a22c, a22v, E1, DD, 0, E0, DD, 0, DD, E22, dflag);
        hipMemsetAsync(AGG2, 0, (size_t)N_DOC * (DD + D_WEMB) * 4, stream);
        spmm_kernel<true><<<spmm_grid(E02), blk, 0, stream>>>(
            a02r, a02c, a02v, E0, DD, 0, AGG2, DD + D_WEMB, 0, DD, E02, dflag);
        spmm_kernel<false><<<spmm_grid(E02), blk, 0, stream>>>(
            a02r, a02c, a02v, wemb, D_WEMB, 1, AGG2, DD + D_WEMB, DD, D_WEMB, E02, dflag);
        l2norm_kernel<<<row_grid(N_DOC), blk, 0, stream>>>(
            AGG2, DD + D_WEMB, d_out, OUT2_OFF, N_DOC, dflag);

        gemm_kernel<false, 60><<<1, 128, 0, stream>>>(f3, 1, W3, b3, P3a, N_POS, dflag);
        hipMemsetAsync(P3b, 0, (size_t)N_POS * DD * 4, stream);
        spmm_kernel<false><<<spmm_grid(E33), blk, 0, stream>>>(
            a33r, a33c, a33v, P3a, DD, 0, P3b, DD, 0, DD, E33, dflag);
        gemm128_kernel<true><<<1, 256, 0, stream>>>(
            P3b, W3_2, b3_2, P3a, N_POS, dflag);
        hipMemsetAsync(P3b, 0, (size_t)N_POS * DD * 4, stream);
        spmm_kernel<false><<<spmm_grid(E33), blk, 0, stream>>>(
            a33r, a33c, a33v, P3a, DD, 0, P3b, DD, 0, DD, E33, dflag);
        hipMemsetAsync(AGG3, 0, (size_t)N_DOC * DD * 4, stream);
        spmm_kernel<true><<<spmm_grid(E03), blk, 0, stream>>>(
            a03r, a03c, a03v, P3b, DD, 0, AGG3, DD, 0, DD, E03, dflag);
        l2norm_kernel<<<row_grid(N_DOC), blk, 0, stream>>>(
            AGG3, DD, d_out, OUT3_OFF, N_DOC, dflag);
    }
}

// Round 15
// 420.266 us; speedup vs baseline: 1.5562x; 1.1471x over previous
//
#include <hip/hip_runtime.h>
#include <hip/hip_bf16.h>

typedef __hip_bfloat16 bf16;

#define N_DOC   10000
#define N_WORD  20000
#define N_ENT   10000
#define N_POS   60
#define DD      128
#define D_WEMB  300
#define E11     320000
#define E22     160000
#define E33     3600
#define E01     300000
#define E02     100000
#define E03     150000

// Concatenated row/edge segment offsets for the fused 6-matrix CSR build.
#define ROFF11  0
#define ROFF22  20000
#define ROFF33  30000
#define ROFF01  30060
#define ROFF02  40060
#define ROFF03  50060
#define NROWS   60060
#define EOFF11  0
#define EOFF22  320000
#define EOFF33  480000
#define EOFF01  483600
#define EOFF02  783600
#define EOFF03  883600
#define NEDGES  1033600

// Runtime dtype flag (ws[0]): 1 if float inputs are packed bf16, 0 if fp32.
__device__ __forceinline__ float loadf(const void* p, size_t i, int isb) {
    return isb ? __bfloat162float(((const bf16*)p)[i])
               : ((const float*)p)[i];
}
__device__ __forceinline__ float b2f(unsigned u16) {
    union { unsigned v; float f; } x; x.v = u16 << 16; return x.f;
}
__device__ __forceinline__ unsigned f2b(float f) {
    bf16 h = __float2bfloat16(f);
    union { bf16 h; unsigned short u; } x; x.h = h; return (unsigned)x.u;
}
__device__ __forceinline__ void storef(void* p, size_t i, int asb, float v) {
    if (asb) ((unsigned short*)p)[i] = (unsigned short)f2b(v);
    else     ((float*)p)[i] = v;
}
// Packed pair: low 16 bits = col (max 20000 < 65536), high 16 = bf16 val.
__device__ __forceinline__ unsigned pack_pair(int col, float v) {
    return (f2b(v) << 16) | (unsigned)col;
}

// Detect input dtype from a randn fp32-or-bf16 buffer (see R2 notes).
__global__ void detect_kernel(const unsigned* __restrict__ probe, int* __restrict__ flag) {
    __shared__ int cnt;
    if (threadIdx.x == 0) cnt = 0;
    __syncthreads();
    int insane = 0;
    for (int i = threadIdx.x; i < 1024; i += 256) {
        float x = __uint_as_float(probe[i]);
        float a = fabsf(x);
        if (!(a > 1e-10f && a < 1e10f)) insane++;
    }
    atomicAdd(&cnt, insane);
    __syncthreads();
    if (threadIdx.x == 0) *flag = (cnt > 512) ? 1 : 0;
}

// ======================= multi-block exclusive scan =======================
// scan_part: each 1024-thr block scans its 1024-chunk; G gets local exclusive
// prefix; bsum[b] gets the chunk total.
__global__ __launch_bounds__(1024) void scan_part(const int* __restrict__ cnt,
                                                  int* __restrict__ G,
                                                  int* __restrict__ bsum, int n) {
    __shared__ int wsum[16];
    int b = blockIdx.x, t = threadIdx.x;
    int lane = t & 63, w = t >> 6;
    int i = b * 1024 + t;
    int x = (i < n) ? cnt[i] : 0;
    int s = x;
    #pragma unroll
    for (int off = 1; off < 64; off <<= 1) {
        int y = __shfl_up(s, off);
        if (lane >= off) s += y;
    }
    if (lane == 63) wsum[w] = s;
    __syncthreads();
    if (w == 0) {
        int v = (lane < 16) ? wsum[lane] : 0;
        #pragma unroll
        for (int off = 1; off < 16; off <<= 1) {
            int y = __shfl_up(v, off);
            if (lane >= off) v += y;
        }
        if (lane < 16) wsum[lane] = v;
    }
    __syncthreads();
    int woff = (w > 0) ? wsum[w - 1] : 0;
    if (i < n) G[i] = woff + s - x;
    if (t == 1023) bsum[b] = woff + s;
}

// scan_tops: single wave scans block sums (nb <= 64), writes exclusive boff
// and the grand total into G[n].
__global__ void scan_tops(const int* __restrict__ bsum, int* __restrict__ boff,
                          int nb, int* __restrict__ G, int n) {
    int t = threadIdx.x;
    int x = (t < nb) ? bsum[t] : 0;
    int s = x;
    #pragma unroll
    for (int off = 1; off < 64; off <<= 1) {
        int y = __shfl_up(s, off);
        if (t >= off) s += y;
    }
    if (t < nb) boff[t] = s - x;
    if (t == 63) G[n] = s;
}

// scan_fix: add chunk offsets; also materialize cursors.
__global__ void scan_fix(int* __restrict__ G, const int* __restrict__ boff,
                         int* __restrict__ cur, int n) {
    int i = blockIdx.x * 256 + threadIdx.x;
    if (i < n) {
        int v = G[i] + boff[i >> 10];
        G[i] = v;
        cur[i] = v;
    }
}

// ======================= fused 6-matrix CSR build (BIG path) =======================
__global__ void hist_all(const int* __restrict__ r11, const int* __restrict__ r22,
                         const int* __restrict__ r33, const int* __restrict__ r01,
                         const int* __restrict__ r02, const int* __restrict__ r03,
                         int* __restrict__ cnt) {
    int i = blockIdx.x * blockDim.x + threadIdx.x;
    if (i >= NEDGES) return;
    int slot;
    if      (i < EOFF22) slot = ROFF11 + r11[i];
    else if (i < EOFF33) slot = ROFF22 + r22[i - EOFF22];
    else if (i < EOFF01) slot = ROFF33 + r33[i - EOFF33];
    else if (i < EOFF02) slot = ROFF01 + r01[i - EOFF01];
    else if (i < EOFF03) slot = ROFF02 + r02[i - EOFF02];
    else                 slot = ROFF03 + r03[i - EOFF03];
    atomicAdd(cnt + slot, 1);
}

__global__ void scatter_all(const int* __restrict__ r11, const int* __restrict__ c11, const void* __restrict__ v11,
                            const int* __restrict__ r22, const int* __restrict__ c22, const void* __restrict__ v22,
                            const int* __restrict__ r33, const int* __restrict__ c33, const void* __restrict__ v33,
                            const int* __restrict__ r01, const int* __restrict__ c01, const void* __restrict__ v01,
                            const int* __restrict__ r02, const int* __restrict__ c02, const void* __restrict__ v02,
                            const int* __restrict__ r03, const int* __restrict__ c03, const void* __restrict__ v03,
                            int* __restrict__ cur, unsigned* __restrict__ pairs,
                            const int* __restrict__ dflag) {
    int i = blockIdx.x * blockDim.x + threadIdx.x;
    if (i >= NEDGES) return;
    int isb = *dflag;
    int slot, col; float val;
    if      (i < EOFF22) { int k = i;          slot = ROFF11 + r11[k]; col = c11[k]; val = loadf(v11, k, isb); }
    else if (i < EOFF01 && i >= EOFF33) { int k = i - EOFF33; slot = ROFF33 + r33[k]; col = c33[k]; val = loadf(v33, k, isb); }
    else if (i < EOFF33) { int k = i - EOFF22; slot = ROFF22 + r22[k]; col = c22[k]; val = loadf(v22, k, isb); }
    else if (i < EOFF02) { int k = i - EOFF01; slot = ROFF01 + r01[k]; col = c01[k]; val = loadf(v01, k, isb); }
    else if (i < EOFF03) { int k = i - EOFF02; slot = ROFF02 + r02[k]; col = c02[k]; val = loadf(v02, k, isb); }
    else                 { int k = i - EOFF03; slot = ROFF03 + r03[k]; col = c03[k]; val = loadf(v03, k, isb); }
    int p = atomicAdd(cur + slot, 1);
    pairs[p] = pack_pair(col, val);
}

// ======================= fused 2-matrix CSR build (mid path) =======================
__global__ void hist2_kernel(const int* __restrict__ rowsA, int nEA,
                             const int* __restrict__ rowsB, int nEB,
                             int nA, int* __restrict__ cnt) {
    int i = blockIdx.x * blockDim.x + threadIdx.x;
    if (i < nEA) atomicAdd(cnt + rowsA[i], 1);
    else if (i < nEA + nEB) atomicAdd(cnt + nA + rowsB[i - nEA], 1);
}

__device__ void scan_ex(const int* __restrict__ cnt, int* __restrict__ rp, int n) {
    __shared__ int wsum[16];
    __shared__ int carry;
    int t = threadIdx.x, lane = t & 63, w = t >> 6;
    if (t == 0) carry = 0;
    __syncthreads();
    for (int base = 0; base < n; base += 1024) {
        int i = base + t;
        int x = (i < n) ? cnt[i] : 0;
        int s = x;
        #pragma unroll
        for (int off = 1; off < 64; off <<= 1) {
            int y = __shfl_up(s, off);
            if (lane >= off) s += y;
        }
        if (lane == 63) wsum[w] = s;
        __syncthreads();
        if (w == 0) {
            int v = (lane < 16) ? wsum[lane] : 0;
            #pragma unroll
            for (int off = 1; off < 16; off <<= 1) {
                int y = __shfl_up(v, off);
                if (lane >= off) v += y;
            }
            if (lane < 16) wsum[lane] = v;
        }
        __syncthreads();
        int woff = (w > 0) ? wsum[w - 1] : 0;
        if (i < n) rp[i] = carry + woff + s - x;
        __syncthreads();
        if (t == 0) carry += wsum[15];
        __syncthreads();
    }
    if (t == 0) rp[n] = carry;
}

__global__ __launch_bounds__(1024) void scan2_kernel(
        const int* __restrict__ cntA, int* __restrict__ rpA, int nA,
        const int* __restrict__ cntB, int* __restrict__ rpB, int nB) {
    scan_ex(cntA, rpA, nA);
    __syncthreads();
    scan_ex(cntB, rpB, nB);
}

__global__ void copy2_kernel(const int* __restrict__ rpA, const int* __restrict__ rpB,
                             int nA, int nB, int* __restrict__ cur) {
    int i = blockIdx.x * blockDim.x + threadIdx.x;
    if (i < nA) cur[i] = rpA[i];
    else if (i < nA + nB) cur[i] = rpB[i - nA];
}

__global__ void scatter2_kernel(const int* __restrict__ rowsA, const int* __restrict__ colsA,
                                const void* __restrict__ valsA, int nEA,
                                const int* __restrict__ rowsB, const int* __restrict__ colsB,
                                const void* __restrict__ valsB, int nEB,
                                int nA, int* __restrict__ cur,
                                unsigned* __restrict__ pairsA, unsigned* __restrict__ pairsB,
                                const int* __restrict__ dflag) {
    int i = blockIdx.x * blockDim.x + threadIdx.x;
    int isb = *dflag;
    if (i < nEA) {
        int p = atomicAdd(cur + rowsA[i], 1);
        pairsA[p] = pack_pair(colsA[i], loadf(valsA, i, isb));
    } else if (i < nEA + nEB) {
        int k = i - nEA;
        int p = atomicAdd(cur + nA + rowsB[k], 1);
        pairsB[p] = pack_pair(colsB[k], loadf(valsB, k, isb));
    }
}

// ======================= gather bodies (8-edge unroll, packed pairs) ===============
template<bool RELU>
__device__ __forceinline__ void gather_accum8(
        const int* __restrict__ rp, const unsigned* __restrict__ pairs,
        const void* __restrict__ src, int sisb, int row, int lane,
        float& tx, float& ty) {
    int e0 = rp[row], e1 = rp[row + 1];
    float accx[8], accy[8];
    #pragma unroll
    for (int k = 0; k < 8; ++k) { accx[k] = 0.f; accy[k] = 0.f; }
    int e = e0;
    if (sisb) {
        const bf16* sb = (const bf16*)src;
        for (; e + 8 <= e1; e += 8) {
            unsigned p[8], u[8];
            #pragma unroll
            for (int k = 0; k < 8; ++k) p[k] = pairs[e + k];
            #pragma unroll
            for (int k = 0; k < 8; ++k)
                u[k] = ((const unsigned*)(sb + (size_t)(p[k] & 0xffffu) * 128))[lane];
            #pragma unroll
            for (int k = 0; k < 8; ++k) {
                float v = b2f(p[k] >> 16);
                float x0 = b2f(u[k] & 0xffffu), x1 = b2f(u[k] >> 16);
                if (RELU) { x0 = fmaxf(x0, 0.f); x1 = fmaxf(x1, 0.f); }
                accx[k] = fmaf(v, x0, accx[k]);
                accy[k] = fmaf(v, x1, accy[k]);
            }
        }
        for (; e + 2 <= e1; e += 2) {
            unsigned p0 = pairs[e], p1 = pairs[e + 1];
            unsigned u0 = ((const unsigned*)(sb + (size_t)(p0 & 0xffffu) * 128))[lane];
            unsigned u1 = ((const unsigned*)(sb + (size_t)(p1 & 0xffffu) * 128))[lane];
            float v0 = b2f(p0 >> 16), v1 = b2f(p1 >> 16);
            float x0 = b2f(u0 & 0xffffu), x1 = b2f(u0 >> 16);
            float y0 = b2f(u1 & 0xffffu), y1 = b2f(u1 >> 16);
            if (RELU) {
                x0 = fmaxf(x0, 0.f); x1 = fmaxf(x1, 0.f);
                y0 = fmaxf(y0, 0.f); y1 = fmaxf(y1, 0.f);
            }
            accx[0] = fmaf(v0, x0, accx[0]); accy[0] = fmaf(v0, x1, accy[0]);
            accx[1] = fmaf(v1, y0, accx[1]); accy[1] = fmaf(v1, y1, accy[1]);
        }
        if (e < e1) {
            unsigned p = pairs[e];
            float v = b2f(p >> 16);
            unsigned u = ((const unsigned*)(sb + (size_t)(p & 0xffffu) * 128))[lane];
            float x0 = b2f(u & 0xffffu), x1 = b2f(u >> 16);
            if (RELU) { x0 = fmaxf(x0, 0.f); x1 = fmaxf(x1, 0.f); }
            accx[0] = fmaf(v, x0, accx[0]); accy[0] = fmaf(v, x1, accy[0]);
        }
    } else {
        const float* sf = (const float*)src;
        for (; e + 8 <= e1; e += 8) {
            unsigned p[8]; float2 u[8];
            #pragma unroll
            for (int k = 0; k < 8; ++k) p[k] = pairs[e + k];
            #pragma unroll
            for (int k = 0; k < 8; ++k)
                u[k] = ((const float2*)(sf + (size_t)(p[k] & 0xffffu) * 128))[lane];
            #pragma unroll
            for (int k = 0; k < 8; ++k) {
                float v = b2f(p[k] >> 16);
                float x0 = u[k].x, x1 = u[k].y;
                if (RELU) { x0 = fmaxf(x0, 0.f); x1 = fmaxf(x1, 0.f); }
                accx[k] = fmaf(v, x0, accx[k]);
                accy[k] = fmaf(v, x1, accy[k]);
            }
        }
        for (; e + 2 <= e1; e += 2) {
            unsigned p0 = pairs[e], p1 = pairs[e + 1];
            float2 x = ((const float2*)(sf + (size_t)(p0 & 0xffffu) * 128))[lane];
            float2 y = ((const float2*)(sf + (size_t)(p1 & 0xffffu) * 128))[lane];
            float v0 = b2f(p0 >> 16), v1 = b2f(p1 >> 16);
            if (RELU) {
                x.x = fmaxf(x.x, 0.f); x.y = fmaxf(x.y, 0.f);
                y.x = fmaxf(y.x, 0.f); y.y = fmaxf(y.y, 0.f);
            }
            accx[0] = fmaf(v0, x.x, accx[0]); accy[0] = fmaf(v0, x.y, accy[0]);
            accx[1] = fmaf(v1, y.x, accx[1]); accy[1] = fmaf(v1, y.y, accy[1]);
        }
        if (e < e1) {
            unsigned p = pairs[e];
            float v = b2f(p >> 16);
            float2 x = ((const float2*)(sf + (size_t)(p & 0xffffu) * 128))[lane];
            if (RELU) { x.x = fmaxf(x.x, 0.f); x.y = fmaxf(x.y, 0.f); }
            accx[0] = fmaf(v, x.x, accx[0]); accy[0] = fmaf(v, x.y, accy[0]);
        }
    }
    tx = ((accx[0] + accx[1]) + (accx[2] + accx[3])) + ((accx[4] + accx[5]) + (accx[6] + accx[7]));
    ty = ((accy[0] + accy[1]) + (accy[2] + accy[3])) + ((accy[4] + accy[5]) + (accy[6] + accy[7]));
}

template<bool RELU>
__device__ __forceinline__ void gather128_body(
        const int* __restrict__ rp, const unsigned* __restrict__ pairs,
        const void* __restrict__ src, int sisb,
        void* __restrict__ dst, int disb, int row, int lane) {
    float tx, ty;
    gather_accum8<RELU>(rp, pairs, src, sisb, row, lane, tx, ty);
    if (disb) {
        ((unsigned*)((bf16*)dst + (size_t)row * 128))[lane] = f2b(tx) | (f2b(ty) << 16);
    } else {
        ((float2*)((float*)dst + (size_t)row * 128))[lane] = make_float2(tx, ty);
    }
}

template<bool RELU>
__device__ __forceinline__ void norm128_body(
        const int* __restrict__ rp, const unsigned* __restrict__ pairs,
        const void* __restrict__ src, int sisb,
        void* __restrict__ out, size_t elem_off, int row, int lane, int isb) {
    float tx, ty;
    gather_accum8<RELU>(rp, pairs, src, sisb, row, lane, tx, ty);
    float ss = tx * tx + ty * ty;
    #pragma unroll
    for (int off = 32; off > 0; off >>= 1) ss += __shfl_down(ss, off);
    ss = __shfl(ss, 0);
    float inv = 1.0f / (sqrtf(ss) + 1e-9f);
    size_t base = elem_off + (size_t)row * 128;
    if (isb) {
        ((unsigned*)((bf16*)out + base))[lane] = f2b(tx * inv) | (f2b(ty * inv) << 16);
    } else {
        ((float2*)((float*)out + base))[lane] = make_float2(tx * inv, ty * inv);
    }
}

__device__ __forceinline__ void norm428_body(
        const int* __restrict__ rp, const unsigned* __restrict__ pairs,
        const void* __restrict__ src1, int s1b,
        const void* __restrict__ src2, int s2b,
        void* __restrict__ out, size_t elem_off, int row, int lane, int isb) {
    constexpr int P2 = D_WEMB / 2;   // 150
    int e0 = rp[row], e1 = rp[row + 1];
    float2 a1 = make_float2(0.f, 0.f), b1 = make_float2(0.f, 0.f);
    float2 a2[3], b2v[3];
    #pragma unroll
    for (int s = 0; s < 3; ++s) { a2[s] = make_float2(0.f, 0.f); b2v[s] = make_float2(0.f, 0.f); }
    int e = e0;
    for (; e + 2 <= e1; e += 2) {
        unsigned pp0 = pairs[e], pp1 = pairs[e + 1];
        int c0 = pp0 & 0xffffu, c1 = pp1 & 0xffffu;
        float v0 = b2f(pp0 >> 16), v1 = b2f(pp1 >> 16);
        float x0, x1, y0, y1;
        if (s1b) {
            unsigned u0 = ((const unsigned*)((const bf16*)src1 + (size_t)c0 * DD))[lane];
            unsigned u1 = ((const unsigned*)((const bf16*)src1 + (size_t)c1 * DD))[lane];
            x0 = b2f(u0 & 0xffffu); x1 = b2f(u0 >> 16);
            y0 = b2f(u1 & 0xffffu); y1 = b2f(u1 >> 16);
        } else {
            float2 x = ((const float2*)((const float*)src1 + (size_t)c0 * DD))[lane];
            float2 y = ((const float2*)((const float*)src1 + (size_t)c1 * DD))[lane];
            x0 = x.x; x1 = x.y; y0 = y.x; y1 = y.y;
        }
        x0 = fmaxf(x0, 0.f); x1 = fmaxf(x1, 0.f);
        y0 = fmaxf(y0, 0.f); y1 = fmaxf(y1, 0.f);
        a1.x = fmaf(v0, x0, a1.x); a1.y = fmaf(v0, x1, a1.y);
        b1.x = fmaf(v1, y0, b1.x); b1.y = fmaf(v1, y1, b1.y);
        if (s2b) {
            const unsigned* s0p = (const unsigned*)((const bf16*)src2 + (size_t)c0 * D_WEMB);
            const unsigned* s1p = (const unsigned*)((const bf16*)src2 + (size_t)c1 * D_WEMB);
            #pragma unroll
            for (int s = 0; s < 3; ++s) {
                int pi = lane + 64 * s;
                if (pi < P2) {
                    unsigned u0 = s0p[pi], u1 = s1p[pi];
                    a2[s].x  = fmaf(v0, b2f(u0 & 0xffffu), a2[s].x);
                    a2[s].y  = fmaf(v0, b2f(u0 >> 16),     a2[s].y);
                    b2v[s].x = fmaf(v1, b2f(u1 & 0xffffu), b2v[s].x);
                    b2v[s].y = fmaf(v1, b2f(u1 >> 16),     b2v[s].y);
                }
            }
        } else {
            const float2* s0p = (const float2*)((const float*)src2 + (size_t)c0 * D_WEMB);
            const float2* s1p = (const float2*)((const float*)src2 + (size_t)c1 * D_WEMB);
            #pragma unroll
            for (int s = 0; s < 3; ++s) {
                int pi = lane + 64 * s;
                if (pi < P2) {
                    float2 x = s0p[pi], y = s1p[pi];
                    a2[s].x  = fmaf(v0, x.x, a2[s].x);
                    a2[s].y  = fmaf(v0, x.y, a2[s].y);
                    b2v[s].x = fmaf(v1, y.x, b2v[s].x);
                    b2v[s].y = fmaf(v1, y.y, b2v[s].y);
                }
            }
        }
    }
    if (e < e1) {
        unsigned pp = pairs[e];
        int c = pp & 0xffffu;
        float v = b2f(pp >> 16);
        float x0, x1;
        if (s1b) {
            unsigned u = ((const unsigned*)((const bf16*)src1 + (size_t)c * DD))[lane];
            x0 = b2f(u & 0xffffu); x1 = b2f(u >> 16);
        } else {
            float2 x = ((const float2*)((const float*)src1 + (size_t)c * DD))[lane];
            x0 = x.x; x1 = x.y;
        }
        x0 = fmaxf(x0, 0.f); x1 = fmaxf(x1, 0.f);
        a1.x = fmaf(v, x0, a1.x); a1.y = fmaf(v, x1, a1.y);
        if (s2b) {
            const unsigned* sp = (const unsigned*)((const bf16*)src2 + (size_t)c * D_WEMB);
            #pragma unroll
            for (int s = 0; s < 3; ++s) {
                int pi = lane + 64 * s;
                if (pi < P2) {
                    unsigned u = sp[pi];
                    a2[s].x = fmaf(v, b2f(u & 0xffffu), a2[s].x);
                    a2[s].y = fmaf(v, b2f(u >> 16),     a2[s].y);
                }
            }
        } else {
            const float2* sp = (const float2*)((const float*)src2 + (size_t)c * D_WEMB);
            #pragma unroll
            for (int s = 0; s < 3; ++s) {
                int pi = lane + 64 * s;
                if (pi < P2) {
                    float2 x = sp[pi];
                    a2[s].x = fmaf(v, x.x, a2[s].x);
                    a2[s].y = fmaf(v, x.y, a2[s].y);
                }
            }
        }
    }
    float t1x = a1.x + b1.x, t1y = a1.y + b1.y;
    float t2x[3], t2y[3];
    #pragma unroll
    for (int s = 0; s < 3; ++s) { t2x[s] = a2[s].x + b2v[s].x; t2y[s] = a2[s].y + b2v[s].y; }
    float ss = t1x * t1x + t1y * t1y;
    #pragma unroll
    for (int s = 0; s < 3; ++s) {
        int pi = lane + 64 * s;
        if (pi < P2) ss += t2x[s] * t2x[s] + t2y[s] * t2y[s];
    }
    #pragma unroll
    for (int off = 32; off > 0; off >>= 1) ss += __shfl_down(ss, off);
    ss = __shfl(ss, 0);
    float inv = 1.0f / (sqrtf(ss) + 1e-9f);
    size_t base = elem_off + (size_t)row * (DD + D_WEMB);
    if (isb) {
        ((unsigned*)((bf16*)out + base))[lane] = f2b(t1x * inv) | (f2b(t1y * inv) << 16);
        unsigned* o2 = (unsigned*)((bf16*)out + base + DD);
        #pragma unroll
        for (int s = 0; s < 3; ++s) {
            int pi = lane + 64 * s;
            if (pi < P2) o2[pi] = f2b(t2x[s] * inv) | (f2b(t2y[s] * inv) << 16);
        }
    } else {
        ((float2*)((float*)out + base))[lane] = make_float2(t1x * inv, t1y * inv);
        float2* o2 = (float2*)((float*)out + base + DD);
        #pragma unroll
        for (int s = 0; s < 3; ++s) {
            int pi = lane + 64 * s;
            if (pi < P2) o2[pi] = make_float2(t2x[s] * inv, t2y[s] * inv);
        }
    }
}

// ======================= gather kernels =======================
template<bool RELU>
__global__ void spmm_gather128(const int* __restrict__ rowptr, const unsigned* __restrict__ pairs,
                               const void* __restrict__ src, int src_flagged,
                               void* __restrict__ dst, int dst_flagged,
                               int n, const int* __restrict__ dflag) {
    int row = blockIdx.x * 4 + (threadIdx.x >> 6);
    if (row >= n) return;
    int isb = *dflag;
    gather128_body<RELU>(rowptr, pairs, src, src_flagged ? isb : 0,
                         dst, dst_flagged ? isb : 0, row, threadIdx.x & 63);
}

template<bool RELU>
__global__ void spmm_gather128_b2(const int* __restrict__ G, const unsigned* __restrict__ pairs,
                                  int roff1, const void* __restrict__ src1, void* __restrict__ dst1, int n1, int B1,
                                  int roff2, const void* __restrict__ src2, void* __restrict__ dst2, int n2,
                                  int src_flagged, int dst_flagged, const int* __restrict__ dflag) {
    int isb = *dflag;
    int sisb = src_flagged ? isb : 0;
    int disb = dst_flagged ? isb : 0;
    int lane = threadIdx.x & 63;
    int b = blockIdx.x;
    if (b < B1) {
        int row = b * 4 + (threadIdx.x >> 6);
        if (row >= n1) return;
        gather128_body<RELU>(G + roff1, pairs, src1, sisb, dst1, disb, row, lane);
    } else {
        int row = (b - B1) * 4 + (threadIdx.x >> 6);
        if (row >= n2) return;
        gather128_body<RELU>(G + roff2, pairs, src2, sisb, dst2, disb, row, lane);
    }
}

template<bool RELU>
__global__ void spmm_norm128(const int* __restrict__ rowptr, const unsigned* __restrict__ pairs,
                             const void* __restrict__ src, int src_flagged,
                             void* __restrict__ out, size_t elem_off,
                             int n, const int* __restrict__ dflag) {
    int row = blockIdx.x * 4 + (threadIdx.x >> 6);
    if (row >= n) return;
    int isb = *dflag;
    norm128_body<RELU>(rowptr, pairs, src, src_flagged ? isb : 0, out, elem_off,
                       row, threadIdx.x & 63, isb);
}

__global__ void spmm2_norm(const int* __restrict__ rowptr, const unsigned* __restrict__ pairs,
                           const void* __restrict__ src1, int s1_flagged,
                           const void* __restrict__ src2, int s2_flagged,
                           void* __restrict__ out, size_t elem_off,
                           int n, const int* __restrict__ dflag) {
    int row = blockIdx.x * 4 + (threadIdx.x >> 6);
    if (row >= n) return;
    int isb = *dflag;
    norm428_body(rowptr, pairs, src1, s1_flagged ? isb : 0, src2, s2_flagged ? isb : 0,
                 out, elem_off, row, threadIdx.x & 63, isb);
}

// BIG path: all 3 output norms in ONE launch.
__global__ void final_norm_all(const int* __restrict__ G, const unsigned* __restrict__ pairs,
                               const void* __restrict__ s1, const void* __restrict__ e0b,
                               const void* __restrict__ wemb, const void* __restrict__ p3b,
                               void* __restrict__ out,
                               size_t off1, size_t off2, size_t off3,
                               const int* __restrict__ dflag) {
    int isb = *dflag;
    int lane = threadIdx.x & 63;
    int b = blockIdx.x;
    if (b < 2500) {
        int row = b * 4 + (threadIdx.x >> 6);
        if (row >= N_DOC) return;
        norm128_body<true>(G + ROFF01, pairs, s1, isb, out, off1, row, lane, isb);
    } else if (b < 5000) {
        int row = (b - 2500) * 4 + (threadIdx.x >> 6);
        if (row >= N_DOC) return;
        norm428_body(G + ROFF02, pairs, e0b, isb, wemb, isb, out, off2, row, lane, isb);
    } else {
        int row = (b - 5000) * 4 + (threadIdx.x >> 6);
        if (row >= N_DOC) return;
        norm128_body<true>(G + ROFF03, pairs, p3b, isb, out, off3, row, lane, isb);
    }
}

// ======================= atomic SpMM (deep fallback) =======================
template<bool RELU>
__global__ void spmm_kernel(const int* __restrict__ rows, const int* __restrict__ cols,
                            const void* __restrict__ vals,
                            const void* __restrict__ src, int sstride, int src_flagged,
                            float* __restrict__ dst, int dstride, int doff,
                            int d, int nE, const int* __restrict__ dflag) {
    int e = blockIdx.x * (blockDim.x >> 6) + (threadIdx.x >> 6);
    if (e >= nE) return;
    int isb  = *dflag;
    int sisb = src_flagged ? isb : 0;
    int lane = threadIdx.x & 63;
    int r = rows[e];
    int c = cols[e];
    float v = loadf(vals, e, isb);
    size_t sbase = (size_t)c * sstride;
    float* dp = dst + (size_t)r * dstride + doff;
    if (sisb) {
        const unsigned* sp = (const unsigned*)((const bf16*)src + sbase);
        for (int j = 2 * lane; j < d; j += 128) {
            unsigned u = sp[j >> 1];
            float x0 = b2f(u & 0xffffu);
            float x1 = b2f(u >> 16);
            if (RELU) { x0 = fmaxf(x0, 0.f); x1 = fmaxf(x1, 0.f); }
            atomicAdd(dp + j,     v * x0);
            atomicAdd(dp + j + 1, v * x1);
        }
    } else {
        const float2* sp = (const float2*)((const float*)src + sbase);
        for (int j = 2 * lane; j < d; j += 128) {
            float2 x = sp[j >> 1];
            if (RELU) { x.x = fmaxf(x.x, 0.f); x.y = fmaxf(x.y, 0.f); }
            atomicAdd(dp + j,     v * x.x);
            atomicAdd(dp + j + 1, v * x.y);
        }
    }
}

// ======================= dense GEMMs =======================
// 64-col tile in 32 KB LDS; packed col-pair stores. X fp32; out/W/b follow isb.
template<bool RELU>
__device__ __forceinline__ void gemm_tile_body(
        const float* __restrict__ X, const void* __restrict__ W,
        const void* __restrict__ b, void* __restrict__ out, int n,
        int bx, int by, int isb, float* Wl /*128*64*/) {
    if (bx * 64 >= n) return;
    int tid = threadIdx.x;
    int jc = by * 64;
    if (isb) {
        const uint2* Wg = (const uint2*)W;
        float4* Wl4 = (float4*)Wl;
        for (int vidx = tid; vidx < 2048; vidx += 256) {
            int k = vidx >> 4, jl4 = vidx & 15;
            uint2 u = Wg[k * 32 + (jc >> 2) + jl4];
            float4 vv;
            vv.x = b2f(u.x & 0xffffu);
            vv.y = b2f(u.x >> 16);
            vv.z = b2f(u.y & 0xffffu);
            vv.w = b2f(u.y >> 16);
            Wl4[vidx] = vv;
        }
    } else {
        const float4* Wg = (const float4*)W;
        float4* Wl4 = (float4*)Wl;
        for (int vidx = tid; vidx < 2048; vidx += 256) {
            int k = vidx >> 4, jl4 = vidx & 15;
            Wl4[vidx] = Wg[k * 32 + (jc >> 2) + jl4];
        }
    }
    __syncthreads();
    int j2 = tid & 31;
    int g  = tid >> 5;
    float bc0 = loadf(b, jc + 2 * j2, isb);
    float bc1 = loadf(b, jc + 2 * j2 + 1, isb);
    int i0 = bx * 64 + g * 8;
    float a0[8], a1[8];
    #pragma unroll
    for (int r = 0; r < 8; ++r) { a0[r] = bc0; a1[r] = bc1; }
    const float4* xp = (const float4*)(X + (size_t)i0 * 128);
    const float2* Wl2 = (const float2*)Wl;
    #pragma unroll 2
    for (int k4 = 0; k4 < 32; ++k4) {
        float2 w0 = Wl2[(4 * k4 + 0) * 32 + j2];
        float2 w1 = Wl2[(4 * k4 + 1) * 32 + j2];
        float2 w2 = Wl2[(4 * k4 + 2) * 32 + j2];
        float2 w3 = Wl2[(4 * k4 + 3) * 32 + j2];
        #pragma unroll
        for (int r = 0; r < 8; ++r) {
            float4 v = xp[r * 32 + k4];
            if (RELU) {
                v.x = fmaxf(v.x, 0.f); v.y = fmaxf(v.y, 0.f);
                v.z = fmaxf(v.z, 0.f); v.w = fmaxf(v.w, 0.f);
            }
            a0[r] = fmaf(v.w, w3.x, fmaf(v.z, w2.x, fmaf(v.y, w1.x, fmaf(v.x, w0.x, a0[r]))));
            a1[r] = fmaf(v.w, w3.y, fmaf(v.z, w2.y, fmaf(v.y, w1.y, fmaf(v.x, w0.y, a1[r]))));
        }
    }
    #pragma unroll
    for (int r = 0; r < 8; ++r) {
        int i = i0 + r;
        if (i < n) {
            if (isb) {
                ((unsigned*)((bf16*)out + (size_t)i * 128 + jc))[j2] =
                    f2b(a0[r]) | (f2b(a1[r]) << 16);
            } else {
                ((float2*)((float*)out + (size_t)i * 128 + jc))[j2] =
                    make_float2(a0[r], a1[r]);
            }
        }
    }
}

template<bool RELU>
__global__ __launch_bounds__(256) void gemm_tile(
        const float* __restrict__ X, const void* __restrict__ W,
        const void* __restrict__ b, void* __restrict__ out, int n,
        const int* __restrict__ dflag) {
    __shared__ float Wl[128 * 64];
    gemm_tile_body<RELU>(X, W, b, out, n, blockIdx.x, blockIdx.y, *dflag, Wl);
}

template<bool RELU>
__global__ __launch_bounds__(256) void gemm_tile_b2(
        const float* __restrict__ X1, const void* __restrict__ W1, const void* __restrict__ b1,
        void* __restrict__ out1, int n1, int G1,
        const float* __restrict__ X2, const void* __restrict__ W2, const void* __restrict__ b2,
        void* __restrict__ out2, int n2,
        const int* __restrict__ dflag) {
    __shared__ float Wl[128 * 64];
    int isb = *dflag;
    if ((int)blockIdx.x < G1)
        gemm_tile_body<RELU>(X1, W1, b1, out1, n1, blockIdx.x, blockIdx.y, isb, Wl);
    else
        gemm_tile_body<RELU>(X2, W2, b2, out2, n2, blockIdx.x - G1, blockIdx.y, isb, Wl);
}

// Legacy big-LDS GEMM (deep fallback only; fp32 ws).
template<bool RELU>
__global__ __launch_bounds__(256) void gemm128_kernel(
        const float* __restrict__ X, const void* __restrict__ W,
        const void* __restrict__ b, float* __restrict__ out, int n,
        const int* __restrict__ dflag) {
    __shared__ float Wl[128 * 128];
    int isb = *dflag;
    int tid = threadIdx.x;
    if (isb) {
        const uint2* Wg = (const uint2*)W;
        float4* Wl4 = (float4*)Wl;
        for (int idx = tid; idx < 4096; idx += 256) {
            uint2 u = Wg[idx];
            float4 vv;
            vv.x = b2f(u.x & 0xffffu);
            vv.y = b2f(u.x >> 16);
            vv.z = b2f(u.y & 0xffffu);
            vv.w = b2f(u.y >> 16);
            Wl4[idx] = vv;
        }
    } else {
        const float4* Wg = (const float4*)W;
        float4* Wl4 = (float4*)Wl;
        for (int idx = tid; idx < 4096; idx += 256) Wl4[idx] = Wg[idx];
    }
    __syncthreads();
    int j = tid & 127;
    int h = tid >> 7;
    float bj = loadf(b, j, isb);
    int row0 = blockIdx.x * 64 + h * 32;
    for (int q = 0; q < 8; ++q) {
        int gi = row0 + q * 4;
        if (gi >= n) break;
        const float4* x0 = (const float4*)(X + (size_t)gi * 128);
        const float4* x1 = x0 + 32;
        const float4* x2 = x1 + 32;
        const float4* x3 = x2 + 32;
        float a0 = bj, a1 = bj, a2 = bj, a3 = bj;
        #pragma unroll 4
        for (int k4 = 0; k4 < 32; ++k4) {
            float4 v0 = x0[k4], v1 = x1[k4], v2 = x2[k4], v3 = x3[k4];
            if (RELU) {
                v0.x = fmaxf(v0.x, 0.f); v0.y = fmaxf(v0.y, 0.f); v0.z = fmaxf(v0.z, 0.f); v0.w = fmaxf(v0.w, 0.f);
                v1.x = fmaxf(v1.x, 0.f); v1.y = fmaxf(v1.y, 0.f); v1.z = fmaxf(v1.z, 0.f); v1.w = fmaxf(v1.w, 0.f);
                v2.x = fmaxf(v2.x, 0.f); v2.y = fmaxf(v2.y, 0.f); v2.z = fmaxf(v2.z, 0.f); v2.w = fmaxf(v2.w, 0.f);
                v3.x = fmaxf(v3.x, 0.f); v3.y = fmaxf(v3.y, 0.f); v3.z = fmaxf(v3.z, 0.f); v3.w = fmaxf(v3.w, 0.f);
            }
            float w0 = Wl[(4 * k4 + 0) * 128 + j];
            float w1 = Wl[(4 * k4 + 1) * 128 + j];
            float w2 = Wl[(4 * k4 + 2) * 128 + j];
            float w3 = Wl[(4 * k4 + 3) * 128 + j];
            a0 = fmaf(v0.w, w3, fmaf(v0.z, w2, fmaf(v0.y, w1, fmaf(v0.x, w0, a0))));
            a1 = fmaf(v1.w, w3, fmaf(v1.z, w2, fmaf(v1.y, w1, fmaf(v1.x, w0, a1))));
            a2 = fmaf(v2.w, w3, fmaf(v2.z, w2, fmaf(v2.y, w1, fmaf(v2.x, w0, a2))));
            a3 = fmaf(v3.w, w3, fmaf(v3.z, w2, fmaf(v3.y, w1, fmaf(v3.x, w0, a3))));
        }
        float* o = out + (size_t)gi * 128 + j;
        o[0] = a0; o[128] = a1; o[256] = a2; o[384] = a3;
    }
}

// Row-parallel tiny GEMM (type-3, n=60): one block per row, 128 threads.
template<bool RELU, int K>
__global__ void rowpar_gemm(const void* __restrict__ X, int x_flagged,
                            const void* __restrict__ W, const void* __restrict__ b,
                            void* __restrict__ out, int out_flagged,
                            const int* __restrict__ dflag) {
    __shared__ float xr[K];
    int isb  = *dflag;
    int xisb = x_flagged ? isb : 0;
    int oisb = out_flagged ? isb : 0;
    int row = blockIdx.x;
    int j = threadIdx.x;
    if (j < K) {
        float x = loadf(X, (size_t)row * K + j, xisb);
        if (RELU) x = fmaxf(x, 0.f);
        xr[j] = x;
    }
    __syncthreads();
    float acc = loadf(b, j, isb);
    #pragma unroll 8
    for (int k = 0; k < K; ++k)
        acc = fmaf(xr[k], loadf(W, (size_t)k * 128 + j, isb), acc);
    storef(out, (size_t)row * 128 + j, oisb, acc);
}

// Generic small GEMM (deep fallback only).
template<bool RELU, int K>
__global__ void gemm_kernel(const void* __restrict__ X, int x_flagged,
                            const void* __restrict__ W,
                            const void* __restrict__ b,
                            float* __restrict__ out, int n,
                            const int* __restrict__ dflag) {
    __shared__ float Wl[K * 128];
    int isb  = *dflag;
    int xisb = x_flagged ? isb : 0;
    int j = threadIdx.x;
    for (int idx = j; idx < K * 128; idx += 128)
        Wl[idx] = loadf(W, idx, isb);
    __syncthreads();
    float bj = loadf(b, j, isb);
    int row0 = blockIdx.x * 64;
    for (int i0 = 0; i0 < 64; i0 += 4) {
        int i = row0 + i0;
        if (i >= n) break;
        size_t r0 = (size_t)i * K;
        float a0 = bj, a1 = bj, a2 = bj, a3 = bj;
        for (int k = 0; k < K; ++k) {
            float w = Wl[k * 128 + j];
            float v0 = loadf(X, r0 + k, xisb);
            float v1 = loadf(X, r0 + K + k, xisb);
            float v2 = loadf(X, r0 + 2 * K + k, xisb);
            float v3 = loadf(X, r0 + 3 * K + k, xisb);
            if (RELU) {
                v0 = fmaxf(v0, 0.f); v1 = fmaxf(v1, 0.f);
                v2 = fmaxf(v2, 0.f); v3 = fmaxf(v3, 0.f);
            }
            a0 = fmaf(v0, w, a0);
            a1 = fmaf(v1, w, a1);
            a2 = fmaf(v2, w, a2);
            a3 = fmaf(v3, w, a3);
        }
        float* o = out + (size_t)i * 128 + j;
        o[0] = a0; o[128] = a1; o[256] = a2; o[384] = a3;
    }
}

// L2-norm (deep fallback only).
__global__ void l2norm_kernel(const float* __restrict__ agg, int d,
                              void* __restrict__ out, size_t elem_off, int n,
                              const int* __restrict__ dflag) {
    int row = blockIdx.x * (blockDim.x >> 6) + (threadIdx.x >> 6);
    if (row >= n) return;
    int isb  = *dflag;
    int lane = threadIdx.x & 63;
    const float2* a2 = (const float2*)(agg + (size_t)row * d);
    float ss = 0.f;
    for (int j = 2 * lane; j < d; j += 128) {
        float2 x = a2[j >> 1];
        ss += x.x * x.x + x.y * x.y;
    }
    #pragma unroll
    for (int off = 32; off > 0; off >>= 1) ss += __shfl_down(ss, off);
    ss = __shfl(ss, 0);
    float inv = 1.0f / (sqrtf(ss) + 1e-9f);
    size_t bbase = elem_off + (size_t)row * d;
    if (isb) {
        unsigned* o = (unsigned*)((bf16*)out + bbase);
        for (int j = 2 * lane; j < d; j += 128) {
            float2 x = a2[j >> 1];
            o[j >> 1] = f2b(x.x * inv) | (f2b(x.y * inv) << 16);
        }
    } else {
        float2* o = (float2*)((float*)out + bbase);
        for (int j = 2 * lane; j < d; j += 128) {
            float2 x = a2[j >> 1];
            o[j >> 1] = make_float2(x.x * inv, x.y * inv);
        }
    }
}

static inline int spmm_grid(int nE) { return (nE + 3) / 4; }
static inline int row_grid(int n)   { return (n + 3) / 4; }
static inline int pad8(int x)       { return (x + 7) & ~7; }

// Mid-path per-phase CSR build (packed pairs).
static void build2(hipStream_t stream,
                   const int* rowsA, const int* colsA, const void* valsA, int nA, int nEA,
                   const int* rowsB, const int* colsB, const void* valsB, int nB, int nEB,
                   int* rpA, int* rpB, int* curAB, unsigned* pairsA, unsigned* pairsB,
                   const int* dflag) {
    int nE = nEA + nEB;
    hipMemsetAsync(curAB, 0, (size_t)(nA + nB) * 4, stream);
    hist2_kernel<<<(nE + 255) / 256, 256, 0, stream>>>(rowsA, nEA, rowsB, nEB, nA, curAB);
    scan2_kernel<<<1, 1024, 0, stream>>>(curAB, rpA, nA, curAB + nA, rpB, nB);
    copy2_kernel<<<(nA + nB + 255) / 256, 256, 0, stream>>>(rpA, rpB, nA, nB, curAB);
    scatter2_kernel<<<(nE + 255) / 256, 256, 0, stream>>>(
        rowsA, colsA, valsA, nEA, rowsB, colsB, valsB, nEB, nA, curAB, pairsA, pairsB, dflag);
}

extern "C" void kernel_launch(void* const* d_in, const int* in_sizes, int n_in,
                              void* d_out, int out_size, void* d_ws, size_t ws_size,
                              hipStream_t stream) {
    const void* f1   = d_in[0];
    const void* f2   = d_in[1];
    const void* f3   = d_in[2];
    const void* wemb = d_in[3];
    const int*  a11r = (const int*)d_in[4];
    const int*  a11c = (const int*)d_in[5];
    const void* a11v = d_in[6];
    const int*  a22r = (const int*)d_in[7];
    const int*  a22c = (const int*)d_in[8];
    const void* a22v = d_in[9];
    const int*  a33r = (const int*)d_in[10];
    const int*  a33c = (const int*)d_in[11];
    const void* a33v = d_in[12];
    const int*  a01r = (const int*)d_in[13];
    const int*  a01c = (const int*)d_in[14];
    const void* a01v = d_in[15];
    const int*  a02r = (const int*)d_in[16];
    const int*  a02c = (const int*)d_in[17];
    const void* a02v = d_in[18];
    const int*  a03r = (const int*)d_in[19];
    const int*  a03c = (const int*)d_in[20];
    const void* a03v = d_in[21];
    const void* W3   = d_in[22];
    const void* b3   = d_in[23];
    const void* W1_2 = d_in[24];
    const void* b1_2 = d_in[25];
    const void* W2_2 = d_in[26];
    const void* b2_2 = d_in[27];
    const void* W3_2 = d_in[28];
    const void* b3_2 = d_in[29];

    int*   dflag = (int*)d_ws;
    float* base  = (float*)d_ws + 16;

    const size_t OUT1_OFF = 0;
    const size_t OUT2_OFF = (size_t)N_DOC * DD;                       // 1,280,000
    const size_t OUT3_OFF = OUT2_OFF + (size_t)N_DOC * (DD + D_WEMB); // 5,560,000

    dim3 blk(256);
    detect_kernel<<<1, 256, 0, stream>>>((const unsigned*)f1, dflag);

    const size_t BF_S0 = 0, BF_S1 = 2560000, BF_E0 = 5120000, BF_E1 = 6400000;
    const size_t BF_P3A = 7680000, BF_P3B = 7687680, BF_INT = 7695360;
    // ints: G(NROWS+1) + cur(NROWS) + bsum(64) + boff(64) + pairs(NEDGES, 4B each)
    const size_t BIG_INTS = (size_t)(NROWS + 1) + NROWS + 128 + NEDGES + 8; // ~1.15M
    const size_t WS_BIG = 64 + (BF_INT + BIG_INTS) * 4;               // ~35.4 MB
    const size_t WS_MID = 64 + 22240000ull + (60008ull + 620000ull) * 4; // ~25 MB

    if (ws_size >= WS_BIG) {
        // ======================= BIG batched path =======================
        float* S0  = base + BF_S0;
        float* S1  = base + BF_S1;
        float* E0  = base + BF_E0;
        float* E1  = base + BF_E1;
        float* P3a = base + BF_P3A;
        float* P3b = base + BF_P3B;
        int*   G    = (int*)(base + BF_INT);
        int*   cur  = G + (NROWS + 1);
        int*   bsum = cur + NROWS;
        int*   boff = bsum + 64;
        unsigned* pairs = (unsigned*)(boff + 64);

        const int NB = (NROWS + 1023) / 1024;   // 59
        hipMemsetAsync(cur, 0, (size_t)NROWS * 4, stream);
        hist_all<<<(NEDGES + 255) / 256, 256, 0, stream>>>(
            a11r, a22r, a33r, a01r, a02r, a03r, cur);
        scan_part<<<NB, 1024, 0, stream>>>(cur, G, bsum, NROWS);
        scan_tops<<<1, 64, 0, stream>>>(bsum, boff, NB, G, NROWS);
        scan_fix<<<(NROWS + 255) / 256, 256, 0, stream>>>(G, boff, cur, NROWS);
        scatter_all<<<(NEDGES + 255) / 256, 256, 0, stream>>>(
            a11r, a11c, a11v, a22r, a22c, a22v, a33r, a33c, a33v,
            a01r, a01c, a01v, a02r, a02c, a02v, a03r, a03c, a03v,
            cur, pairs, dflag);

        rowpar_gemm<false, 60><<<N_POS, 128, 0, stream>>>(
            f3, 1, W3, b3, P3a, 1, dflag);                              // P3a = f3@W3+b3

        {
            int B1 = row_grid(N_WORD), B2 = row_grid(N_ENT);
            spmm_gather128_b2<false><<<B1 + B2, blk, 0, stream>>>(
                G, pairs, ROFF11, f1, S0, N_WORD, B1,
                ROFF22, f2, E0, N_ENT, 1, 0, dflag);                    // hop1 (fp32 out)
        }
        {
            int G1 = pad8((N_WORD + 63) / 64), G2 = pad8((N_ENT + 63) / 64);
            gemm_tile_b2<true><<<dim3(G1 + G2, 2), 256, 0, stream>>>(
                S0, W1_2, b1_2, S1, N_WORD, G1,
                E0, W2_2, b2_2, E1, N_ENT, dflag);                      // gemm batch
        }
        {
            int B1 = row_grid(N_WORD), B2 = row_grid(N_ENT);
            spmm_gather128_b2<false><<<B1 + B2, blk, 0, stream>>>(
                G, pairs, ROFF11, S1, S0, N_WORD, B1,
                ROFF22, E1, E0, N_ENT, 1, 1, dflag);                    // hop2 (flagged out)
        }
        spmm_gather128<false><<<row_grid(N_POS), blk, 0, stream>>>(
            G + ROFF33, pairs, P3a, 1, P3b, 1, N_POS, dflag);
        rowpar_gemm<true, 128><<<N_POS, 128, 0, stream>>>(
            P3b, 1, W3_2, b3_2, P3a, 1, dflag);
        spmm_gather128<false><<<row_grid(N_POS), blk, 0, stream>>>(
            G + ROFF33, pairs, P3a, 1, P3b, 1, N_POS, dflag);

        final_norm_all<<<7500, blk, 0, stream>>>(
            G, pairs, S0, E0, wemb, P3b, d_out, OUT1_OFF, OUT2_OFF, OUT3_OFF, dflag);
    } else if (ws_size >= WS_MID) {
        // ======================= mid path =======================
        float* S0   = base;
        float* S1   = base + 2560000;
        float* E0   = base;
        float* E1   = base + 1280000;
        float* P3a  = base;
        float* P3b  = base + 7680;
        int* I = (int*)(base + 5560000);
        {
            int* rpA = I; int* rpB = rpA + (N_WORD + 1); int* cur = rpB + (N_DOC + 1);
            unsigned* pA = (unsigned*)(cur + N_WORD + N_DOC); unsigned* pB = pA + E11;
            build2(stream, a11r, a11c, a11v, N_WORD, E11,
                   a01r, a01c, a01v, N_DOC, E01, rpA, rpB, cur, pA, pB, dflag);
            spmm_gather128<false><<<row_grid(N_WORD), blk, 0, stream>>>(
                rpA, pA, f1, 1, S0, 0, N_WORD, dflag);
            gemm_tile<true><<<dim3(pad8((N_WORD + 63) / 64), 2), 256, 0, stream>>>(
                S0, W1_2, b1_2, S1, N_WORD, dflag);
            spmm_gather128<false><<<row_grid(N_WORD), blk, 0, stream>>>(
                rpA, pA, S1, 1, S0, 1, N_WORD, dflag);
            spmm_norm128<true><<<row_grid(N_DOC), blk, 0, stream>>>(
                rpB, pB, S0, 1, d_out, OUT1_OFF, N_DOC, dflag);
        }
        {
            int* rpA = I; int* rpB = rpA + (N_ENT + 1); int* cur = rpB + (N_DOC + 1);
            unsigned* pA = (unsigned*)(cur + N_ENT + N_DOC); unsigned* pB = pA + E22;
            build2(stream, a22r, a22c, a22v, N_ENT, E22,
                   a02r, a02c, a02v, N_DOC, E02, rpA, rpB, cur, pA, pB, dflag);
            spmm_gather128<false><<<row_grid(N_ENT), blk, 0, stream>>>(
                rpA, pA, f2, 1, E0, 0, N_ENT, dflag);
            gemm_tile<true><<<dim3(pad8((N_ENT + 63) / 64), 2), 256, 0, stream>>>(
                E0, W2_2, b2_2, E1, N_ENT, dflag);
            spmm_gather128<false><<<row_grid(N_ENT), blk, 0, stream>>>(
                rpA, pA, E1, 1, E0, 1, N_ENT, dflag);
            spmm2_norm<<<row_grid(N_DOC), blk, 0, stream>>>(
                rpB, pB, E0, 1, wemb, 1, d_out, OUT2_OFF, N_DOC, dflag);
        }
        {
            int* rpA = I; int* rpB = rpA + (N_POS + 1); int* cur = rpB + (N_DOC + 1);
            unsigned* pA = (unsigned*)(cur + N_POS + N_DOC); unsigned* pB = pA + E33;
            build2(stream, a33r, a33c, a33v, N_POS, E33,
                   a03r, a03c, a03v, N_DOC, E03, rpA, rpB, cur, pA, pB, dflag);
            rowpar_gemm<false, 60><<<N_POS, 128, 0, stream>>>(
                f3, 1, W3, b3, P3a, 1, dflag);
            spmm_gather128<false><<<row_grid(N_POS), blk, 0, stream>>>(
                rpA, pA, P3a, 1, P3b, 1, N_POS, dflag);
            rowpar_gemm<true, 128><<<N_POS, 128, 0, stream>>>(
                P3b, 1, W3_2, b3_2, P3a, 1, dflag);
            spmm_gather128<false><<<row_grid(N_POS), blk, 0, stream>>>(
                rpA, pA, P3a, 1, P3b, 1, N_POS, dflag);
            spmm_norm128<true><<<row_grid(N_DOC), blk, 0, stream>>>(
                rpB, pB, P3b, 1, d_out, OUT3_OFF, N_DOC, dflag);
        }
    } else {
        // ======================= deep fallback: atomic path =======================
        float* S0   = base;
        float* S1   = base + 2560000;
        float* AGG1 = S1;
        float* E0   = base;
        float* E1   = base + 1280000;
        float* AGG2 = base + 1280000;
        float* P3a  = base;
        float* P3b  = base + 7680;
        float* AGG3 = base + 15360;
        hipMemsetAsync(S0, 0, (size_t)N_WORD * DD * 4, stream);
        spmm_kernel<false><<<spmm_grid(E11), blk, 0, stream>>>(
            a11r, a11c, a11v, f1, DD, 1, S0, DD, 0, DD, E11, dflag);
        gemm128_kernel<true><<<(N_WORD + 63) / 64, 256, 0, stream>>>(
            S0, W1_2, b1_2, S1, N_WORD, dflag);
        hipMemsetAsync(S0, 0, (size_t)N_WORD * DD * 4, stream);
        spmm_kernel<false><<<spmm_grid(E11), blk, 0, stream>>>(
            a11r, a11c, a11v, S1, DD, 0, S0, DD, 0, DD, E11, dflag);
        hipMemsetAsync(AGG1, 0, (size_t)N_DOC * DD * 4, stream);
        spmm_kernel<true><<<spmm_grid(E01), blk, 0, stream>>>(
            a01r, a01c, a01v, S0, DD, 0, AGG1, DD, 0, DD, E01, dflag);
        l2norm_kernel<<<row_grid(N_DOC), blk, 0, stream>>>(
            AGG1, DD, d_out, OUT1_OFF, N_DOC, dflag);

        hipMemsetAsync(E0, 0, (size_t)N_ENT * DD * 4, stream);
        spmm_kernel<false><<<spmm_grid(E22), blk, 0, stream>>>(
            a22r, a22c, a22v, f2, DD, 1, E0, DD, 0, DD, E22, dflag);
        gemm128_kernel<true><<<(N_ENT + 63) / 64, 256, 0, stream>>>(
            E0, W2_2, b2_2, E1, N_ENT, dflag);
        hipMemsetAsync(E0, 0, (size_t)N_ENT * DD * 4, stream);
        spmm_kernel<false><<<spmm_grid(E22), blk, 0, stream>>>(
            a22r, a22c, a22v, E1, DD, 0, E0, DD, 0, DD, E22, dflag);
        hipMemsetAsync(AGG2, 0, (size_t)N_DOC * (DD + D_WEMB) * 4, stream);
        spmm_kernel<true><<<spmm_grid(E02), blk, 0, stream>>>(
            a02r, a02c, a02v, E0, DD, 0, AGG2, DD + D_WEMB, 0, DD, E02, dflag);
        spmm_kernel<false><<<spmm_grid(E02), blk, 0, stream>>>(
            a02r, a02c, a02v, wemb, D_WEMB, 1, AGG2, DD + D_WEMB, DD, D_WEMB, E02, dflag);
        l2norm_kernel<<<row_grid(N_DOC), blk, 0, stream>>>(
            AGG2, DD + D_WEMB, d_out, OUT2_OFF, N_DOC, dflag);

        gemm_kernel<false, 60><<<1, 128, 0, stream>>>(f3, 1, W3, b3, P3a, N_POS, dflag);
        hipMemsetAsync(P3b, 0, (size_t)N_POS * DD * 4, stream);
        spmm_kernel<false><<<spmm_grid(E33), blk, 0, stream>>>(
            a33r, a33c, a33v, P3a, DD, 0, P3b, DD, 0, DD, E33, dflag);
        gemm128_kernel<true><<<1, 256, 0, stream>>>(
            P3b, W3_2, b3_2, P3a, N_POS, dflag);
        hipMemsetAsync(P3b, 0, (size_t)N_POS * DD * 4, stream);
        spmm_kernel<false><<<spmm_grid(E33), blk, 0, stream>>>(
            a33r, a33c, a33v, P3a, DD, 0, P3b, DD, 0, DD, E33, dflag);
        hipMemsetAsync(AGG3, 0, (size_t)N_DOC * DD * 4, stream);
        spmm_kernel<true><<<spmm_grid(E03), blk, 0, stream>>>(
            a03r, a03c, a03v, P3b, DD, 0, AGG3, DD, 0, DD, E03, dflag);
        l2norm_kernel<<<row_grid(N_DOC), blk, 0, stream>>>(
            AGG3, DD, d_out, OUT3_OFF, N_DOC, dflag);
    }
}

// Round 16
// 410.434 us; speedup vs baseline: 1.5935x; 1.0240x over previous
//
#include <hip/hip_runtime.h>
#include <hip/hip_bf16.h>

typedef __hip_bfloat16 bf16;

#define N_DOC   10000
#define N_WORD  20000
#define N_ENT   10000
#define N_POS   60
#define DD      128
#define D_WEMB  300
#define E11     320000
#define E22     160000
#define E33     3600
#define E01     300000
#define E02     100000
#define E03     150000

// Concatenated row/edge segment offsets for the fused 6-matrix CSR build.
#define ROFF11  0
#define ROFF22  20000
#define ROFF33  30000
#define ROFF01  30060
#define ROFF02  40060
#define ROFF03  50060
#define NROWS   60060
#define EOFF11  0
#define EOFF22  320000
#define EOFF33  480000
#define EOFF01  483600
#define EOFF02  783600
#define EOFF03  883600
#define NEDGES  1033600

// Runtime dtype flag (ws[0]): 1 if float inputs are packed bf16, 0 if fp32.
__device__ __forceinline__ float loadf(const void* p, size_t i, int isb) {
    return isb ? __bfloat162float(((const bf16*)p)[i])
               : ((const float*)p)[i];
}
__device__ __forceinline__ float b2f(unsigned u16) {
    union { unsigned v; float f; } x; x.v = u16 << 16; return x.f;
}
__device__ __forceinline__ unsigned f2b(float f) {
    bf16 h = __float2bfloat16(f);
    union { bf16 h; unsigned short u; } x; x.h = h; return (unsigned)x.u;
}
__device__ __forceinline__ void storef(void* p, size_t i, int asb, float v) {
    if (asb) ((unsigned short*)p)[i] = (unsigned short)f2b(v);
    else     ((float*)p)[i] = v;
}
// Packed pair: low 16 bits = col (max 20000 < 65536), high 16 = bf16 val.
__device__ __forceinline__ unsigned pack_pair(int col, float v) {
    return (f2b(v) << 16) | (unsigned)col;
}

// Per-edge (slot,col,val) lookup for the concatenated edge space.
__device__ __forceinline__ void edge_decode(
        int i,
        const int* __restrict__ r11, const int* __restrict__ c11, const void* __restrict__ v11,
        const int* __restrict__ r22, const int* __restrict__ c22, const void* __restrict__ v22,
        const int* __restrict__ r33, const int* __restrict__ c33, const void* __restrict__ v33,
        const int* __restrict__ r01, const int* __restrict__ c01, const void* __restrict__ v01,
        const int* __restrict__ r02, const int* __restrict__ c02, const void* __restrict__ v02,
        const int* __restrict__ r03, const int* __restrict__ c03, const void* __restrict__ v03,
        int isb, int& slot, int& col, float& val) {
    if      (i < EOFF22) { int k = i;          slot = ROFF11 + r11[k]; col = c11[k]; val = loadf(v11, k, isb); }
    else if (i < EOFF33) { int k = i - EOFF22; slot = ROFF22 + r22[k]; col = c22[k]; val = loadf(v22, k, isb); }
    else if (i < EOFF01) { int k = i - EOFF33; slot = ROFF33 + r33[k]; col = c33[k]; val = loadf(v33, k, isb); }
    else if (i < EOFF02) { int k = i - EOFF01; slot = ROFF01 + r01[k]; col = c01[k]; val = loadf(v01, k, isb); }
    else if (i < EOFF03) { int k = i - EOFF02; slot = ROFF02 + r02[k]; col = c02[k]; val = loadf(v02, k, isb); }
    else                 { int k = i - EOFF03; slot = ROFF03 + r03[k]; col = c03[k]; val = loadf(v03, k, isb); }
}
__device__ __forceinline__ int edge_slot(
        int i,
        const int* __restrict__ r11, const int* __restrict__ r22, const int* __restrict__ r33,
        const int* __restrict__ r01, const int* __restrict__ r02, const int* __restrict__ r03) {
    if      (i < EOFF22) return ROFF11 + r11[i];
    else if (i < EOFF33) return ROFF22 + r22[i - EOFF22];
    else if (i < EOFF01) return ROFF33 + r33[i - EOFF33];
    else if (i < EOFF02) return ROFF01 + r01[i - EOFF01];
    else if (i < EOFF03) return ROFF02 + r02[i - EOFF02];
    else                 return ROFF03 + r03[i - EOFF03];
}

// Detect input dtype from a randn fp32-or-bf16 buffer (see R2 notes).
__global__ void detect_kernel(const unsigned* __restrict__ probe, int* __restrict__ flag) {
    __shared__ int cnt;
    if (threadIdx.x == 0) cnt = 0;
    __syncthreads();
    int insane = 0;
    for (int i = threadIdx.x; i < 1024; i += 256) {
        float x = __uint_as_float(probe[i]);
        float a = fabsf(x);
        if (!(a > 1e-10f && a < 1e10f)) insane++;
    }
    atomicAdd(&cnt, insane);
    __syncthreads();
    if (threadIdx.x == 0) *flag = (cnt > 512) ? 1 : 0;
}

// ======================= multi-block exclusive scan =======================
__global__ __launch_bounds__(1024) void scan_part(const int* __restrict__ cnt,
                                                  int* __restrict__ G,
                                                  int* __restrict__ bsum, int n) {
    __shared__ int wsum[16];
    int b = blockIdx.x, t = threadIdx.x;
    int lane = t & 63, w = t >> 6;
    int i = b * 1024 + t;
    int x = (i < n) ? cnt[i] : 0;
    int s = x;
    #pragma unroll
    for (int off = 1; off < 64; off <<= 1) {
        int y = __shfl_up(s, off);
        if (lane >= off) s += y;
    }
    if (lane == 63) wsum[w] = s;
    __syncthreads();
    if (w == 0) {
        int v = (lane < 16) ? wsum[lane] : 0;
        #pragma unroll
        for (int off = 1; off < 16; off <<= 1) {
            int y = __shfl_up(v, off);
            if (lane >= off) v += y;
        }
        if (lane < 16) wsum[lane] = v;
    }
    __syncthreads();
    int woff = (w > 0) ? wsum[w - 1] : 0;
    if (i < n) G[i] = woff + s - x;
    if (t == 1023) bsum[b] = woff + s;
}

__global__ void scan_tops(const int* __restrict__ bsum, int* __restrict__ boff,
                          int nb, int* __restrict__ G, int n) {
    int t = threadIdx.x;
    int x = (t < nb) ? bsum[t] : 0;
    int s = x;
    #pragma unroll
    for (int off = 1; off < 64; off <<= 1) {
        int y = __shfl_up(s, off);
        if (t >= off) s += y;
    }
    if (t < nb) boff[t] = s - x;
    if (t == 63) G[n] = s;
}

__global__ void scan_fix(int* __restrict__ G, const int* __restrict__ boff,
                         int* __restrict__ cur, int n) {
    int i = blockIdx.x * 256 + threadIdx.x;
    if (i < n) {
        int v = G[i] + boff[i >> 10];
        G[i] = v;
        cur[i] = v;
    }
}

// ======================= fused 6-matrix CSR build (BIG path) =======================
// 4 edges per thread -> 4 independent atomic/store chains (MLP).
#define EPT 4
__global__ void hist_all(const int* __restrict__ r11, const int* __restrict__ r22,
                         const int* __restrict__ r33, const int* __restrict__ r01,
                         const int* __restrict__ r02, const int* __restrict__ r03,
                         int* __restrict__ cnt) {
    int base = (blockIdx.x * blockDim.x + threadIdx.x) * EPT;
    #pragma unroll
    for (int k = 0; k < EPT; ++k) {
        int i = base + k;
        if (i < NEDGES)
            atomicAdd(cnt + edge_slot(i, r11, r22, r33, r01, r02, r03), 1);
    }
}

__global__ void scatter_all(const int* __restrict__ r11, const int* __restrict__ c11, const void* __restrict__ v11,
                            const int* __restrict__ r22, const int* __restrict__ c22, const void* __restrict__ v22,
                            const int* __restrict__ r33, const int* __restrict__ c33, const void* __restrict__ v33,
                            const int* __restrict__ r01, const int* __restrict__ c01, const void* __restrict__ v01,
                            const int* __restrict__ r02, const int* __restrict__ c02, const void* __restrict__ v02,
                            const int* __restrict__ r03, const int* __restrict__ c03, const void* __restrict__ v03,
                            int* __restrict__ cur, unsigned* __restrict__ pairs,
                            const int* __restrict__ dflag) {
    int isb = *dflag;
    int base = (blockIdx.x * blockDim.x + threadIdx.x) * EPT;
    int slot[EPT], col[EPT]; float val[EPT]; int p[EPT];
    #pragma unroll
    for (int k = 0; k < EPT; ++k) {
        int i = base + k;
        if (i < NEDGES)
            edge_decode(i, r11, c11, v11, r22, c22, v22, r33, c33, v33,
                        r01, c01, v01, r02, c02, v02, r03, c03, v03,
                        isb, slot[k], col[k], val[k]);
    }
    #pragma unroll
    for (int k = 0; k < EPT; ++k) {
        int i = base + k;
        if (i < NEDGES) p[k] = atomicAdd(cur + slot[k], 1);
    }
    #pragma unroll
    for (int k = 0; k < EPT; ++k) {
        int i = base + k;
        if (i < NEDGES) pairs[p[k]] = pack_pair(col[k], val[k]);
    }
}

// ======================= fused 2-matrix CSR build (mid path) =======================
__global__ void hist2_kernel(const int* __restrict__ rowsA, int nEA,
                             const int* __restrict__ rowsB, int nEB,
                             int nA, int* __restrict__ cnt) {
    int i = blockIdx.x * blockDim.x + threadIdx.x;
    if (i < nEA) atomicAdd(cnt + rowsA[i], 1);
    else if (i < nEA + nEB) atomicAdd(cnt + nA + rowsB[i - nEA], 1);
}

__device__ void scan_ex(const int* __restrict__ cnt, int* __restrict__ rp, int n) {
    __shared__ int wsum[16];
    __shared__ int carry;
    int t = threadIdx.x, lane = t & 63, w = t >> 6;
    if (t == 0) carry = 0;
    __syncthreads();
    for (int base = 0; base < n; base += 1024) {
        int i = base + t;
        int x = (i < n) ? cnt[i] : 0;
        int s = x;
        #pragma unroll
        for (int off = 1; off < 64; off <<= 1) {
            int y = __shfl_up(s, off);
            if (lane >= off) s += y;
        }
        if (lane == 63) wsum[w] = s;
        __syncthreads();
        if (w == 0) {
            int v = (lane < 16) ? wsum[lane] : 0;
            #pragma unroll
            for (int off = 1; off < 16; off <<= 1) {
                int y = __shfl_up(v, off);
                if (lane >= off) v += y;
            }
            if (lane < 16) wsum[lane] = v;
        }
        __syncthreads();
        int woff = (w > 0) ? wsum[w - 1] : 0;
        if (i < n) rp[i] = carry + woff + s - x;
        __syncthreads();
        if (t == 0) carry += wsum[15];
        __syncthreads();
    }
    if (t == 0) rp[n] = carry;
}

__global__ __launch_bounds__(1024) void scan2_kernel(
        const int* __restrict__ cntA, int* __restrict__ rpA, int nA,
        const int* __restrict__ cntB, int* __restrict__ rpB, int nB) {
    scan_ex(cntA, rpA, nA);
    __syncthreads();
    scan_ex(cntB, rpB, nB);
}

__global__ void copy2_kernel(const int* __restrict__ rpA, const int* __restrict__ rpB,
                             int nA, int nB, int* __restrict__ cur) {
    int i = blockIdx.x * blockDim.x + threadIdx.x;
    if (i < nA) cur[i] = rpA[i];
    else if (i < nA + nB) cur[i] = rpB[i - nA];
}

__global__ void scatter2_kernel(const int* __restrict__ rowsA, const int* __restrict__ colsA,
                                const void* __restrict__ valsA, int nEA,
                                const int* __restrict__ rowsB, const int* __restrict__ colsB,
                                const void* __restrict__ valsB, int nEB,
                                int nA, int* __restrict__ cur,
                                unsigned* __restrict__ pairsA, unsigned* __restrict__ pairsB,
                                const int* __restrict__ dflag) {
    int i = blockIdx.x * blockDim.x + threadIdx.x;
    int isb = *dflag;
    if (i < nEA) {
        int p = atomicAdd(cur + rowsA[i], 1);
        pairsA[p] = pack_pair(colsA[i], loadf(valsA, i, isb));
    } else if (i < nEA + nEB) {
        int k = i - nEA;
        int p = atomicAdd(cur + nA + rowsB[k], 1);
        pairsB[p] = pack_pair(colsB[k], loadf(valsB, k, isb));
    }
}

// ======================= gather bodies (8-edge unroll, packed pairs) ===============
template<bool RELU>
__device__ __forceinline__ void gather_accum8(
        const int* __restrict__ rp, const unsigned* __restrict__ pairs,
        const void* __restrict__ src, int sisb, int row, int lane,
        float& tx, float& ty) {
    int e0 = rp[row], e1 = rp[row + 1];
    float accx[8], accy[8];
    #pragma unroll
    for (int k = 0; k < 8; ++k) { accx[k] = 0.f; accy[k] = 0.f; }
    int e = e0;
    if (sisb) {
        const bf16* sb = (const bf16*)src;
        for (; e + 8 <= e1; e += 8) {
            unsigned p[8], u[8];
            #pragma unroll
            for (int k = 0; k < 8; ++k) p[k] = pairs[e + k];
            #pragma unroll
            for (int k = 0; k < 8; ++k)
                u[k] = ((const unsigned*)(sb + (size_t)(p[k] & 0xffffu) * 128))[lane];
            #pragma unroll
            for (int k = 0; k < 8; ++k) {
                float v = b2f(p[k] >> 16);
                float x0 = b2f(u[k] & 0xffffu), x1 = b2f(u[k] >> 16);
                if (RELU) { x0 = fmaxf(x0, 0.f); x1 = fmaxf(x1, 0.f); }
                accx[k] = fmaf(v, x0, accx[k]);
                accy[k] = fmaf(v, x1, accy[k]);
            }
        }
        for (; e + 2 <= e1; e += 2) {
            unsigned p0 = pairs[e], p1 = pairs[e + 1];
            unsigned u0 = ((const unsigned*)(sb + (size_t)(p0 & 0xffffu) * 128))[lane];
            unsigned u1 = ((const unsigned*)(sb + (size_t)(p1 & 0xffffu) * 128))[lane];
            float v0 = b2f(p0 >> 16), v1 = b2f(p1 >> 16);
            float x0 = b2f(u0 & 0xffffu), x1 = b2f(u0 >> 16);
            float y0 = b2f(u1 & 0xffffu), y1 = b2f(u1 >> 16);
            if (RELU) {
                x0 = fmaxf(x0, 0.f); x1 = fmaxf(x1, 0.f);
                y0 = fmaxf(y0, 0.f); y1 = fmaxf(y1, 0.f);
            }
            accx[0] = fmaf(v0, x0, accx[0]); accy[0] = fmaf(v0, x1, accy[0]);
            accx[1] = fmaf(v1, y0, accx[1]); accy[1] = fmaf(v1, y1, accy[1]);
        }
        if (e < e1) {
            unsigned p = pairs[e];
            float v = b2f(p >> 16);
            unsigned u = ((const unsigned*)(sb + (size_t)(p & 0xffffu) * 128))[lane];
            float x0 = b2f(u & 0xffffu), x1 = b2f(u >> 16);
            if (RELU) { x0 = fmaxf(x0, 0.f); x1 = fmaxf(x1, 0.f); }
            accx[0] = fmaf(v, x0, accx[0]); accy[0] = fmaf(v, x1, accy[0]);
        }
    } else {
        const float* sf = (const float*)src;
        for (; e + 8 <= e1; e += 8) {
            unsigned p[8]; float2 u[8];
            #pragma unroll
            for (int k = 0; k < 8; ++k) p[k] = pairs[e + k];
            #pragma unroll
            for (int k = 0; k < 8; ++k)
                u[k] = ((const float2*)(sf + (size_t)(p[k] & 0xffffu) * 128))[lane];
            #pragma unroll
            for (int k = 0; k < 8; ++k) {
                float v = b2f(p[k] >> 16);
                float x0 = u[k].x, x1 = u[k].y;
                if (RELU) { x0 = fmaxf(x0, 0.f); x1 = fmaxf(x1, 0.f); }
                accx[k] = fmaf(v, x0, accx[k]);
                accy[k] = fmaf(v, x1, accy[k]);
            }
        }
        for (; e + 2 <= e1; e += 2) {
            unsigned p0 = pairs[e], p1 = pairs[e + 1];
            float2 x = ((const float2*)(sf + (size_t)(p0 & 0xffffu) * 128))[lane];
            float2 y = ((const float2*)(sf + (size_t)(p1 & 0xffffu) * 128))[lane];
            float v0 = b2f(p0 >> 16), v1 = b2f(p1 >> 16);
            if (RELU) {
                x.x = fmaxf(x.x, 0.f); x.y = fmaxf(x.y, 0.f);
                y.x = fmaxf(y.x, 0.f); y.y = fmaxf(y.y, 0.f);
            }
            accx[0] = fmaf(v0, x.x, accx[0]); accy[0] = fmaf(v0, x.y, accy[0]);
            accx[1] = fmaf(v1, y.x, accx[1]); accy[1] = fmaf(v1, y.y, accy[1]);
        }
        if (e < e1) {
            unsigned p = pairs[e];
            float v = b2f(p >> 16);
            float2 x = ((const float2*)(sf + (size_t)(p & 0xffffu) * 128))[lane];
            if (RELU) { x.x = fmaxf(x.x, 0.f); x.y = fmaxf(x.y, 0.f); }
            accx[0] = fmaf(v, x.x, accx[0]); accy[0] = fmaf(v, x.y, accy[0]);
        }
    }
    tx = ((accx[0] + accx[1]) + (accx[2] + accx[3])) + ((accx[4] + accx[5]) + (accx[6] + accx[7]));
    ty = ((accy[0] + accy[1]) + (accy[2] + accy[3])) + ((accy[4] + accy[5]) + (accy[6] + accy[7]));
}

template<bool RELU>
__device__ __forceinline__ void gather128_body(
        const int* __restrict__ rp, const unsigned* __restrict__ pairs,
        const void* __restrict__ src, int sisb,
        void* __restrict__ dst, int disb, int row, int lane) {
    float tx, ty;
    gather_accum8<RELU>(rp, pairs, src, sisb, row, lane, tx, ty);
    if (disb) {
        ((unsigned*)((bf16*)dst + (size_t)row * 128))[lane] = f2b(tx) | (f2b(ty) << 16);
    } else {
        ((float2*)((float*)dst + (size_t)row * 128))[lane] = make_float2(tx, ty);
    }
}

template<bool RELU>
__device__ __forceinline__ void norm128_body(
        const int* __restrict__ rp, const unsigned* __restrict__ pairs,
        const void* __restrict__ src, int sisb,
        void* __restrict__ out, size_t elem_off, int row, int lane, int isb) {
    float tx, ty;
    gather_accum8<RELU>(rp, pairs, src, sisb, row, lane, tx, ty);
    float ss = tx * tx + ty * ty;
    #pragma unroll
    for (int off = 32; off > 0; off >>= 1) ss += __shfl_down(ss, off);
    ss = __shfl(ss, 0);
    float inv = 1.0f / (sqrtf(ss) + 1e-9f);
    size_t base = elem_off + (size_t)row * 128;
    if (isb) {
        ((unsigned*)((bf16*)out + base))[lane] = f2b(tx * inv) | (f2b(ty * inv) << 16);
    } else {
        ((float2*)((float*)out + base))[lane] = make_float2(tx * inv, ty * inv);
    }
}

__device__ __forceinline__ void norm428_body(
        const int* __restrict__ rp, const unsigned* __restrict__ pairs,
        const void* __restrict__ src1, int s1b,
        const void* __restrict__ src2, int s2b,
        void* __restrict__ out, size_t elem_off, int row, int lane, int isb) {
    constexpr int P2 = D_WEMB / 2;   // 150
    int e0 = rp[row], e1 = rp[row + 1];
    float2 a1 = make_float2(0.f, 0.f), b1 = make_float2(0.f, 0.f);
    float2 a2[3], b2v[3];
    #pragma unroll
    for (int s = 0; s < 3; ++s) { a2[s] = make_float2(0.f, 0.f); b2v[s] = make_float2(0.f, 0.f); }
    int e = e0;
    for (; e + 2 <= e1; e += 2) {
        unsigned pp0 = pairs[e], pp1 = pairs[e + 1];
        int c0 = pp0 & 0xffffu, c1 = pp1 & 0xffffu;
        float v0 = b2f(pp0 >> 16), v1 = b2f(pp1 >> 16);
        float x0, x1, y0, y1;
        if (s1b) {
            unsigned u0 = ((const unsigned*)((const bf16*)src1 + (size_t)c0 * DD))[lane];
            unsigned u1 = ((const unsigned*)((const bf16*)src1 + (size_t)c1 * DD))[lane];
            x0 = b2f(u0 & 0xffffu); x1 = b2f(u0 >> 16);
            y0 = b2f(u1 & 0xffffu); y1 = b2f(u1 >> 16);
        } else {
            float2 x = ((const float2*)((const float*)src1 + (size_t)c0 * DD))[lane];
            float2 y = ((const float2*)((const float*)src1 + (size_t)c1 * DD))[lane];
            x0 = x.x; x1 = x.y; y0 = y.x; y1 = y.y;
        }
        x0 = fmaxf(x0, 0.f); x1 = fmaxf(x1, 0.f);
        y0 = fmaxf(y0, 0.f); y1 = fmaxf(y1, 0.f);
        a1.x = fmaf(v0, x0, a1.x); a1.y = fmaf(v0, x1, a1.y);
        b1.x = fmaf(v1, y0, b1.x); b1.y = fmaf(v1, y1, b1.y);
        if (s2b) {
            const unsigned* s0p = (const unsigned*)((const bf16*)src2 + (size_t)c0 * D_WEMB);
            const unsigned* s1p = (const unsigned*)((const bf16*)src2 + (size_t)c1 * D_WEMB);
            #pragma unroll
            for (int s = 0; s < 3; ++s) {
                int pi = lane + 64 * s;
                if (pi < P2) {
                    unsigned u0 = s0p[pi], u1 = s1p[pi];
                    a2[s].x  = fmaf(v0, b2f(u0 & 0xffffu), a2[s].x);
                    a2[s].y  = fmaf(v0, b2f(u0 >> 16),     a2[s].y);
                    b2v[s].x = fmaf(v1, b2f(u1 & 0xffffu), b2v[s].x);
                    b2v[s].y = fmaf(v1, b2f(u1 >> 16),     b2v[s].y);
                }
            }
        } else {
            const float2* s0p = (const float2*)((const float*)src2 + (size_t)c0 * D_WEMB);
            const float2* s1p = (const float2*)((const float*)src2 + (size_t)c1 * D_WEMB);
            #pragma unroll
            for (int s = 0; s < 3; ++s) {
                int pi = lane + 64 * s;
                if (pi < P2) {
                    float2 x = s0p[pi], y = s1p[pi];
                    a2[s].x  = fmaf(v0, x.x, a2[s].x);
                    a2[s].y  = fmaf(v0, x.y, a2[s].y);
                    b2v[s].x = fmaf(v1, y.x, b2v[s].x);
                    b2v[s].y = fmaf(v1, y.y, b2v[s].y);
                }
            }
        }
    }
    if (e < e1) {
        unsigned pp = pairs[e];
        int c = pp & 0xffffu;
        float v = b2f(pp >> 16);
        float x0, x1;
        if (s1b) {
            unsigned u = ((const unsigned*)((const bf16*)src1 + (size_t)c * DD))[lane];
            x0 = b2f(u & 0xffffu); x1 = b2f(u >> 16);
        } else {
            float2 x = ((const float2*)((const float*)src1 + (size_t)c * DD))[lane];
            x0 = x.x; x1 = x.y;
        }
        x0 = fmaxf(x0, 0.f); x1 = fmaxf(x1, 0.f);
        a1.x = fmaf(v, x0, a1.x); a1.y = fmaf(v, x1, a1.y);
        if (s2b) {
            const unsigned* sp = (const unsigned*)((const bf16*)src2 + (size_t)c * D_WEMB);
            #pragma unroll
            for (int s = 0; s < 3; ++s) {
                int pi = lane + 64 * s;
                if (pi < P2) {
                    unsigned u = sp[pi];
                    a2[s].x = fmaf(v, b2f(u & 0xffffu), a2[s].x);
                    a2[s].y = fmaf(v, b2f(u >> 16),     a2[s].y);
                }
            }
        } else {
            const float2* sp = (const float2*)((const float*)src2 + (size_t)c * D_WEMB);
            #pragma unroll
            for (int s = 0; s < 3; ++s) {
                int pi = lane + 64 * s;
                if (pi < P2) {
                    float2 x = sp[pi];
                    a2[s].x = fmaf(v, x.x, a2[s].x);
                    a2[s].y = fmaf(v, x.y, a2[s].y);
                }
            }
        }
    }
    float t1x = a1.x + b1.x, t1y = a1.y + b1.y;
    float t2x[3], t2y[3];
    #pragma unroll
    for (int s = 0; s < 3; ++s) { t2x[s] = a2[s].x + b2v[s].x; t2y[s] = a2[s].y + b2v[s].y; }
    float ss = t1x * t1x + t1y * t1y;
    #pragma unroll
    for (int s = 0; s < 3; ++s) {
        int pi = lane + 64 * s;
        if (pi < P2) ss += t2x[s] * t2x[s] + t2y[s] * t2y[s];
    }
    #pragma unroll
    for (int off = 32; off > 0; off >>= 1) ss += __shfl_down(ss, off);
    ss = __shfl(ss, 0);
    float inv = 1.0f / (sqrtf(ss) + 1e-9f);
    size_t base = elem_off + (size_t)row * (DD + D_WEMB);
    if (isb) {
        ((unsigned*)((bf16*)out + base))[lane] = f2b(t1x * inv) | (f2b(t1y * inv) << 16);
        unsigned* o2 = (unsigned*)((bf16*)out + base + DD);
        #pragma unroll
        for (int s = 0; s < 3; ++s) {
            int pi = lane + 64 * s;
            if (pi < P2) o2[pi] = f2b(t2x[s] * inv) | (f2b(t2y[s] * inv) << 16);
        }
    } else {
        ((float2*)((float*)out + base))[lane] = make_float2(t1x * inv, t1y * inv);
        float2* o2 = (float2*)((float*)out + base + DD);
        #pragma unroll
        for (int s = 0; s < 3; ++s) {
            int pi = lane + 64 * s;
            if (pi < P2) o2[pi] = make_float2(t2x[s] * inv, t2y[s] * inv);
        }
    }
}

// ======================= gather kernels =======================
template<bool RELU>
__global__ void spmm_gather128(const int* __restrict__ rowptr, const unsigned* __restrict__ pairs,
                               const void* __restrict__ src, int src_flagged,
                               void* __restrict__ dst, int dst_flagged,
                               int n, const int* __restrict__ dflag) {
    int row = blockIdx.x * 4 + (threadIdx.x >> 6);
    if (row >= n) return;
    int isb = *dflag;
    gather128_body<RELU>(rowptr, pairs, src, src_flagged ? isb : 0,
                         dst, dst_flagged ? isb : 0, row, threadIdx.x & 63);
}

template<bool RELU>
__global__ void spmm_gather128_b2(const int* __restrict__ G, const unsigned* __restrict__ pairs,
                                  int roff1, const void* __restrict__ src1, void* __restrict__ dst1, int n1, int B1,
                                  int roff2, const void* __restrict__ src2, void* __restrict__ dst2, int n2,
                                  int src_flagged, int dst_flagged, const int* __restrict__ dflag) {
    int isb = *dflag;
    int sisb = src_flagged ? isb : 0;
    int disb = dst_flagged ? isb : 0;
    int lane = threadIdx.x & 63;
    int b = blockIdx.x;
    if (b < B1) {
        int row = b * 4 + (threadIdx.x >> 6);
        if (row >= n1) return;
        gather128_body<RELU>(G + roff1, pairs, src1, sisb, dst1, disb, row, lane);
    } else {
        int row = (b - B1) * 4 + (threadIdx.x >> 6);
        if (row >= n2) return;
        gather128_body<RELU>(G + roff2, pairs, src2, sisb, dst2, disb, row, lane);
    }
}

template<bool RELU>
__global__ void spmm_norm128(const int* __restrict__ rowptr, const unsigned* __restrict__ pairs,
                             const void* __restrict__ src, int src_flagged,
                             void* __restrict__ out, size_t elem_off,
                             int n, const int* __restrict__ dflag) {
    int row = blockIdx.x * 4 + (threadIdx.x >> 6);
    if (row >= n) return;
    int isb = *dflag;
    norm128_body<RELU>(rowptr, pairs, src, src_flagged ? isb : 0, out, elem_off,
                       row, threadIdx.x & 63, isb);
}

__global__ void spmm2_norm(const int* __restrict__ rowptr, const unsigned* __restrict__ pairs,
                           const void* __restrict__ src1, int s1_flagged,
                           const void* __restrict__ src2, int s2_flagged,
                           void* __restrict__ out, size_t elem_off,
                           int n, const int* __restrict__ dflag) {
    int row = blockIdx.x * 4 + (threadIdx.x >> 6);
    if (row >= n) return;
    int isb = *dflag;
    norm428_body(rowptr, pairs, src1, s1_flagged ? isb : 0, src2, s2_flagged ? isb : 0,
                 out, elem_off, row, threadIdx.x & 63, isb);
}

// BIG path: all 3 output norms in ONE launch.
__global__ void final_norm_all(const int* __restrict__ G, const unsigned* __restrict__ pairs,
                               const void* __restrict__ s1, const void* __restrict__ e0b,
                               const void* __restrict__ wemb, const void* __restrict__ p3b,
                               void* __restrict__ out,
                               size_t off1, size_t off2, size_t off3,
                               const int* __restrict__ dflag) {
    int isb = *dflag;
    int lane = threadIdx.x & 63;
    int b = blockIdx.x;
    if (b < 2500) {
        int row = b * 4 + (threadIdx.x >> 6);
        if (row >= N_DOC) return;
        norm128_body<true>(G + ROFF01, pairs, s1, isb, out, off1, row, lane, isb);
    } else if (b < 5000) {
        int row = (b - 2500) * 4 + (threadIdx.x >> 6);
        if (row >= N_DOC) return;
        norm428_body(G + ROFF02, pairs, e0b, isb, wemb, isb, out, off2, row, lane, isb);
    } else {
        int row = (b - 5000) * 4 + (threadIdx.x >> 6);
        if (row >= N_DOC) return;
        norm128_body<true>(G + ROFF03, pairs, p3b, isb, out, off3, row, lane, isb);
    }
}

// ======================= atomic SpMM (deep fallback) =======================
template<bool RELU>
__global__ void spmm_kernel(const int* __restrict__ rows, const int* __restrict__ cols,
                            const void* __restrict__ vals,
                            const void* __restrict__ src, int sstride, int src_flagged,
                            float* __restrict__ dst, int dstride, int doff,
                            int d, int nE, const int* __restrict__ dflag) {
    int e = blockIdx.x * (blockDim.x >> 6) + (threadIdx.x >> 6);
    if (e >= nE) return;
    int isb  = *dflag;
    int sisb = src_flagged ? isb : 0;
    int lane = threadIdx.x & 63;
    int r = rows[e];
    int c = cols[e];
    float v = loadf(vals, e, isb);
    size_t sbase = (size_t)c * sstride;
    float* dp = dst + (size_t)r * dstride + doff;
    if (sisb) {
        const unsigned* sp = (const unsigned*)((const bf16*)src + sbase);
        for (int j = 2 * lane; j < d; j += 128) {
            unsigned u = sp[j >> 1];
            float x0 = b2f(u & 0xffffu);
            float x1 = b2f(u >> 16);
            if (RELU) { x0 = fmaxf(x0, 0.f); x1 = fmaxf(x1, 0.f); }
            atomicAdd(dp + j,     v * x0);
            atomicAdd(dp + j + 1, v * x1);
        }
    } else {
        const float2* sp = (const float2*)((const float*)src + sbase);
        for (int j = 2 * lane; j < d; j += 128) {
            float2 x = sp[j >> 1];
            if (RELU) { x.x = fmaxf(x.x, 0.f); x.y = fmaxf(x.y, 0.f); }
            atomicAdd(dp + j,     v * x.x);
            atomicAdd(dp + j + 1, v * x.y);
        }
    }
}

// ======================= dense GEMMs =======================
// 64-col tile in 32 KB LDS; packed col-pair stores. X fp32; out/W/b follow isb.
template<bool RELU>
__device__ __forceinline__ void gemm_tile_body(
        const float* __restrict__ X, const void* __restrict__ W,
        const void* __restrict__ b, void* __restrict__ out, int n,
        int bx, int by, int isb, float* Wl /*128*64*/) {
    if (bx * 64 >= n) return;
    int tid = threadIdx.x;
    int jc = by * 64;
    if (isb) {
        const uint2* Wg = (const uint2*)W;
        float4* Wl4 = (float4*)Wl;
        for (int vidx = tid; vidx < 2048; vidx += 256) {
            int k = vidx >> 4, jl4 = vidx & 15;
            uint2 u = Wg[k * 32 + (jc >> 2) + jl4];
            float4 vv;
            vv.x = b2f(u.x & 0xffffu);
            vv.y = b2f(u.x >> 16);
            vv.z = b2f(u.y & 0xffffu);
            vv.w = b2f(u.y >> 16);
            Wl4[vidx] = vv;
        }
    } else {
        const float4* Wg = (const float4*)W;
        float4* Wl4 = (float4*)Wl;
        for (int vidx = tid; vidx < 2048; vidx += 256) {
            int k = vidx >> 4, jl4 = vidx & 15;
            Wl4[vidx] = Wg[k * 32 + (jc >> 2) + jl4];
        }
    }
    __syncthreads();
    int j2 = tid & 31;
    int g  = tid >> 5;
    float bc0 = loadf(b, jc + 2 * j2, isb);
    float bc1 = loadf(b, jc + 2 * j2 + 1, isb);
    int i0 = bx * 64 + g * 8;
    float a0[8], a1[8];
    #pragma unroll
    for (int r = 0; r < 8; ++r) { a0[r] = bc0; a1[r] = bc1; }
    const float4* xp = (const float4*)(X + (size_t)i0 * 128);
    const float2* Wl2 = (const float2*)Wl;
    #pragma unroll 2
    for (int k4 = 0; k4 < 32; ++k4) {
        float2 w0 = Wl2[(4 * k4 + 0) * 32 + j2];
        float2 w1 = Wl2[(4 * k4 + 1) * 32 + j2];
        float2 w2 = Wl2[(4 * k4 + 2) * 32 + j2];
        float2 w3 = Wl2[(4 * k4 + 3) * 32 + j2];
        #pragma unroll
        for (int r = 0; r < 8; ++r) {
            float4 v = xp[r * 32 + k4];
            if (RELU) {
                v.x = fmaxf(v.x, 0.f); v.y = fmaxf(v.y, 0.f);
                v.z = fmaxf(v.z, 0.f); v.w = fmaxf(v.w, 0.f);
            }
            a0[r] = fmaf(v.w, w3.x, fmaf(v.z, w2.x, fmaf(v.y, w1.x, fmaf(v.x, w0.x, a0[r]))));
            a1[r] = fmaf(v.w, w3.y, fmaf(v.z, w2.y, fmaf(v.y, w1.y, fmaf(v.x, w0.y, a1[r]))));
        }
    }
    #pragma unroll
    for (int r = 0; r < 8; ++r) {
        int i = i0 + r;
        if (i < n) {
            if (isb) {
                ((unsigned*)((bf16*)out + (size_t)i * 128 + jc))[j2] =
                    f2b(a0[r]) | (f2b(a1[r]) << 16);
            } else {
                ((float2*)((float*)out + (size_t)i * 128 + jc))[j2] =
                    make_float2(a0[r], a1[r]);
            }
        }
    }
}

template<bool RELU>
__global__ __launch_bounds__(256) void gemm_tile(
        const float* __restrict__ X, const void* __restrict__ W,
        const void* __restrict__ b, void* __restrict__ out, int n,
        const int* __restrict__ dflag) {
    __shared__ float Wl[128 * 64];
    gemm_tile_body<RELU>(X, W, b, out, n, blockIdx.x, blockIdx.y, *dflag, Wl);
}

template<bool RELU>
__global__ __launch_bounds__(256) void gemm_tile_b2(
        const float* __restrict__ X1, const void* __restrict__ W1, const void* __restrict__ b1,
        void* __restrict__ out1, int n1, int G1,
        const float* __restrict__ X2, const void* __restrict__ W2, const void* __restrict__ b2,
        void* __restrict__ out2, int n2,
        const int* __restrict__ dflag) {
    __shared__ float Wl[128 * 64];
    int isb = *dflag;
    if ((int)blockIdx.x < G1)
        gemm_tile_body<RELU>(X1, W1, b1, out1, n1, blockIdx.x, blockIdx.y, isb, Wl);
    else
        gemm_tile_body<RELU>(X2, W2, b2, out2, n2, blockIdx.x - G1, blockIdx.y, isb, Wl);
}

// Legacy big-LDS GEMM (deep fallback only; fp32 ws).
template<bool RELU>
__global__ __launch_bounds__(256) void gemm128_kernel(
        const float* __restrict__ X, const void* __restrict__ W,
        const void* __restrict__ b, float* __restrict__ out, int n,
        const int* __restrict__ dflag) {
    __shared__ float Wl[128 * 128];
    int isb = *dflag;
    int tid = threadIdx.x;
    if (isb) {
        const uint2* Wg = (const uint2*)W;
        float4* Wl4 = (float4*)Wl;
        for (int idx = tid; idx < 4096; idx += 256) {
            uint2 u = Wg[idx];
            float4 vv;
            vv.x = b2f(u.x & 0xffffu);
            vv.y = b2f(u.x >> 16);
            vv.z = b2f(u.y & 0xffffu);
            vv.w = b2f(u.y >> 16);
            Wl4[idx] = vv;
        }
    } else {
        const float4* Wg = (const float4*)W;
        float4* Wl4 = (float4*)Wl;
        for (int idx = tid; idx < 4096; idx += 256) Wl4[idx] = Wg[idx];
    }
    __syncthreads();
    int j = tid & 127;
    int h = tid >> 7;
    float bj = loadf(b, j, isb);
    int row0 = blockIdx.x * 64 + h * 32;
    for (int q = 0; q < 8; ++q) {
        int gi = row0 + q * 4;
        if (gi >= n) break;
        const float4* x0 = (const float4*)(X + (size_t)gi * 128);
        const float4* x1 = x0 + 32;
        const float4* x2 = x1 + 32;
        const float4* x3 = x2 + 32;
        float a0 = bj, a1 = bj, a2 = bj, a3 = bj;
        #pragma unroll 4
        for (int k4 = 0; k4 < 32; ++k4) {
            float4 v0 = x0[k4], v1 = x1[k4], v2 = x2[k4], v3 = x3[k4];
            if (RELU) {
                v0.x = fmaxf(v0.x, 0.f); v0.y = fmaxf(v0.y, 0.f); v0.z = fmaxf(v0.z, 0.f); v0.w = fmaxf(v0.w, 0.f);
                v1.x = fmaxf(v1.x, 0.f); v1.y = fmaxf(v1.y, 0.f); v1.z = fmaxf(v1.z, 0.f); v1.w = fmaxf(v1.w, 0.f);
                v2.x = fmaxf(v2.x, 0.f); v2.y = fmaxf(v2.y, 0.f); v2.z = fmaxf(v2.z, 0.f); v2.w = fmaxf(v2.w, 0.f);
                v3.x = fmaxf(v3.x, 0.f); v3.y = fmaxf(v3.y, 0.f); v3.z = fmaxf(v3.z, 0.f); v3.w = fmaxf(v3.w, 0.f);
            }
            float w0 = Wl[(4 * k4 + 0) * 128 + j];
            float w1 = Wl[(4 * k4 + 1) * 128 + j];
            float w2 = Wl[(4 * k4 + 2) * 128 + j];
            float w3 = Wl[(4 * k4 + 3) * 128 + j];
            a0 = fmaf(v0.w, w3, fmaf(v0.z, w2, fmaf(v0.y, w1, fmaf(v0.x, w0, a0))));
            a1 = fmaf(v1.w, w3, fmaf(v1.z, w2, fmaf(v1.y, w1, fmaf(v1.x, w0, a1))));
            a2 = fmaf(v2.w, w3, fmaf(v2.z, w2, fmaf(v2.y, w1, fmaf(v2.x, w0, a2))));
            a3 = fmaf(v3.w, w3, fmaf(v3.z, w2, fmaf(v3.y, w1, fmaf(v3.x, w0, a3))));
        }
        float* o = out + (size_t)gi * 128 + j;
        o[0] = a0; o[128] = a1; o[256] = a2; o[384] = a3;
    }
}

// Row-parallel tiny GEMM (type-3, n=60): one block per row, 128 threads.
template<bool RELU, int K>
__global__ void rowpar_gemm(const void* __restrict__ X, int x_flagged,
                            const void* __restrict__ W, const void* __restrict__ b,
                            void* __restrict__ out, int out_flagged,
                            const int* __restrict__ dflag) {
    __shared__ float xr[K];
    int isb  = *dflag;
    int xisb = x_flagged ? isb : 0;
    int oisb = out_flagged ? isb : 0;
    int row = blockIdx.x;
    int j = threadIdx.x;
    if (j < K) {
        float x = loadf(X, (size_t)row * K + j, xisb);
        if (RELU) x = fmaxf(x, 0.f);
        xr[j] = x;
    }
    __syncthreads();
    float acc = loadf(b, j, isb);
    #pragma unroll 8
    for (int k = 0; k < K; ++k)
        acc = fmaf(xr[k], loadf(W, (size_t)k * 128 + j, isb), acc);
    storef(out, (size_t)row * 128 + j, oisb, acc);
}

// Generic small GEMM (deep fallback only).
template<bool RELU, int K>
__global__ void gemm_kernel(const void* __restrict__ X, int x_flagged,
                            const void* __restrict__ W,
                            const void* __restrict__ b,
                            float* __restrict__ out, int n,
                            const int* __restrict__ dflag) {
    __shared__ float Wl[K * 128];
    int isb  = *dflag;
    int xisb = x_flagged ? isb : 0;
    int j = threadIdx.x;
    for (int idx = j; idx < K * 128; idx += 128)
        Wl[idx] = loadf(W, idx, isb);
    __syncthreads();
    float bj = loadf(b, j, isb);
    int row0 = blockIdx.x * 64;
    for (int i0 = 0; i0 < 64; i0 += 4) {
        int i = row0 + i0;
        if (i >= n) break;
        size_t r0 = (size_t)i * K;
        float a0 = bj, a1 = bj, a2 = bj, a3 = bj;
        for (int k = 0; k < K; ++k) {
            float w = Wl[k * 128 + j];
            float v0 = loadf(X, r0 + k, xisb);
            float v1 = loadf(X, r0 + K + k, xisb);
            float v2 = loadf(X, r0 + 2 * K + k, xisb);
            float v3 = loadf(X, r0 + 3 * K + k, xisb);
            if (RELU) {
                v0 = fmaxf(v0, 0.f); v1 = fmaxf(v1, 0.f);
                v2 = fmaxf(v2, 0.f); v3 = fmaxf(v3, 0.f);
            }
            a0 = fmaf(v0, w, a0);
            a1 = fmaf(v1, w, a1);
            a2 = fmaf(v2, w, a2);
            a3 = fmaf(v3, w, a3);
        }
        float* o = out + (size_t)i * 128 + j;
        o[0] = a0; o[128] = a1; o[256] = a2; o[384] = a3;
    }
}

// L2-norm (deep fallback only).
__global__ void l2norm_kernel(const float* __restrict__ agg, int d,
                              void* __restrict__ out, size_t elem_off, int n,
                              const int* __restrict__ dflag) {
    int row = blockIdx.x * (blockDim.x >> 6) + (threadIdx.x >> 6);
    if (row >= n) return;
    int isb  = *dflag;
    int lane = threadIdx.x & 63;
    const float2* a2 = (const float2*)(agg + (size_t)row * d);
    float ss = 0.f;
    for (int j = 2 * lane; j < d; j += 128) {
        float2 x = a2[j >> 1];
        ss += x.x * x.x + x.y * x.y;
    }
    #pragma unroll
    for (int off = 32; off > 0; off >>= 1) ss += __shfl_down(ss, off);
    ss = __shfl(ss, 0);
    float inv = 1.0f / (sqrtf(ss) + 1e-9f);
    size_t bbase = elem_off + (size_t)row * d;
    if (isb) {
        unsigned* o = (unsigned*)((bf16*)out + bbase);
        for (int j = 2 * lane; j < d; j += 128) {
            float2 x = a2[j >> 1];
            o[j >> 1] = f2b(x.x * inv) | (f2b(x.y * inv) << 16);
        }
    } else {
        float2* o = (float2*)((float*)out + bbase);
        for (int j = 2 * lane; j < d; j += 128) {
            float2 x = a2[j >> 1];
            o[j >> 1] = make_float2(x.x * inv, x.y * inv);
        }
    }
}

static inline int spmm_grid(int nE) { return (nE + 3) / 4; }
static inline int row_grid(int n)   { return (n + 3) / 4; }
static inline int pad8(int x)       { return (x + 7) & ~7; }

// Mid-path per-phase CSR build (packed pairs).
static void build2(hipStream_t stream,
                   const int* rowsA, const int* colsA, const void* valsA, int nA, int nEA,
                   const int* rowsB, const int* colsB, const void* valsB, int nB, int nEB,
                   int* rpA, int* rpB, int* curAB, unsigned* pairsA, unsigned* pairsB,
                   const int* dflag) {
    int nE = nEA + nEB;
    hipMemsetAsync(curAB, 0, (size_t)(nA + nB) * 4, stream);
    hist2_kernel<<<(nE + 255) / 256, 256, 0, stream>>>(rowsA, nEA, rowsB, nEB, nA, curAB);
    scan2_kernel<<<1, 1024, 0, stream>>>(curAB, rpA, nA, curAB + nA, rpB, nB);
    copy2_kernel<<<(nA + nB + 255) / 256, 256, 0, stream>>>(rpA, rpB, nA, nB, curAB);
    scatter2_kernel<<<(nE + 255) / 256, 256, 0, stream>>>(
        rowsA, colsA, valsA, nEA, rowsB, colsB, valsB, nEB, nA, curAB, pairsA, pairsB, dflag);
}

extern "C" void kernel_launch(void* const* d_in, const int* in_sizes, int n_in,
                              void* d_out, int out_size, void* d_ws, size_t ws_size,
                              hipStream_t stream) {
    const void* f1   = d_in[0];
    const void* f2   = d_in[1];
    const void* f3   = d_in[2];
    const void* wemb = d_in[3];
    const int*  a11r = (const int*)d_in[4];
    const int*  a11c = (const int*)d_in[5];
    const void* a11v = d_in[6];
    const int*  a22r = (const int*)d_in[7];
    const int*  a22c = (const int*)d_in[8];
    const void* a22v = d_in[9];
    const int*  a33r = (const int*)d_in[10];
    const int*  a33c = (const int*)d_in[11];
    const void* a33v = d_in[12];
    const int*  a01r = (const int*)d_in[13];
    const int*  a01c = (const int*)d_in[14];
    const void* a01v = d_in[15];
    const int*  a02r = (const int*)d_in[16];
    const int*  a02c = (const int*)d_in[17];
    const void* a02v = d_in[18];
    const int*  a03r = (const int*)d_in[19];
    const int*  a03c = (const int*)d_in[20];
    const void* a03v = d_in[21];
    const void* W3   = d_in[22];
    const void* b3   = d_in[23];
    const void* W1_2 = d_in[24];
    const void* b1_2 = d_in[25];
    const void* W2_2 = d_in[26];
    const void* b2_2 = d_in[27];
    const void* W3_2 = d_in[28];
    const void* b3_2 = d_in[29];

    int*   dflag = (int*)d_ws;
    float* base  = (float*)d_ws + 16;

    const size_t OUT1_OFF = 0;
    const size_t OUT2_OFF = (size_t)N_DOC * DD;                       // 1,280,000
    const size_t OUT3_OFF = OUT2_OFF + (size_t)N_DOC * (DD + D_WEMB); // 5,560,000

    dim3 blk(256);
    detect_kernel<<<1, 256, 0, stream>>>((const unsigned*)f1, dflag);

    const size_t BF_S0 = 0, BF_S1 = 2560000, BF_E0 = 5120000, BF_E1 = 6400000;
    const size_t BF_P3A = 7680000, BF_P3B = 7687680, BF_INT = 7695360;
    const size_t BIG_INTS = (size_t)(NROWS + 1) + NROWS + 128 + NEDGES + 8; // ~1.15M
    const size_t WS_BIG = 64 + (BF_INT + BIG_INTS) * 4;               // ~35.4 MB
    const size_t WS_MID = 64 + 22240000ull + (60008ull + 620000ull) * 4; // ~25 MB

    if (ws_size >= WS_BIG) {
        // ======================= BIG batched path =======================
        float* S0  = base + BF_S0;
        float* S1  = base + BF_S1;
        float* E0  = base + BF_E0;
        float* E1  = base + BF_E1;
        float* P3a = base + BF_P3A;
        float* P3b = base + BF_P3B;
        int*   G    = (int*)(base + BF_INT);
        int*   cur  = G + (NROWS + 1);
        int*   bsum = cur + NROWS;
        int*   boff = bsum + 64;
        unsigned* pairs = (unsigned*)(boff + 64);

        const int NB = (NROWS + 1023) / 1024;   // 59
        const int NTE = (NEDGES + EPT - 1) / EPT;   // threads for edge kernels
        hipMemsetAsync(cur, 0, (size_t)NROWS * 4, stream);
        hist_all<<<(NTE + 255) / 256, 256, 0, stream>>>(
            a11r, a22r, a33r, a01r, a02r, a03r, cur);
        scan_part<<<NB, 1024, 0, stream>>>(cur, G, bsum, NROWS);
        scan_tops<<<1, 64, 0, stream>>>(bsum, boff, NB, G, NROWS);
        scan_fix<<<(NROWS + 255) / 256, 256, 0, stream>>>(G, boff, cur, NROWS);
        scatter_all<<<(NTE + 255) / 256, 256, 0, stream>>>(
            a11r, a11c, a11v, a22r, a22c, a22v, a33r, a33c, a33v,
            a01r, a01c, a01v, a02r, a02c, a02v, a03r, a03c, a03v,
            cur, pairs, dflag);

        rowpar_gemm<false, 60><<<N_POS, 128, 0, stream>>>(
            f3, 1, W3, b3, P3a, 1, dflag);                              // P3a = f3@W3+b3

        {
            int B1 = row_grid(N_WORD), B2 = row_grid(N_ENT);
            spmm_gather128_b2<false><<<B1 + B2, blk, 0, stream>>>(
                G, pairs, ROFF11, f1, S0, N_WORD, B1,
                ROFF22, f2, E0, N_ENT, 1, 0, dflag);                    // hop1 (fp32 out)
        }
        {
            int G1 = pad8((N_WORD + 63) / 64), G2 = pad8((N_ENT + 63) / 64);
            gemm_tile_b2<true><<<dim3(G1 + G2, 2), 256, 0, stream>>>(
                S0, W1_2, b1_2, S1, N_WORD, G1,
                E0, W2_2, b2_2, E1, N_ENT, dflag);                      // gemm batch
        }
        {
            int B1 = row_grid(N_WORD), B2 = row_grid(N_ENT);
            spmm_gather128_b2<false><<<B1 + B2, blk, 0, stream>>>(
                G, pairs, ROFF11, S1, S0, N_WORD, B1,
                ROFF22, E1, E0, N_ENT, 1, 1, dflag);                    // hop2 (flagged out)
        }
        spmm_gather128<false><<<row_grid(N_POS), blk, 0, stream>>>(
            G + ROFF33, pairs, P3a, 1, P3b, 1, N_POS, dflag);
        rowpar_gemm<true, 128><<<N_POS, 128, 0, stream>>>(
            P3b, 1, W3_2, b3_2, P3a, 1, dflag);
        spmm_gather128<false><<<row_grid(N_POS), blk, 0, stream>>>(
            G + ROFF33, pairs, P3a, 1, P3b, 1, N_POS, dflag);

        final_norm_all<<<7500, blk, 0, stream>>>(
            G, pairs, S0, E0, wemb, P3b, d_out, OUT1_OFF, OUT2_OFF, OUT3_OFF, dflag);
    } else if (ws_size >= WS_MID) {
        // ======================= mid path =======================
        float* S0   = base;
        float* S1   = base + 2560000;
        float* E0   = base;
        float* E1   = base + 1280000;
        float* P3a  = base;
        float* P3b  = base + 7680;
        int* I = (int*)(base + 5560000);
        {
            int* rpA = I; int* rpB = rpA + (N_WORD + 1); int* cur = rpB + (N_DOC + 1);
            unsigned* pA = (unsigned*)(cur + N_WORD + N_DOC); unsigned* pB = pA + E11;
            build2(stream, a11r, a11c, a11v, N_WORD, E11,
                   a01r, a01c, a01v, N_DOC, E01, rpA, rpB, cur, pA, pB, dflag);
            spmm_gather128<false><<<row_grid(N_WORD), blk, 0, stream>>>(
                rpA, pA, f1, 1, S0, 0, N_WORD, dflag);
            gemm_tile<true><<<dim3(pad8((N_WORD + 63) / 64), 2), 256, 0, stream>>>(
                S0, W1_2, b1_2, S1, N_WORD, dflag);
            spmm_gather128<false><<<row_grid(N_WORD), blk, 0, stream>>>(
                rpA, pA, S1, 1, S0, 1, N_WORD, dflag);
            spmm_norm128<true><<<row_grid(N_DOC), blk, 0, stream>>>(
                rpB, pB, S0, 1, d_out, OUT1_OFF, N_DOC, dflag);
        }
        {
            int* rpA = I; int* rpB = rpA + (N_ENT + 1); int* cur = rpB + (N_DOC + 1);
            unsigned* pA = (unsigned*)(cur + N_ENT + N_DOC); unsigned* pB = pA + E22;
            build2(stream, a22r, a22c, a22v, N_ENT, E22,
                   a02r, a02c, a02v, N_DOC, E02, rpA, rpB, cur, pA, pB, dflag);
            spmm_gather128<false><<<row_grid(N_ENT), blk, 0, stream>>>(
                rpA, pA, f2, 1, E0, 0, N_ENT, dflag);
            gemm_tile<true><<<dim3(pad8((N_ENT + 63) / 64), 2), 256, 0, stream>>>(
                E0, W2_2, b2_2, E1, N_ENT, dflag);
            spmm_gather128<false><<<row_grid(N_ENT), blk, 0, stream>>>(
                rpA, pA, E1, 1, E0, 1, N_ENT, dflag);
            spmm2_norm<<<row_grid(N_DOC), blk, 0, stream>>>(
                rpB, pB, E0, 1, wemb, 1, d_out, OUT2_OFF, N_DOC, dflag);
        }
        {
            int* rpA = I; int* rpB = rpA + (N_POS + 1); int* cur = rpB + (N_DOC + 1);
            unsigned* pA = (unsigned*)(cur + N_POS + N_DOC); unsigned* pB = pA + E33;
            build2(stream, a33r, a33c, a33v, N_POS, E33,
                   a03r, a03c, a03v, N_DOC, E03, rpA, rpB, cur, pA, pB, dflag);
            rowpar_gemm<false, 60><<<N_POS, 128, 0, stream>>>(
                f3, 1, W3, b3, P3a, 1, dflag);
            spmm_gather128<false><<<row_grid(N_POS), blk, 0, stream>>>(
                rpA, pA, P3a, 1, P3b, 1, N_POS, dflag);
            rowpar_gemm<true, 128><<<N_POS, 128, 0, stream>>>(
                P3b, 1, W3_2, b3_2, P3a, 1, dflag);
            spmm_gather128<false><<<row_grid(N_POS), blk, 0, stream>>>(
                rpA, pA, P3a, 1, P3b, 1, N_POS, dflag);
            spmm_norm128<true><<<row_grid(N_DOC), blk, 0, stream>>>(
                rpB, pB, P3b, 1, d_out, OUT3_OFF, N_DOC, dflag);
        }
    } else {
        // ======================= deep fallback: atomic path =======================
        float* S0   = base;
        float* S1   = base + 2560000;
        float* AGG1 = S1;
        float* E0   = base;
        float* E1   = base + 1280000;
        float* AGG2 = base + 1280000;
        float* P3a  = base;
        float* P3b  = base + 7680;
        float* AGG3 = base + 15360;
        hipMemsetAsync(S0, 0, (size_t)N_WORD * DD * 4, stream);
        spmm_kernel<false><<<spmm_grid(E11), blk, 0, stream>>>(
            a11r, a11c, a11v, f1, DD, 1, S0, DD, 0, DD, E11, dflag);
        gemm128_kernel<true><<<(N_WORD + 63) / 64, 256, 0, stream>>>(
            S0, W1_2, b1_2, S1, N_WORD, dflag);
        hipMemsetAsync(S0, 0, (size_t)N_WORD * DD * 4, stream);
        spmm_kernel<false><<<spmm_grid(E11), blk, 0, stream>>>(
            a11r, a11c, a11v, S1, DD, 0, S0, DD, 0, DD, E11, dflag);
        hipMemsetAsync(AGG1, 0, (size_t)N_DOC * DD * 4, stream);
        spmm_kernel<true><<<spmm_grid(E01), blk, 0, stream>>>(
            a01r, a01c, a01v, S0, DD, 0, AGG1, DD, 0, DD, E01, dflag);
        l2norm_kernel<<<row_grid(N_DOC), blk, 0, stream>>>(
            AGG1, DD, d_out, OUT1_OFF, N_DOC, dflag);

        hipMemsetAsync(E0, 0, (size_t)N_ENT * DD * 4, stream);
        spmm_kernel<false><<<spmm_grid(E22), blk, 0, stream>>>(
            a22r, a22c, a22v, f2, DD, 1, E0, DD, 0, DD, E22, dflag);
        gemm128_kernel<true><<<(N_ENT + 63) / 64, 256, 0, stream>>>(
            E0, W2_2, b2_2, E1, N_ENT, dflag);
        hipMemsetAsync(E0, 0, (size_t)N_ENT * DD * 4, stream);
        spmm_kernel<false><<<spmm_grid(E22), blk, 0, stream>>>(
            a22r, a22c, a22v, E1, DD, 0, E0, DD, 0, DD, E22, dflag);
        hipMemsetAsync(AGG2, 0, (size_t)N_DOC * (DD + D_WEMB) * 4, stream);
        spmm_kernel<true><<<spmm_grid(E02), blk, 0, stream>>>(
            a02r, a02c, a02v, E0, DD, 0, AGG2, DD + D_WEMB, 0, DD, E02, dflag);
        spmm_kernel<false><<<spmm_grid(E02), blk, 0, stream>>>(
            a02r, a02c, a02v, wemb, D_WEMB, 1, AGG2, DD + D_WEMB, DD, D_WEMB, E02, dflag);
        l2norm_kernel<<<row_grid(N_DOC), blk, 0, stream>>>(
            AGG2, DD + D_WEMB, d_out, OUT2_OFF, N_DOC, dflag);

        gemm_kernel<false, 60><<<1, 128, 0, stream>>>(f3, 1, W3, b3, P3a, N_POS, dflag);
        hipMemsetAsync(P3b, 0, (size_t)N_POS * DD * 4, stream);
        spmm_kernel<false><<<spmm_grid(E33), blk, 0, stream>>>(
            a33r, a33c, a33v, P3a, DD, 0, P3b, DD, 0, DD, E33, dflag);
        gemm128_kernel<true><<<1, 256, 0, stream>>>(
            P3b, W3_2, b3_2, P3a, N_POS, dflag);
        hipMemsetAsync(P3b, 0, (size_t)N_POS * DD * 4, stream);
        spmm_kernel<false><<<spmm_grid(E33), blk, 0, stream>>>(
            a33r, a33c, a33v, P3a, DD, 0, P3b, DD, 0, DD, E33, dflag);
        hipMemsetAsync(AGG3, 0, (size_t)N_DOC * DD * 4, stream);
        spmm_kernel<true><<<spmm_grid(E03), blk, 0, stream>>>(
            a03r, a03c, a03v, P3b, DD, 0, AGG3, DD, 0, DD, E03, dflag);
        l2norm_kernel<<<row_grid(N_DOC), blk, 0, stream>>>(
            AGG3, DD, d_out, OUT3_OFF, N_DOC, dflag);
    }
}